// Round 1
// baseline (334.038 us; speedup 1.0000x reference)
//
#include <hip/hip_runtime.h>
#include <cstdint>

// Problem constants
#define NB 4
#define NSEQ 1024
#define NH 16
#define HD 72
#define HID 1152
#define QKV3 3456
#define DP 96           // padded head dim (multiple of 32 for K=32 MFMA)
#define SCALE 0.11785113019775793f  // 72^-0.5

typedef __attribute__((ext_vector_type(8))) __bf16 bf16x8;
typedef __attribute__((ext_vector_type(4))) __bf16 bf16x4;
typedef __attribute__((ext_vector_type(4))) float f32x4;

// Workspace layout (bytes)
#define XB_OFF     0UL           // x as bf16            [4096][1152]  9,437,184
#define WQKVT_OFF  9437184UL     // w_qkv^T bf16         [3456][1152]  7,962,624
#define WOUTT_OFF  17399808UL    // w_out^T bf16         [1152][1152]  2,654,208
#define QP_OFF     20054016UL    // Q padded bf16        [64][1024][96] 12,582,912 (scale folded)
#define KP_OFF     32636928UL    // K padded bf16        [64][1024][96] 12,582,912
#define VT_OFF     45219840UL    // V^T padded bf16      [64][96][1024] 12,582,912
#define ATTO_OFF   57802752UL    // attn out bf16        [4096][1152]   9,437,184
// total: 67,239,936 bytes

// ---------------- prep kernels ----------------

__global__ void zero_kernel(uint4* __restrict__ p, long n16) {
    long i = (long)blockIdx.x * blockDim.x + threadIdx.x;
    if (i < n16) p[i] = make_uint4(0u, 0u, 0u, 0u);
}

__global__ void conv_x_kernel(const float* __restrict__ in, __bf16* __restrict__ out, long n4) {
    long i = (long)blockIdx.x * blockDim.x + threadIdx.x;
    if (i >= n4) return;
    float4 v = ((const float4*)in)[i];
    bf16x4 o = { (__bf16)v.x, (__bf16)v.y, (__bf16)v.z, (__bf16)v.w };
    ((bf16x4*)out)[i] = o;
}

// in fp32 [K][Nc] row-major -> out bf16 [Nc][K]
__global__ void transpose_cvt_kernel(const float* __restrict__ in, __bf16* __restrict__ out,
                                     int K, int Nc) {
    __shared__ float t[32][33];
    int n0 = blockIdx.x * 32, k0 = blockIdx.y * 32;
    int x = threadIdx.x, y = threadIdx.y;
    #pragma unroll
    for (int i = 0; i < 32; i += 8)
        t[y + i][x] = in[(long)(k0 + y + i) * Nc + n0 + x];
    __syncthreads();
    #pragma unroll
    for (int i = 0; i < 32; i += 8)
        out[(long)(n0 + y + i) * K + k0 + x] = (__bf16)t[x][y + i];
}

// ---------------- GEMM core (128x128 tile, 4 waves 2x2, BK=32) ----------------
// A row-major [M][K], Bt row-major [N][K]; both bf16. C-frag: col=lane&15, row=(lane>>4)*4+r.

__device__ __forceinline__ void gemm_mainloop(
    const __bf16* __restrict__ A, const __bf16* __restrict__ Bt,
    int lda, int ldb, int K, long rowA0, long rowB0,
    __bf16* As, __bf16* Bs, f32x4 acc[4][4])
{
    const int tid  = threadIdx.x;
    const int wave = tid >> 6, lane = tid & 63;
    const int wm = wave >> 1, wn = wave & 1;
    const int lhi = lane >> 4, llo = lane & 15;

    for (int k0 = 0; k0 < K; k0 += 32) {
        // stage 128x32 A-tile and B-tile (8KB each) via registers
        bf16x8 ra[2], rb[2];
        #pragma unroll
        for (int c = 0; c < 2; ++c) {
            int boff = tid * 16 + c * 4096;           // byte offset in tile
            int e = boff >> 1, r = e >> 5, kk = e & 31;
            ra[c] = *(const bf16x8*)(A  + (rowA0 + r) * (long)lda + k0 + kk);
            rb[c] = *(const bf16x8*)(Bt + (rowB0 + r) * (long)ldb + k0 + kk);
        }
        __syncthreads();   // prev iteration's frag reads done
        #pragma unroll
        for (int c = 0; c < 2; ++c) {
            int boff = tid * 16 + c * 4096;
            *(bf16x8*)((char*)As + boff) = ra[c];
            *(bf16x8*)((char*)Bs + boff) = rb[c];
        }
        __syncthreads();   // staged data visible
        bf16x8 af[4], bfr[4];
        #pragma unroll
        for (int mt = 0; mt < 4; ++mt)
            af[mt] = *(const bf16x8*)(As + (wm * 64 + mt * 16 + llo) * 32 + lhi * 8);
        #pragma unroll
        for (int nt = 0; nt < 4; ++nt)
            bfr[nt] = *(const bf16x8*)(Bs + (wn * 64 + nt * 16 + llo) * 32 + lhi * 8);
        #pragma unroll
        for (int mt = 0; mt < 4; ++mt)
            #pragma unroll
            for (int nt = 0; nt < 4; ++nt)
                acc[mt][nt] = __builtin_amdgcn_mfma_f32_16x16x32_bf16(af[mt], bfr[nt], acc[mt][nt], 0, 0, 0);
    }
}

// ---------------- GEMM 1: qkv = x @ w_qkv + b, scatter to Qp/Kp/Vt ----------------

__global__ __launch_bounds__(256) void gemm_qkv_kernel(
    const __bf16* __restrict__ xb, const __bf16* __restrict__ wqkvT,
    const float* __restrict__ b_qkv,
    __bf16* __restrict__ Qp, __bf16* __restrict__ Kp, __bf16* __restrict__ Vt)
{
    __shared__ __bf16 smem[8192];
    f32x4 acc[4][4];
    #pragma unroll
    for (int i = 0; i < 4; ++i)
        #pragma unroll
        for (int j = 0; j < 4; ++j) acc[i][j] = (f32x4){0.f, 0.f, 0.f, 0.f};

    long rowA0 = (long)blockIdx.x * 128, rowB0 = (long)blockIdx.y * 128;
    gemm_mainloop(xb, wqkvT, HID, HID, HID, rowA0, rowB0, smem, smem + 4096, acc);

    const int wave = threadIdx.x >> 6, lane = threadIdx.x & 63;
    const int wm = wave >> 1, wn = wave & 1, lhi = lane >> 4, llo = lane & 15;

    #pragma unroll
    for (int nt = 0; nt < 4; ++nt) {
        #pragma unroll
        for (int mt = 0; mt < 4; ++mt) {
            int n   = (int)rowB0 + wn * 64 + nt * 16 + llo;   // 0..3455
            int sec = n / HID;
            int nn  = n - sec * HID;
            int h   = nn / HD;
            int d   = nn - h * HD;
            float bias = b_qkv[n];
            #pragma unroll
            for (int r = 0; r < 4; ++r) {
                int m = (int)rowA0 + wm * 64 + mt * 16 + lhi * 4 + r;  // 0..4095
                float v = acc[mt][nt][r] + bias;
                int bb = m >> 10, nq = m & 1023;
                long bhn = (long)(bb * NH + h) * NSEQ + nq;
                if (sec == 0)      Qp[bhn * DP + d] = (__bf16)(v * SCALE);
                else if (sec == 1) Kp[bhn * DP + d] = (__bf16)v;
                else               Vt[((long)(bb * NH + h) * DP + d) * NSEQ + nq] = (__bf16)v;
            }
        }
    }
}

// ---------------- flash attention ----------------
// grid (16 qblocks, 64 bh), 256 threads = 4 independent waves, each owns 16 q-rows.

__global__ __launch_bounds__(256) void flash_kernel(
    const __bf16* __restrict__ Qp, const __bf16* __restrict__ Kp,
    const __bf16* __restrict__ Vt, __bf16* __restrict__ atto)
{
    __shared__ char plds[4][2048];   // per-wave P tile, 16x64 bf16, XOR-swizzled

    const int bh   = blockIdx.y;
    const int wave = threadIdx.x >> 6, lane = threadIdx.x & 63;
    const int lhi = lane >> 4, llo = lane & 15;
    const int q0 = blockIdx.x * 64 + wave * 16;

    const __bf16* Qb = Qp + (long)bh * NSEQ * DP;
    const __bf16* Kb = Kp + (long)bh * NSEQ * DP;
    const __bf16* Vb = Vt + (long)bh * DP * NSEQ;
    char* P = plds[wave];

    // Q fragments: A[row=llo][k=dc*32+lhi*8+j] (scale already folded)
    bf16x8 aq[3];
    #pragma unroll
    for (int dc = 0; dc < 3; ++dc)
        aq[dc] = *(const bf16x8*)(Qb + (long)(q0 + llo) * DP + dc * 32 + lhi * 8);

    float mrun[4], lrun[4];
    f32x4 accO[5];
    #pragma unroll
    for (int r = 0; r < 4; ++r) { mrun[r] = -1e30f; lrun[r] = 0.f; }
    #pragma unroll
    for (int t = 0; t < 5; ++t) accO[t] = (f32x4){0.f, 0.f, 0.f, 0.f};

    for (int kb = 0; kb < 16; ++kb) {
        const int key0 = kb * 64;
        // S = Q K^T  (scaled), 4 col-tiles x 3 d-chunks
        f32x4 s[4];
        #pragma unroll
        for (int ct = 0; ct < 4; ++ct) {
            f32x4 z = (f32x4){0.f, 0.f, 0.f, 0.f};
            int key = key0 + ct * 16 + llo;
            #pragma unroll
            for (int dc = 0; dc < 3; ++dc) {
                bf16x8 bk = *(const bf16x8*)(Kb + (long)key * DP + dc * 32 + lhi * 8);
                z = __builtin_amdgcn_mfma_f32_16x16x32_bf16(aq[dc], bk, z, 0, 0, 0);
            }
            s[ct] = z;
        }
        // online softmax (wave-parallel: reduce across the 16 llo lanes)
        float mnew[4], alpha[4];
        #pragma unroll
        for (int r = 0; r < 4; ++r) {
            float mx = fmaxf(fmaxf(s[0][r], s[1][r]), fmaxf(s[2][r], s[3][r]));
            #pragma unroll
            for (int off = 1; off < 16; off <<= 1)
                mx = fmaxf(mx, __shfl_xor(mx, off, 64));
            mnew[r]  = fmaxf(mrun[r], mx);
            alpha[r] = __expf(mrun[r] - mnew[r]);
            mrun[r]  = mnew[r];
        }
        float p[4][4];
        #pragma unroll
        for (int ct = 0; ct < 4; ++ct)
            #pragma unroll
            for (int r = 0; r < 4; ++r)
                p[ct][r] = __expf(s[ct][r] - mnew[r]);
        #pragma unroll
        for (int r = 0; r < 4; ++r) {
            float sm = p[0][r] + p[1][r] + p[2][r] + p[3][r];
            #pragma unroll
            for (int off = 1; off < 16; off <<= 1)
                sm += __shfl_xor(sm, off, 64);
            lrun[r] = lrun[r] * alpha[r] + sm;
        }
        #pragma unroll
        for (int t = 0; t < 5; ++t)
            #pragma unroll
            for (int r = 0; r < 4; ++r)
                accO[t][r] *= alpha[r];
        // P -> LDS (bf16, swizzled): P[q=lhi*4+r][col=ct*16+llo]
        #pragma unroll
        for (int ct = 0; ct < 4; ++ct)
            #pragma unroll
            for (int r = 0; r < 4; ++r) {
                int row = lhi * 4 + r, col = ct * 16 + llo;
                int byte = (row * 128 + col * 2) ^ ((row & 7) << 4);
                *(__bf16*)(P + byte) = (__bf16)p[ct][r];
            }
        asm volatile("s_waitcnt lgkmcnt(0)" ::: "memory");
        // PV: A[row=llo][k=nc*32+lhi*8+j] from P; B from Vt rows (contiguous n)
        #pragma unroll
        for (int nc = 0; nc < 2; ++nc) {
            int byte = (llo * 128 + nc * 64 + lhi * 16) ^ ((llo & 7) << 4);
            bf16x8 pa = *(const bf16x8*)(P + byte);
            #pragma unroll
            for (int t = 0; t < 5; ++t) {
                bf16x8 bv = *(const bf16x8*)(Vb + (long)(t * 16 + llo) * NSEQ + key0 + nc * 32 + lhi * 8);
                accO[t] = __builtin_amdgcn_mfma_f32_16x16x32_bf16(pa, bv, accO[t], 0, 0, 0);
            }
        }
    }
    // epilogue: atto[b*1024+q][h*72+d]
    const int b = bh >> 4, h = bh & 15;
    #pragma unroll
    for (int t = 0; t < 5; ++t) {
        int d = t * 16 + llo;
        if (d < HD) {
            #pragma unroll
            for (int r = 0; r < 4; ++r) {
                int q = q0 + lhi * 4 + r;
                float v = accO[t][r] / lrun[r];
                atto[(long)(b * NSEQ + q) * HID + h * HD + d] = (__bf16)v;
            }
        }
    }
}

// ---------------- GEMM 2: out = atto @ w_out + b_out (fp32 out) ----------------

__global__ __launch_bounds__(256) void gemm_out_kernel(
    const __bf16* __restrict__ atto, const __bf16* __restrict__ woutT,
    const float* __restrict__ b_out, float* __restrict__ out)
{
    __shared__ __bf16 smem[8192];
    f32x4 acc[4][4];
    #pragma unroll
    for (int i = 0; i < 4; ++i)
        #pragma unroll
        for (int j = 0; j < 4; ++j) acc[i][j] = (f32x4){0.f, 0.f, 0.f, 0.f};

    long rowA0 = (long)blockIdx.x * 128, rowB0 = (long)blockIdx.y * 128;
    gemm_mainloop(atto, woutT, HID, HID, HID, rowA0, rowB0, smem, smem + 4096, acc);

    const int wave = threadIdx.x >> 6, lane = threadIdx.x & 63;
    const int wm = wave >> 1, wn = wave & 1, lhi = lane >> 4, llo = lane & 15;

    #pragma unroll
    for (int nt = 0; nt < 4; ++nt) {
        int n = (int)rowB0 + wn * 64 + nt * 16 + llo;
        float bias = b_out[n];
        #pragma unroll
        for (int mt = 0; mt < 4; ++mt) {
            #pragma unroll
            for (int r = 0; r < 4; ++r) {
                int m = (int)rowA0 + wm * 64 + mt * 16 + lhi * 4 + r;
                out[(long)m * HID + n] = acc[mt][nt][r] + bias;
            }
        }
    }
}

// ---------------- launch ----------------

extern "C" void kernel_launch(void* const* d_in, const int* in_sizes, int n_in,
                              void* d_out, int out_size, void* d_ws, size_t ws_size,
                              hipStream_t stream) {
    const float* x      = (const float*)d_in[0];
    const float* w_qkv  = (const float*)d_in[1];
    const float* b_qkv  = (const float*)d_in[2];
    const float* w_out  = (const float*)d_in[3];
    const float* b_out  = (const float*)d_in[4];
    float* out = (float*)d_out;
    char* ws = (char*)d_ws;

    __bf16* xb    = (__bf16*)(ws + XB_OFF);
    __bf16* wqkvT = (__bf16*)(ws + WQKVT_OFF);
    __bf16* woutT = (__bf16*)(ws + WOUTT_OFF);
    __bf16* Qp    = (__bf16*)(ws + QP_OFF);
    __bf16* Kp    = (__bf16*)(ws + KP_OFF);
    __bf16* Vt    = (__bf16*)(ws + VT_OFF);
    __bf16* atto  = (__bf16*)(ws + ATTO_OFF);

    // zero Qp/Kp/Vt (contiguous 37,748,736 B) for the D-padding
    zero_kernel<<<9216, 256, 0, stream>>>((uint4*)(ws + QP_OFF), 37748736L / 16);
    conv_x_kernel<<<4608, 256, 0, stream>>>(x, xb, 1179648L);
    transpose_cvt_kernel<<<dim3(108, 36), dim3(32, 8), 0, stream>>>(w_qkv, wqkvT, HID, QKV3);
    transpose_cvt_kernel<<<dim3(36, 36), dim3(32, 8), 0, stream>>>(w_out, woutT, HID, HID);
    gemm_qkv_kernel<<<dim3(32, 27), 256, 0, stream>>>(xb, wqkvT, b_qkv, Qp, Kp, Vt);
    flash_kernel<<<dim3(16, 64), 256, 0, stream>>>(Qp, Kp, Vt, atto);
    gemm_out_kernel<<<dim3(32, 9), 256, 0, stream>>>(atto, woutT, b_out, out);
}

// Round 2
// 240.765 us; speedup vs baseline: 1.3874x; 1.3874x over previous
//
#include <hip/hip_runtime.h>
#include <cstdint>

// Problem constants
#define NB 4
#define NSEQ 1024
#define NH 16
#define HD 72
#define HID 1152
#define QKV3 3456
#define DP 96           // padded head dim (multiple of 32 for K=32 MFMA)
// scale = 72^-0.5 folded with log2(e) so softmax runs in exp2 domain
#define QSCALE 0.17003713711193175f

typedef __attribute__((ext_vector_type(8))) __bf16 bf16x8;
typedef __attribute__((ext_vector_type(4))) __bf16 bf16x4;
typedef __attribute__((ext_vector_type(4))) float f32x4;

// Workspace layout (bytes)
#define XB_OFF     0UL           // x as bf16            [4096][1152]
#define WQKVT_OFF  9437184UL     // w_qkv^T bf16         [3456][1152]
#define WOUTT_OFF  17399808UL    // w_out^T bf16         [1152][1152]
#define QP_OFF     20054016UL    // Q padded bf16        [64][1024][96] (QSCALE folded)
#define KP_OFF     32636928UL    // K padded bf16        [64][1024][96]
#define VT_OFF     45219840UL    // V^T padded bf16      [64][96][1024]
#define ATTO_OFF   57802752UL    // attn out bf16        [4096][1152]

// ---------------- prep kernels ----------------

__global__ void zero_kernel(uint4* __restrict__ p, long n16) {
    long i = (long)blockIdx.x * blockDim.x + threadIdx.x;
    if (i < n16) p[i] = make_uint4(0u, 0u, 0u, 0u);
}

__global__ void conv_x_kernel(const float* __restrict__ in, __bf16* __restrict__ out, long n4) {
    long i = (long)blockIdx.x * blockDim.x + threadIdx.x;
    if (i >= n4) return;
    float4 v = ((const float4*)in)[i];
    bf16x4 o = { (__bf16)v.x, (__bf16)v.y, (__bf16)v.z, (__bf16)v.w };
    ((bf16x4*)out)[i] = o;
}

// in fp32 [K][Nc] row-major -> out bf16 [Nc][K]
__global__ void transpose_cvt_kernel(const float* __restrict__ in, __bf16* __restrict__ out,
                                     int K, int Nc) {
    __shared__ float t[32][33];
    int n0 = blockIdx.x * 32, k0 = blockIdx.y * 32;
    int x = threadIdx.x, y = threadIdx.y;
    #pragma unroll
    for (int i = 0; i < 32; i += 8)
        t[y + i][x] = in[(long)(k0 + y + i) * Nc + n0 + x];
    __syncthreads();
    #pragma unroll
    for (int i = 0; i < 32; i += 8)
        out[(long)(n0 + y + i) * K + k0 + x] = (__bf16)t[x][y + i];
}

// ---------------- GEMM core (128x128 tile, 4 waves 2x2, BK=32) ----------------
// A row-major [M][K], Bt row-major [N][K]; both bf16. C-frag: col=lane&15, row=(lane>>4)*4+r.

__device__ __forceinline__ void gemm_mainloop(
    const __bf16* __restrict__ A, const __bf16* __restrict__ Bt,
    int lda, int ldb, int K, long rowA0, long rowB0,
    __bf16* As, __bf16* Bs, f32x4 acc[4][4])
{
    const int tid  = threadIdx.x;
    const int wave = tid >> 6, lane = tid & 63;
    const int wm = wave >> 1, wn = wave & 1;
    const int lhi = lane >> 4, llo = lane & 15;

    for (int k0 = 0; k0 < K; k0 += 32) {
        bf16x8 ra[2], rb[2];
        #pragma unroll
        for (int c = 0; c < 2; ++c) {
            int boff = tid * 16 + c * 4096;           // byte offset in tile
            int e = boff >> 1, r = e >> 5, kk = e & 31;
            ra[c] = *(const bf16x8*)(A  + (rowA0 + r) * (long)lda + k0 + kk);
            rb[c] = *(const bf16x8*)(Bt + (rowB0 + r) * (long)ldb + k0 + kk);
        }
        __syncthreads();   // prev iteration's frag reads done
        #pragma unroll
        for (int c = 0; c < 2; ++c) {
            int boff = tid * 16 + c * 4096;
            *(bf16x8*)((char*)As + boff) = ra[c];
            *(bf16x8*)((char*)Bs + boff) = rb[c];
        }
        __syncthreads();   // staged data visible
        bf16x8 af[4], bfr[4];
        #pragma unroll
        for (int mt = 0; mt < 4; ++mt)
            af[mt] = *(const bf16x8*)(As + (wm * 64 + mt * 16 + llo) * 32 + lhi * 8);
        #pragma unroll
        for (int nt = 0; nt < 4; ++nt)
            bfr[nt] = *(const bf16x8*)(Bs + (wn * 64 + nt * 16 + llo) * 32 + lhi * 8);
        #pragma unroll
        for (int mt = 0; mt < 4; ++mt)
            #pragma unroll
            for (int nt = 0; nt < 4; ++nt)
                acc[mt][nt] = __builtin_amdgcn_mfma_f32_16x16x32_bf16(af[mt], bfr[nt], acc[mt][nt], 0, 0, 0);
    }
}

// ---------------- GEMM 1: qkv = x @ w_qkv + b, scatter to Qp/Kp/Vt ----------------

__global__ __launch_bounds__(256) void gemm_qkv_kernel(
    const __bf16* __restrict__ xb, const __bf16* __restrict__ wqkvT,
    const float* __restrict__ b_qkv,
    __bf16* __restrict__ Qp, __bf16* __restrict__ Kp, __bf16* __restrict__ Vt)
{
    __shared__ __bf16 smem[8192];
    f32x4 acc[4][4];
    #pragma unroll
    for (int i = 0; i < 4; ++i)
        #pragma unroll
        for (int j = 0; j < 4; ++j) acc[i][j] = (f32x4){0.f, 0.f, 0.f, 0.f};

    long rowA0 = (long)blockIdx.x * 128, rowB0 = (long)blockIdx.y * 128;
    gemm_mainloop(xb, wqkvT, HID, HID, HID, rowA0, rowB0, smem, smem + 4096, acc);

    const int wave = threadIdx.x >> 6, lane = threadIdx.x & 63;
    const int wm = wave >> 1, wn = wave & 1, lhi = lane >> 4, llo = lane & 15;

    #pragma unroll
    for (int nt = 0; nt < 4; ++nt) {
        #pragma unroll
        for (int mt = 0; mt < 4; ++mt) {
            int n   = (int)rowB0 + wn * 64 + nt * 16 + llo;   // 0..3455
            int sec = n / HID;
            int nn  = n - sec * HID;
            int h   = nn / HD;
            int d   = nn - h * HD;
            float bias = b_qkv[n];
            #pragma unroll
            for (int r = 0; r < 4; ++r) {
                int m = (int)rowA0 + wm * 64 + mt * 16 + lhi * 4 + r;  // 0..4095
                float v = acc[mt][nt][r] + bias;
                int bb = m >> 10, nq = m & 1023;
                long bhn = (long)(bb * NH + h) * NSEQ + nq;
                if (sec == 0)      Qp[bhn * DP + d] = (__bf16)(v * QSCALE);
                else if (sec == 1) Kp[bhn * DP + d] = (__bf16)v;
                else               Vt[((long)(bb * NH + h) * DP + d) * NSEQ + nq] = (__bf16)v;
            }
        }
    }
}

// ---------------- flash attention v2 ----------------
// grid (16 qblocks, 64 bh), 256 threads = 4 waves, each wave owns 16 q-rows.
// K/V tiles staged in LDS (shared by all 4 waves), T14 async-split pipeline:
// issue next-tile global loads -> compute current tile from LDS -> barrier ->
// ds_write staged regs -> barrier.  Transposed QK^T (mfma(K,Q)) makes the
// softmax row lane-local (15 fmax + 2 shfl instead of 32 shfl).

__global__ __launch_bounds__(256) void flash_kernel(
    const __bf16* __restrict__ Qp, const __bf16* __restrict__ Kp,
    const __bf16* __restrict__ Vt, __bf16* __restrict__ atto)
{
    __shared__ char lds[32768];
    char* Ks = lds;            // [64 key][96 d] bf16, 192B rows, XOR-swizzled
    char* Vs = lds + 12288;    // [96 d][64 key] bf16, 128B rows, XOR-swizzled

    const int bh   = blockIdx.y;
    const int tid  = threadIdx.x;
    const int wave = tid >> 6, lane = tid & 63;
    const int lhi = lane >> 4, llo = lane & 15;
    char* P = lds + 24576 + wave * 2048;   // per-wave P tile [16 q][64 k] bf16, swizzled
    const int q0 = blockIdx.x * 64 + wave * 16;

    const __bf16* Qb = Qp + (long)bh * NSEQ * DP;
    const __bf16* Kb = Kp + (long)bh * NSEQ * DP;
    const __bf16* Vb = Vt + (long)bh * DP * NSEQ;

    // staging assignment: 3 x 16B chunks per thread for each of K and V
    const __bf16* kG[3]; const __bf16* vG[3];
    int kL[3], vL[3];
    #pragma unroll
    for (int i = 0; i < 3; ++i) {
        int c = tid + i * 256;                    // 0..767
        int key = c / 12, part = c - key * 12;    // 64 rows x 12 chunks
        kL[i] = (key * 192 + part * 16) ^ ((key & 7) << 4);
        kG[i] = Kb + key * DP + part * 8;
        int dv = c >> 3, k8 = c & 7;              // 96 rows x 8 chunks
        vL[i] = (dv * 128 + k8 * 16) ^ ((dv & 7) << 4);
        vG[i] = Vb + dv * NSEQ + k8 * 8;
    }

    // Q fragments (B operand): Q[q=llo][d = dc*32 + lhi*8 + j]; QSCALE folded
    bf16x8 aq[3];
    #pragma unroll
    for (int dc = 0; dc < 3; ++dc)
        aq[dc] = *(const bf16x8*)(Qb + (long)(q0 + llo) * DP + dc * 32 + lhi * 8);

    float mrun = -3.0e38f, lrun = 0.f;    // per-lane state for q = q0 + llo
    f32x4 accO[5];
    #pragma unroll
    for (int t = 0; t < 5; ++t) accO[t] = (f32x4){0.f, 0.f, 0.f, 0.f};

    // prologue: stage tile 0
    uint4 rK[3], rV[3];
    #pragma unroll
    for (int i = 0; i < 3; ++i) { rK[i] = *(const uint4*)kG[i]; rV[i] = *(const uint4*)vG[i]; }
    #pragma unroll
    for (int i = 0; i < 3; ++i) { *(uint4*)(Ks + kL[i]) = rK[i]; *(uint4*)(Vs + vL[i]) = rV[i]; }
    __syncthreads();

    #pragma unroll 1
    for (int kb = 0; kb < 16; ++kb) {
        // issue next-tile global loads (land during compute phase)
        if (kb < 15) {
            #pragma unroll
            for (int i = 0; i < 3; ++i) {
                rK[i] = *(const uint4*)(kG[i] + (kb + 1) * 64 * DP);
                rV[i] = *(const uint4*)(vG[i] + (kb + 1) * 64);
            }
        }
        // S^T = mfma(K, Q): s[ct][r] = S[q=llo][key = ct*16 + lhi*4 + r]
        f32x4 s[4];
        #pragma unroll
        for (int ct = 0; ct < 4; ++ct) {
            f32x4 z = (f32x4){0.f, 0.f, 0.f, 0.f};
            #pragma unroll
            for (int dc = 0; dc < 3; ++dc) {
                bf16x8 kf = *(const bf16x8*)(Ks +
                    (((ct * 16 + llo) * 192 + dc * 64 + lhi * 16) ^ ((llo & 7) << 4)));
                z = __builtin_amdgcn_mfma_f32_16x16x32_bf16(kf, aq[dc], z, 0, 0, 0);
            }
            s[ct] = z;
        }
        // online softmax, exp2 domain, lane-local row
        float m0 = fmaxf(fmaxf(s[0][0], s[0][1]), fmaxf(s[0][2], s[0][3]));
        float m1 = fmaxf(fmaxf(s[1][0], s[1][1]), fmaxf(s[1][2], s[1][3]));
        float m2 = fmaxf(fmaxf(s[2][0], s[2][1]), fmaxf(s[2][2], s[2][3]));
        float m3 = fmaxf(fmaxf(s[3][0], s[3][1]), fmaxf(s[3][2], s[3][3]));
        float mx = fmaxf(fmaxf(m0, m1), fmaxf(m2, m3));
        mx = fmaxf(mx, __shfl_xor(mx, 16, 64));
        mx = fmaxf(mx, __shfl_xor(mx, 32, 64));
        float mnew = fmaxf(mrun, mx);
        float al = exp2f(mrun - mnew);
        mrun = mnew;
        float p[4][4];
        float sm = 0.f;
        #pragma unroll
        for (int ct = 0; ct < 4; ++ct)
            #pragma unroll
            for (int r = 0; r < 4; ++r) {
                p[ct][r] = exp2f(s[ct][r] - mnew);
                sm += p[ct][r];
            }
        sm += __shfl_xor(sm, 16, 64);
        sm += __shfl_xor(sm, 32, 64);
        lrun = lrun * al + sm;
        float alq[4];
        #pragma unroll
        for (int r = 0; r < 4; ++r) alq[r] = __shfl(al, lhi * 4 + r, 64);
        #pragma unroll
        for (int t = 0; t < 5; ++t)
            #pragma unroll
            for (int r = 0; r < 4; ++r)
                accO[t][r] *= alq[r];
        // P -> LDS: row q=llo, cols ct*16+lhi*4..+3 contiguous -> one b64 per ct
        #pragma unroll
        for (int ct = 0; ct < 4; ++ct) {
            bf16x4 pk = { (__bf16)p[ct][0], (__bf16)p[ct][1], (__bf16)p[ct][2], (__bf16)p[ct][3] };
            *(bf16x4*)(P + ((llo * 128 + ct * 32 + lhi * 8) ^ ((llo & 7) << 4))) = pk;
        }
        asm volatile("s_waitcnt lgkmcnt(0)" ::: "memory");
        // PV: A = P[q=llo][k], B = V^T[d][k] from LDS
        #pragma unroll
        for (int nc = 0; nc < 2; ++nc) {
            bf16x8 pa = *(const bf16x8*)(P + ((llo * 128 + nc * 64 + lhi * 16) ^ ((llo & 7) << 4)));
            #pragma unroll
            for (int t = 0; t < 5; ++t) {
                bf16x8 bv = *(const bf16x8*)(Vs +
                    (((t * 16 + llo) * 128 + nc * 64 + lhi * 16) ^ ((llo & 7) << 4)));
                accO[t] = __builtin_amdgcn_mfma_f32_16x16x32_bf16(pa, bv, accO[t], 0, 0, 0);
            }
        }
        __syncthreads();   // all waves done reading Ks/Vs
        if (kb < 15) {
            #pragma unroll
            for (int i = 0; i < 3; ++i) { *(uint4*)(Ks + kL[i]) = rK[i]; *(uint4*)(Vs + vL[i]) = rV[i]; }
        }
        __syncthreads();   // staged tile visible
    }

    // epilogue: atto[b*1024+q][h*72+d], q = q0 + lhi*4 + r, d = t*16 + llo
    float linv[4];
    #pragma unroll
    for (int r = 0; r < 4; ++r) linv[r] = 1.f / __shfl(lrun, lhi * 4 + r, 64);
    const int b = bh >> 4, h = bh & 15;
    #pragma unroll
    for (int t = 0; t < 5; ++t) {
        int d = t * 16 + llo;
        if (d < HD) {
            #pragma unroll
            for (int r = 0; r < 4; ++r) {
                int q = q0 + lhi * 4 + r;
                atto[(long)(b * NSEQ + q) * HID + h * HD + d] = (__bf16)(accO[t][r] * linv[r]);
            }
        }
    }
}

// ---------------- GEMM 2: out = atto @ w_out + b_out (fp32 out) ----------------

__global__ __launch_bounds__(256) void gemm_out_kernel(
    const __bf16* __restrict__ atto, const __bf16* __restrict__ woutT,
    const float* __restrict__ b_out, float* __restrict__ out)
{
    __shared__ __bf16 smem[8192];
    f32x4 acc[4][4];
    #pragma unroll
    for (int i = 0; i < 4; ++i)
        #pragma unroll
        for (int j = 0; j < 4; ++j) acc[i][j] = (f32x4){0.f, 0.f, 0.f, 0.f};

    long rowA0 = (long)blockIdx.x * 128, rowB0 = (long)blockIdx.y * 128;
    gemm_mainloop(atto, woutT, HID, HID, HID, rowA0, rowB0, smem, smem + 4096, acc);

    const int wave = threadIdx.x >> 6, lane = threadIdx.x & 63;
    const int wm = wave >> 1, wn = wave & 1, lhi = lane >> 4, llo = lane & 15;

    #pragma unroll
    for (int nt = 0; nt < 4; ++nt) {
        int n = (int)rowB0 + wn * 64 + nt * 16 + llo;
        float bias = b_out[n];
        #pragma unroll
        for (int mt = 0; mt < 4; ++mt) {
            #pragma unroll
            for (int r = 0; r < 4; ++r) {
                int m = (int)rowA0 + wm * 64 + mt * 16 + lhi * 4 + r;
                out[(long)m * HID + n] = acc[mt][nt][r] + bias;
            }
        }
    }
}

// ---------------- launch ----------------

extern "C" void kernel_launch(void* const* d_in, const int* in_sizes, int n_in,
                              void* d_out, int out_size, void* d_ws, size_t ws_size,
                              hipStream_t stream) {
    const float* x      = (const float*)d_in[0];
    const float* w_qkv  = (const float*)d_in[1];
    const float* b_qkv  = (const float*)d_in[2];
    const float* w_out  = (const float*)d_in[3];
    const float* b_out  = (const float*)d_in[4];
    float* out = (float*)d_out;
    char* ws = (char*)d_ws;

    __bf16* xb    = (__bf16*)(ws + XB_OFF);
    __bf16* wqkvT = (__bf16*)(ws + WQKVT_OFF);
    __bf16* woutT = (__bf16*)(ws + WOUTT_OFF);
    __bf16* Qp    = (__bf16*)(ws + QP_OFF);
    __bf16* Kp    = (__bf16*)(ws + KP_OFF);
    __bf16* Vt    = (__bf16*)(ws + VT_OFF);
    __bf16* atto  = (__bf16*)(ws + ATTO_OFF);

    // zero Qp/Kp/Vt (contiguous 37,748,736 B) for the D-padding
    zero_kernel<<<9216, 256, 0, stream>>>((uint4*)(ws + QP_OFF), 37748736L / 16);
    conv_x_kernel<<<4608, 256, 0, stream>>>(x, xb, 1179648L);
    transpose_cvt_kernel<<<dim3(108, 36), dim3(32, 8), 0, stream>>>(w_qkv, wqkvT, HID, QKV3);
    transpose_cvt_kernel<<<dim3(36, 36), dim3(32, 8), 0, stream>>>(w_out, woutT, HID, HID);
    gemm_qkv_kernel<<<dim3(32, 27), 256, 0, stream>>>(xb, wqkvT, b_qkv, Qp, Kp, Vt);
    flash_kernel<<<dim3(16, 64), 256, 0, stream>>>(Qp, Kp, Vt, atto);
    gemm_out_kernel<<<dim3(32, 9), 256, 0, stream>>>(atto, woutT, b_out, out);
}

// Round 3
// 198.431 us; speedup vs baseline: 1.6834x; 1.2133x over previous
//
#include <hip/hip_runtime.h>
#include <cstdint>

// Problem constants
#define NB 4
#define NSEQ 1024
#define NH 16
#define HD 72
#define HID 1152
#define QKV3 3456
#define DP 96           // padded head dim (multiple of 32 for K=32 MFMA)
// scale = 72^-0.5 folded with log2(e) so softmax runs in exp2 domain
#define QSCALE 0.17003713711193175f

typedef __attribute__((ext_vector_type(8))) __bf16 bf16x8;
typedef __attribute__((ext_vector_type(4))) __bf16 bf16x4;
typedef __attribute__((ext_vector_type(4))) float f32x4;

#define AS1 __attribute__((address_space(1)))
#define AS3 __attribute__((address_space(3)))

__device__ __forceinline__ void gl_lds16(const void* g, void* l) {
    // async global->LDS, 16B per lane; LDS dest = wave-uniform base + lane*16
    __builtin_amdgcn_global_load_lds((const AS1 uint32_t*)g, (AS3 uint32_t*)l, 16, 0, 0);
}

// Workspace layout (bytes)
#define XB_OFF     0UL           // x as bf16            [4096][1152]
#define WQKVT_OFF  9437184UL     // w_qkv^T bf16         [3456][1152]
#define WOUTT_OFF  17399808UL    // w_out^T bf16         [1152][1152]
#define QP_OFF     20054016UL    // Q padded bf16        [64][1024][96] (QSCALE folded)
#define KP_OFF     32636928UL    // K padded bf16        [64][1024][96]
#define VT_OFF     45219840UL    // V^T padded bf16      [64][96][1024]
#define ATTO_OFF   57802752UL    // attn out bf16        [4096][1152]

// ---------------- prep kernels ----------------

__global__ void zero_kernel(uint4* __restrict__ p, long n16) {
    long i = (long)blockIdx.x * blockDim.x + threadIdx.x;
    if (i < n16) p[i] = make_uint4(0u, 0u, 0u, 0u);
}

__global__ void conv_x_kernel(const float* __restrict__ in, __bf16* __restrict__ out, long n4) {
    long i = (long)blockIdx.x * blockDim.x + threadIdx.x;
    if (i >= n4) return;
    float4 v = ((const float4*)in)[i];
    bf16x4 o = { (__bf16)v.x, (__bf16)v.y, (__bf16)v.z, (__bf16)v.w };
    ((bf16x4*)out)[i] = o;
}

// in fp32 [K][Nc] row-major -> out bf16 [Nc][K]
__global__ void transpose_cvt_kernel(const float* __restrict__ in, __bf16* __restrict__ out,
                                     int K, int Nc) {
    __shared__ float t[32][33];
    int n0 = blockIdx.x * 32, k0 = blockIdx.y * 32;
    int x = threadIdx.x, y = threadIdx.y;
    #pragma unroll
    for (int i = 0; i < 32; i += 8)
        t[y + i][x] = in[(long)(k0 + y + i) * Nc + n0 + x];
    __syncthreads();
    #pragma unroll
    for (int i = 0; i < 32; i += 8)
        out[(long)(n0 + y + i) * K + k0 + x] = (__bf16)t[x][y + i];
}

// ---------------- GEMM core (128x128 tile, 4 waves 2x2, BK=32, global_load_lds) ----------------
// A row-major [M][K], Bt row-major [N][K]; both bf16. C-frag: col=lane&15, row=(lane>>4)*4+r.

__device__ __forceinline__ void gemm_mainloop(
    const __bf16* __restrict__ A, const __bf16* __restrict__ Bt,
    int lda, int ldb, int K, long rowA0, long rowB0,
    __bf16* As, __bf16* Bs, f32x4 acc[4][4])
{
    const int tid  = threadIdx.x;
    const int wave = tid >> 6, lane = tid & 63;
    const int wm = wave >> 1, wn = wave & 1;
    const int lhi = lane >> 4, llo = lane & 15;
    // staging coords: LDS elem offset tid*8 (+2048 for 2nd chunk) == rows rr/rr+64, col kk
    const int rr = tid >> 2, kk = (tid & 3) * 8;

    for (int k0 = 0; k0 < K; k0 += 32) {
        __syncthreads();   // prev iteration's frag reads done
        gl_lds16(A  + (rowA0 + rr)      * (long)lda + k0 + kk, As + tid * 8);
        gl_lds16(A  + (rowA0 + rr + 64) * (long)lda + k0 + kk, As + tid * 8 + 2048);
        gl_lds16(Bt + (rowB0 + rr)      * (long)ldb + k0 + kk, Bs + tid * 8);
        gl_lds16(Bt + (rowB0 + rr + 64) * (long)ldb + k0 + kk, Bs + tid * 8 + 2048);
        asm volatile("s_waitcnt vmcnt(0)" ::: "memory");
        __syncthreads();   // staged data visible
        bf16x8 af[4], bfr[4];
        #pragma unroll
        for (int mt = 0; mt < 4; ++mt)
            af[mt] = *(const bf16x8*)(As + (wm * 64 + mt * 16 + llo) * 32 + lhi * 8);
        #pragma unroll
        for (int nt = 0; nt < 4; ++nt)
            bfr[nt] = *(const bf16x8*)(Bs + (wn * 64 + nt * 16 + llo) * 32 + lhi * 8);
        #pragma unroll
        for (int mt = 0; mt < 4; ++mt)
            #pragma unroll
            for (int nt = 0; nt < 4; ++nt)
                acc[mt][nt] = __builtin_amdgcn_mfma_f32_16x16x32_bf16(af[mt], bfr[nt], acc[mt][nt], 0, 0, 0);
    }
}

// ---------------- GEMM 1: qkv = x @ w_qkv + b, scatter to Qp/Kp/Vt ----------------

__global__ __launch_bounds__(256) void gemm_qkv_kernel(
    const __bf16* __restrict__ xb, const __bf16* __restrict__ wqkvT,
    const float* __restrict__ b_qkv,
    __bf16* __restrict__ Qp, __bf16* __restrict__ Kp, __bf16* __restrict__ Vt)
{
    __shared__ __bf16 smem[8192];
    f32x4 acc[4][4];
    #pragma unroll
    for (int i = 0; i < 4; ++i)
        #pragma unroll
        for (int j = 0; j < 4; ++j) acc[i][j] = (f32x4){0.f, 0.f, 0.f, 0.f};

    long rowA0 = (long)blockIdx.x * 128, rowB0 = (long)blockIdx.y * 128;
    gemm_mainloop(xb, wqkvT, HID, HID, HID, rowA0, rowB0, smem, smem + 4096, acc);

    const int wave = threadIdx.x >> 6, lane = threadIdx.x & 63;
    const int wm = wave >> 1, wn = wave & 1, lhi = lane >> 4, llo = lane & 15;

    #pragma unroll
    for (int nt = 0; nt < 4; ++nt) {
        #pragma unroll
        for (int mt = 0; mt < 4; ++mt) {
            int n   = (int)rowB0 + wn * 64 + nt * 16 + llo;   // 0..3455
            int sec = n / HID;
            int nn  = n - sec * HID;
            int h   = nn / HD;
            int d   = nn - h * HD;
            float bias = b_qkv[n];
            #pragma unroll
            for (int r = 0; r < 4; ++r) {
                int m = (int)rowA0 + wm * 64 + mt * 16 + lhi * 4 + r;  // 0..4095
                float v = acc[mt][nt][r] + bias;
                int bb = m >> 10, nq = m & 1023;
                long bhn = (long)(bb * NH + h) * NSEQ + nq;
                if (sec == 0)      Qp[bhn * DP + d] = (__bf16)(v * QSCALE);
                else if (sec == 1) Kp[bhn * DP + d] = (__bf16)v;
                else               Vt[((long)(bb * NH + h) * DP + d) * NSEQ + nq] = (__bf16)v;
            }
        }
    }
}

// ---------------- flash attention v3 ----------------
// grid (8 qpairs, 64 bh), 256 threads = 4 waves; each wave owns TWO 16-row
// q-tiles (q0a, q0b=q0a+64) so every K/V LDS fragment feeds 2 MFMAs.
// Double-buffered K/V LDS -> ONE barrier per iteration; staging ds_writes to
// the idle buffer overlap other waves' compute. T14 reg-staged prefetch,
// T5 setprio around MFMA clusters, exp2-domain online softmax (lane-local rows
// via swapped QK^T).

__global__ __launch_bounds__(256) void flash_kernel(
    const __bf16* __restrict__ Qp, const __bf16* __restrict__ Kp,
    const __bf16* __restrict__ Vt, __bf16* __restrict__ atto)
{
    __shared__ char lds[65536];
    // Ks[2] @ 0,12288 ; Vs[2] @ 24576,36864 ; P @ 49152 + wave*4096 (a), +2048 (b)

    const int bh   = blockIdx.y;
    const int tid  = threadIdx.x;
    const int wave = tid >> 6, lane = tid & 63;
    const int lhi = lane >> 4, llo = lane & 15;

    const __bf16* Qb = Qp + (long)bh * NSEQ * DP;
    const __bf16* Kb = Kp + (long)bh * NSEQ * DP;
    const __bf16* Vb = Vt + (long)bh * DP * NSEQ;

    char* Pa = lds + 49152 + wave * 4096;
    char* Pb = Pa + 2048;

    const int q0a = blockIdx.x * 128 + wave * 16;
    const int q0b = q0a + 64;

    // staging assignment: 3 x 16B chunks per thread for each of K and V
    const __bf16* kG[3]; const __bf16* vG[3];
    int kL[3], vL[3];
    #pragma unroll
    for (int i = 0; i < 3; ++i) {
        int c = tid + i * 256;                    // 0..767
        int key = c / 12, part = c - key * 12;    // K: 64 rows x 12 chunks
        kL[i] = (key * 192 + part * 16) ^ ((key & 7) << 4);
        kG[i] = Kb + key * DP + part * 8;
        int dv = c >> 3, k8 = c & 7;              // V: 96 rows x 8 chunks
        vL[i] = (dv * 128 + k8 * 16) ^ ((dv & 7) << 4);
        vG[i] = Vb + dv * NSEQ + k8 * 8;
    }

    // Q fragments (B operand): Q[q=llo][d = dc*32 + lhi*8 + j]; QSCALE folded
    bf16x8 aqa[3], aqb[3];
    #pragma unroll
    for (int dc = 0; dc < 3; ++dc) {
        aqa[dc] = *(const bf16x8*)(Qb + (long)(q0a + llo) * DP + dc * 32 + lhi * 8);
        aqb[dc] = *(const bf16x8*)(Qb + (long)(q0b + llo) * DP + dc * 32 + lhi * 8);
    }

    float mra = -3.0e38f, lra = 0.f;   // per-lane state for q = q0a + llo
    float mrb = -3.0e38f, lrb = 0.f;   // per-lane state for q = q0b + llo
    f32x4 accA[5], accB[5];
    #pragma unroll
    for (int t = 0; t < 5; ++t) {
        accA[t] = (f32x4){0.f, 0.f, 0.f, 0.f};
        accB[t] = (f32x4){0.f, 0.f, 0.f, 0.f};
    }

    // prologue: stage tile 0 into buffer 0
    uint4 rK[3], rV[3];
    #pragma unroll
    for (int i = 0; i < 3; ++i) { rK[i] = *(const uint4*)kG[i]; rV[i] = *(const uint4*)vG[i]; }
    #pragma unroll
    for (int i = 0; i < 3; ++i) {
        *(uint4*)(lds + kL[i]) = rK[i];
        *(uint4*)(lds + 24576 + vL[i]) = rV[i];
    }
    __syncthreads();

    #pragma unroll 1
    for (int kb = 0; kb < 16; ++kb) {
        // T14: issue next-tile global loads; they land during this tile's compute
        if (kb < 15) {
            #pragma unroll
            for (int i = 0; i < 3; ++i) {
                rK[i] = *(const uint4*)(kG[i] + (kb + 1) * 64 * DP);
                rV[i] = *(const uint4*)(vG[i] + (kb + 1) * 64);
            }
        }
        char* Ks = lds + ((kb & 1) ? 12288 : 0);
        char* Vs = lds + 24576 + ((kb & 1) ? 12288 : 0);

        // S^T = mfma(K, Q) for both q-sets: each K frag feeds 2 MFMAs
        f32x4 sa[4], sb[4];
        __builtin_amdgcn_s_setprio(1);
        #pragma unroll
        for (int ct = 0; ct < 4; ++ct) {
            f32x4 za = (f32x4){0.f, 0.f, 0.f, 0.f};
            f32x4 zb = (f32x4){0.f, 0.f, 0.f, 0.f};
            #pragma unroll
            for (int dc = 0; dc < 3; ++dc) {
                bf16x8 kf = *(const bf16x8*)(Ks +
                    (((ct * 16 + llo) * 192 + dc * 64 + lhi * 16) ^ ((llo & 7) << 4)));
                za = __builtin_amdgcn_mfma_f32_16x16x32_bf16(kf, aqa[dc], za, 0, 0, 0);
                zb = __builtin_amdgcn_mfma_f32_16x16x32_bf16(kf, aqb[dc], zb, 0, 0, 0);
            }
            sa[ct] = za; sb[ct] = zb;
        }
        __builtin_amdgcn_s_setprio(0);

        // ---- online softmax set A (exp2 domain, lane-local row q=llo) ----
        {
            float m0 = fmaxf(fmaxf(sa[0][0], sa[0][1]), fmaxf(sa[0][2], sa[0][3]));
            float m1 = fmaxf(fmaxf(sa[1][0], sa[1][1]), fmaxf(sa[1][2], sa[1][3]));
            float m2 = fmaxf(fmaxf(sa[2][0], sa[2][1]), fmaxf(sa[2][2], sa[2][3]));
            float m3 = fmaxf(fmaxf(sa[3][0], sa[3][1]), fmaxf(sa[3][2], sa[3][3]));
            float mx = fmaxf(fmaxf(m0, m1), fmaxf(m2, m3));
            mx = fmaxf(mx, __shfl_xor(mx, 16, 64));
            mx = fmaxf(mx, __shfl_xor(mx, 32, 64));
            float mn = fmaxf(mra, mx);
            float al = exp2f(mra - mn);
            mra = mn;
            float p[4][4]; float sm = 0.f;
            #pragma unroll
            for (int ct = 0; ct < 4; ++ct)
                #pragma unroll
                for (int r = 0; r < 4; ++r) { p[ct][r] = exp2f(sa[ct][r] - mn); sm += p[ct][r]; }
            sm += __shfl_xor(sm, 16, 64);
            sm += __shfl_xor(sm, 32, 64);
            lra = lra * al + sm;
            float alq[4];
            #pragma unroll
            for (int r = 0; r < 4; ++r) alq[r] = __shfl(al, lhi * 4 + r, 64);
            #pragma unroll
            for (int t = 0; t < 5; ++t)
                #pragma unroll
                for (int r = 0; r < 4; ++r) accA[t][r] *= alq[r];
            #pragma unroll
            for (int ct = 0; ct < 4; ++ct) {
                bf16x4 pk = { (__bf16)p[ct][0], (__bf16)p[ct][1], (__bf16)p[ct][2], (__bf16)p[ct][3] };
                *(bf16x4*)(Pa + ((llo * 128 + ct * 32 + lhi * 8) ^ ((llo & 7) << 4))) = pk;
            }
        }
        // ---- online softmax set B ----
        {
            float m0 = fmaxf(fmaxf(sb[0][0], sb[0][1]), fmaxf(sb[0][2], sb[0][3]));
            float m1 = fmaxf(fmaxf(sb[1][0], sb[1][1]), fmaxf(sb[1][2], sb[1][3]));
            float m2 = fmaxf(fmaxf(sb[2][0], sb[2][1]), fmaxf(sb[2][2], sb[2][3]));
            float m3 = fmaxf(fmaxf(sb[3][0], sb[3][1]), fmaxf(sb[3][2], sb[3][3]));
            float mx = fmaxf(fmaxf(m0, m1), fmaxf(m2, m3));
            mx = fmaxf(mx, __shfl_xor(mx, 16, 64));
            mx = fmaxf(mx, __shfl_xor(mx, 32, 64));
            float mn = fmaxf(mrb, mx);
            float al = exp2f(mrb - mn);
            mrb = mn;
            float p[4][4]; float sm = 0.f;
            #pragma unroll
            for (int ct = 0; ct < 4; ++ct)
                #pragma unroll
                for (int r = 0; r < 4; ++r) { p[ct][r] = exp2f(sb[ct][r] - mn); sm += p[ct][r]; }
            sm += __shfl_xor(sm, 16, 64);
            sm += __shfl_xor(sm, 32, 64);
            lrb = lrb * al + sm;
            float alq[4];
            #pragma unroll
            for (int r = 0; r < 4; ++r) alq[r] = __shfl(al, lhi * 4 + r, 64);
            #pragma unroll
            for (int t = 0; t < 5; ++t)
                #pragma unroll
                for (int r = 0; r < 4; ++r) accB[t][r] *= alq[r];
            #pragma unroll
            for (int ct = 0; ct < 4; ++ct) {
                bf16x4 pk = { (__bf16)p[ct][0], (__bf16)p[ct][1], (__bf16)p[ct][2], (__bf16)p[ct][3] };
                *(bf16x4*)(Pb + ((llo * 128 + ct * 32 + lhi * 8) ^ ((llo & 7) << 4))) = pk;
            }
        }
        asm volatile("s_waitcnt lgkmcnt(0)" ::: "memory");

        // PV for both sets: each V frag feeds 2 MFMAs
        __builtin_amdgcn_s_setprio(1);
        #pragma unroll
        for (int nc = 0; nc < 2; ++nc) {
            bf16x8 pA = *(const bf16x8*)(Pa + ((llo * 128 + nc * 64 + lhi * 16) ^ ((llo & 7) << 4)));
            bf16x8 pB = *(const bf16x8*)(Pb + ((llo * 128 + nc * 64 + lhi * 16) ^ ((llo & 7) << 4)));
            #pragma unroll
            for (int t = 0; t < 5; ++t) {
                bf16x8 bv = *(const bf16x8*)(Vs +
                    (((t * 16 + llo) * 128 + nc * 64 + lhi * 16) ^ ((llo & 7) << 4)));
                accA[t] = __builtin_amdgcn_mfma_f32_16x16x32_bf16(pA, bv, accA[t], 0, 0, 0);
                accB[t] = __builtin_amdgcn_mfma_f32_16x16x32_bf16(pB, bv, accB[t], 0, 0, 0);
            }
        }
        __builtin_amdgcn_s_setprio(0);

        // write next tile into the idle buffer (safe: all waves passed the
        // previous iteration's barrier, so nobody still reads it)
        if (kb < 15) {
            char* Kd = lds + ((kb & 1) ? 0 : 12288);
            char* Vd = lds + 24576 + ((kb & 1) ? 12288 : 24576 - 12288);
            Vd = lds + 24576 + ((kb & 1) ? 0 : 12288);
            #pragma unroll
            for (int i = 0; i < 3; ++i) {
                *(uint4*)(Kd + kL[i]) = rK[i];
                *(uint4*)(Vd + vL[i]) = rV[i];
            }
        }
        __syncthreads();
    }

    // epilogue: atto[b*1024+q][h*72+d], q = q0 + lhi*4 + r, d = t*16 + llo
    float linvA[4], linvB[4];
    #pragma unroll
    for (int r = 0; r < 4; ++r) {
        linvA[r] = 1.f / __shfl(lra, lhi * 4 + r, 64);
        linvB[r] = 1.f / __shfl(lrb, lhi * 4 + r, 64);
    }
    const int b = bh >> 4, h = bh & 15;
    #pragma unroll
    for (int t = 0; t < 5; ++t) {
        int d = t * 16 + llo;
        if (d < HD) {
            #pragma unroll
            for (int r = 0; r < 4; ++r) {
                int qa = q0a + lhi * 4 + r;
                int qb = q0b + lhi * 4 + r;
                atto[(long)(b * NSEQ + qa) * HID + h * HD + d] = (__bf16)(accA[t][r] * linvA[r]);
                atto[(long)(b * NSEQ + qb) * HID + h * HD + d] = (__bf16)(accB[t][r] * linvB[r]);
            }
        }
    }
}

// ---------------- GEMM 2: out = atto @ w_out + b_out (fp32 out) ----------------

__global__ __launch_bounds__(256) void gemm_out_kernel(
    const __bf16* __restrict__ atto, const __bf16* __restrict__ woutT,
    const float* __restrict__ b_out, float* __restrict__ out)
{
    __shared__ __bf16 smem[8192];
    f32x4 acc[4][4];
    #pragma unroll
    for (int i = 0; i < 4; ++i)
        #pragma unroll
        for (int j = 0; j < 4; ++j) acc[i][j] = (f32x4){0.f, 0.f, 0.f, 0.f};

    long rowA0 = (long)blockIdx.x * 128, rowB0 = (long)blockIdx.y * 128;
    gemm_mainloop(atto, woutT, HID, HID, HID, rowA0, rowB0, smem, smem + 4096, acc);

    const int wave = threadIdx.x >> 6, lane = threadIdx.x & 63;
    const int wm = wave >> 1, wn = wave & 1, lhi = lane >> 4, llo = lane & 15;

    #pragma unroll
    for (int nt = 0; nt < 4; ++nt) {
        int n = (int)rowB0 + wn * 64 + nt * 16 + llo;
        float bias = b_out[n];
        #pragma unroll
        for (int mt = 0; mt < 4; ++mt) {
            #pragma unroll
            for (int r = 0; r < 4; ++r) {
                int m = (int)rowA0 + wm * 64 + mt * 16 + lhi * 4 + r;
                out[(long)m * HID + n] = acc[mt][nt][r] + bias;
            }
        }
    }
}

// ---------------- launch ----------------

extern "C" void kernel_launch(void* const* d_in, const int* in_sizes, int n_in,
                              void* d_out, int out_size, void* d_ws, size_t ws_size,
                              hipStream_t stream) {
    const float* x      = (const float*)d_in[0];
    const float* w_qkv  = (const float*)d_in[1];
    const float* b_qkv  = (const float*)d_in[2];
    const float* w_out  = (const float*)d_in[3];
    const float* b_out  = (const float*)d_in[4];
    float* out = (float*)d_out;
    char* ws = (char*)d_ws;

    __bf16* xb    = (__bf16*)(ws + XB_OFF);
    __bf16* wqkvT = (__bf16*)(ws + WQKVT_OFF);
    __bf16* woutT = (__bf16*)(ws + WOUTT_OFF);
    __bf16* Qp    = (__bf16*)(ws + QP_OFF);
    __bf16* Kp    = (__bf16*)(ws + KP_OFF);
    __bf16* Vt    = (__bf16*)(ws + VT_OFF);
    __bf16* atto  = (__bf16*)(ws + ATTO_OFF);

    // zero Qp/Kp/Vt (contiguous 37,748,736 B) for the D-padding
    zero_kernel<<<9216, 256, 0, stream>>>((uint4*)(ws + QP_OFF), 37748736L / 16);
    conv_x_kernel<<<4608, 256, 0, stream>>>(x, xb, 1179648L);
    transpose_cvt_kernel<<<dim3(108, 36), dim3(32, 8), 0, stream>>>(w_qkv, wqkvT, HID, QKV3);
    transpose_cvt_kernel<<<dim3(36, 36), dim3(32, 8), 0, stream>>>(w_out, woutT, HID, HID);
    gemm_qkv_kernel<<<dim3(32, 27), 256, 0, stream>>>(xb, wqkvT, b_qkv, Qp, Kp, Vt);
    flash_kernel<<<dim3(8, 64), 256, 0, stream>>>(Qp, Kp, Vt, atto);
    gemm_out_kernel<<<dim3(32, 9), 256, 0, stream>>>(atto, woutT, b_out, out);
}

// Round 4
// 194.526 us; speedup vs baseline: 1.7172x; 1.0201x over previous
//
#include <hip/hip_runtime.h>
#include <cstdint>

// Problem constants
#define NB 4
#define NSEQ 1024
#define NH 16
#define HD 72
#define HID 1152
#define QKV3 3456
#define DP 96           // padded head dim (multiple of 32 for K=32 MFMA)
// scale = 72^-0.5 folded with log2(e) so softmax runs in exp2 domain
#define QSCALE 0.17003713711193175f

typedef __attribute__((ext_vector_type(8))) __bf16 bf16x8;
typedef __attribute__((ext_vector_type(4))) __bf16 bf16x4;
typedef __attribute__((ext_vector_type(4))) float f32x4;

#define AS1 __attribute__((address_space(1)))
#define AS3 __attribute__((address_space(3)))

__device__ __forceinline__ void gl_lds16(const void* g, void* l) {
    // async global->LDS, 16B per lane; LDS dest = wave-uniform base + lane*16
    __builtin_amdgcn_global_load_lds((const AS1 uint32_t*)g, (AS3 uint32_t*)l, 16, 0, 0);
}

// Workspace layout (bytes)
#define XB_OFF     0UL           // x as bf16            [4096][1152]
#define WQKVT_OFF  9437184UL     // w_qkv^T bf16         [3456][1152]
#define WOUTT_OFF  17399808UL    // w_out^T bf16         [1152][1152]
#define QP_OFF     20054016UL    // Q padded bf16        [64][1024][96] (QSCALE folded)
#define KP_OFF     32636928UL    // K padded bf16        [64][1024][96]
#define VT_OFF     45219840UL    // V^T padded bf16      [64][96][1024]
#define ATTO_OFF   57802752UL    // attn out bf16        [4096][1152]

// ---------------- prep kernels ----------------

__global__ void zero_kernel(uint4* __restrict__ p, long n16) {
    long i = (long)blockIdx.x * blockDim.x + threadIdx.x;
    if (i < n16) p[i] = make_uint4(0u, 0u, 0u, 0u);
}

__global__ void conv_x_kernel(const float* __restrict__ in, __bf16* __restrict__ out, long n4) {
    long i = (long)blockIdx.x * blockDim.x + threadIdx.x;
    if (i >= n4) return;
    float4 v = ((const float4*)in)[i];
    bf16x4 o = { (__bf16)v.x, (__bf16)v.y, (__bf16)v.z, (__bf16)v.w };
    ((bf16x4*)out)[i] = o;
}

// in fp32 [K][Nc] row-major -> out bf16 [Nc][K]
__global__ void transpose_cvt_kernel(const float* __restrict__ in, __bf16* __restrict__ out,
                                     int K, int Nc) {
    __shared__ float t[32][33];
    int n0 = blockIdx.x * 32, k0 = blockIdx.y * 32;
    int x = threadIdx.x, y = threadIdx.y;
    #pragma unroll
    for (int i = 0; i < 32; i += 8)
        t[y + i][x] = in[(long)(k0 + y + i) * Nc + n0 + x];
    __syncthreads();
    #pragma unroll
    for (int i = 0; i < 32; i += 8)
        out[(long)(n0 + y + i) * K + k0 + x] = (__bf16)t[x][y + i];
}

// ---------------- GEMM core (128x128 tile, 4 waves 2x2, BK=32) ----------------
// Double-buffered LDS + global_load_lds: stage tile t+1 before computing tile t,
// one vmcnt(0)+barrier per tile (T3-minimum 2-phase). Unrolled x2 so buffer
// pointers are compile-time static. A row-major [M][K], Bt row-major [N][K].
// C-frag: col=lane&15, row=(lane>>4)*4+r.

__device__ __forceinline__ void stage_tile(
    const __bf16* __restrict__ A, const __bf16* __restrict__ Bt,
    int lda, int ldb, long rowA0, long rowB0, int k0,
    __bf16* As, __bf16* Bs, int tid)
{
    const int rr = tid >> 2, kk = (tid & 3) * 8;
    gl_lds16(A  + (rowA0 + rr)      * (long)lda + k0 + kk, As + tid * 8);
    gl_lds16(A  + (rowA0 + rr + 64) * (long)lda + k0 + kk, As + tid * 8 + 2048);
    gl_lds16(Bt + (rowB0 + rr)      * (long)ldb + k0 + kk, Bs + tid * 8);
    gl_lds16(Bt + (rowB0 + rr + 64) * (long)ldb + k0 + kk, Bs + tid * 8 + 2048);
}

__device__ __forceinline__ void compute_tile(
    const __bf16* As, const __bf16* Bs,
    int wm, int wn, int lhi, int llo, f32x4 acc[4][4])
{
    bf16x8 af[4], bfr[4];
    #pragma unroll
    for (int mt = 0; mt < 4; ++mt)
        af[mt] = *(const bf16x8*)(As + (wm * 64 + mt * 16 + llo) * 32 + lhi * 8);
    #pragma unroll
    for (int nt = 0; nt < 4; ++nt)
        bfr[nt] = *(const bf16x8*)(Bs + (wn * 64 + nt * 16 + llo) * 32 + lhi * 8);
    #pragma unroll
    for (int mt = 0; mt < 4; ++mt)
        #pragma unroll
        for (int nt = 0; nt < 4; ++nt)
            acc[mt][nt] = __builtin_amdgcn_mfma_f32_16x16x32_bf16(af[mt], bfr[nt], acc[mt][nt], 0, 0, 0);
}

__device__ __forceinline__ void gemm_mainloop(
    const __bf16* __restrict__ A, const __bf16* __restrict__ Bt,
    int lda, int ldb, int K, long rowA0, long rowB0,
    __bf16* lds, f32x4 acc[4][4])
{
    const int tid  = threadIdx.x;
    const int lane = tid & 63, wave = tid >> 6;
    const int wm = wave >> 1, wn = wave & 1;
    const int lhi = lane >> 4, llo = lane & 15;
    __bf16* A0 = lds;           __bf16* B0 = lds + 4096;
    __bf16* A1 = lds + 8192;    __bf16* B1 = lds + 12288;

    stage_tile(A, Bt, lda, ldb, rowA0, rowB0, 0, A0, B0, tid);
    asm volatile("s_waitcnt vmcnt(0)" ::: "memory");
    __syncthreads();

    const int ntk = K / 32;   // 36 for K=1152 (even)
    for (int t = 0; t < ntk; t += 2) {
        if (t + 1 < ntk)
            stage_tile(A, Bt, lda, ldb, rowA0, rowB0, (t + 1) * 32, A1, B1, tid);
        compute_tile(A0, B0, wm, wn, lhi, llo, acc);
        asm volatile("s_waitcnt vmcnt(0)" ::: "memory");
        __syncthreads();
        if (t + 1 < ntk) {
            if (t + 2 < ntk)
                stage_tile(A, Bt, lda, ldb, rowA0, rowB0, (t + 2) * 32, A0, B0, tid);
            compute_tile(A1, B1, wm, wn, lhi, llo, acc);
            asm volatile("s_waitcnt vmcnt(0)" ::: "memory");
            __syncthreads();
        }
    }
}

// ---------------- GEMM 1: qkv = x @ w_qkv + b, scatter to Qp/Kp/Vt ----------------

__global__ __launch_bounds__(256) void gemm_qkv_kernel(
    const __bf16* __restrict__ xb, const __bf16* __restrict__ wqkvT,
    const float* __restrict__ b_qkv,
    __bf16* __restrict__ Qp, __bf16* __restrict__ Kp, __bf16* __restrict__ Vt)
{
    __shared__ __bf16 smem[16384];
    f32x4 acc[4][4];
    #pragma unroll
    for (int i = 0; i < 4; ++i)
        #pragma unroll
        for (int j = 0; j < 4; ++j) acc[i][j] = (f32x4){0.f, 0.f, 0.f, 0.f};

    // bijective chunked XCD swizzle: 864 blocks, XCD i gets v in [i*108,(i+1)*108)
    // decode y-fastest so each XCD keeps 4 A-panels hot in its L2
    int lin = blockIdx.x + blockIdx.y * 32;
    int v   = (lin & 7) * 108 + (lin >> 3);
    int bxn = v / 27, byn = v - bxn * 27;
    long rowA0 = (long)bxn * 128, rowB0 = (long)byn * 128;
    gemm_mainloop(xb, wqkvT, HID, HID, HID, rowA0, rowB0, smem, acc);

    const int wave = threadIdx.x >> 6, lane = threadIdx.x & 63;
    const int wm = wave >> 1, wn = wave & 1, lhi = lane >> 4, llo = lane & 15;

    #pragma unroll
    for (int nt = 0; nt < 4; ++nt) {
        #pragma unroll
        for (int mt = 0; mt < 4; ++mt) {
            int n   = (int)rowB0 + wn * 64 + nt * 16 + llo;   // 0..3455
            int sec = n / HID;
            int nn  = n - sec * HID;
            int h   = nn / HD;
            int d   = nn - h * HD;
            float bias = b_qkv[n];
            #pragma unroll
            for (int r = 0; r < 4; ++r) {
                int m = (int)rowA0 + wm * 64 + mt * 16 + lhi * 4 + r;  // 0..4095
                float v2 = acc[mt][nt][r] + bias;
                int bb = m >> 10, nq = m & 1023;
                long bhn = (long)(bb * NH + h) * NSEQ + nq;
                if (sec == 0)      Qp[bhn * DP + d] = (__bf16)(v2 * QSCALE);
                else if (sec == 1) Kp[bhn * DP + d] = (__bf16)v2;
                else               Vt[((long)(bb * NH + h) * DP + d) * NSEQ + nq] = (__bf16)v2;
            }
        }
    }
}

// ---------------- flash attention v4 ----------------
// grid 512 blocks; chunked XCD swizzle puts all 8 q-chunk blocks of a head on
// ONE XCD (8 heads/XCD, K+V 3.1MB < 4MB L2) -> K/V refetch served from L2.
// Each wave owns TWO 16-row q-tiles; double-buffered K/V LDS, one barrier/iter;
// T14 reg-staged prefetch; T5 setprio; exp2-domain lane-local online softmax.

__global__ __launch_bounds__(256) void flash_kernel(
    const __bf16* __restrict__ Qp, const __bf16* __restrict__ Kp,
    const __bf16* __restrict__ Vt, __bf16* __restrict__ atto)
{
    __shared__ char lds[65536];
    // Ks[2] @ 0,12288 ; Vs[2] @ 24576,36864 ; P @ 49152 + wave*4096 (a), +2048 (b)

    const int tid  = threadIdx.x;
    const int wave = tid >> 6, lane = tid & 63;
    const int lhi = lane >> 4, llo = lane & 15;

    // chunked XCD swizzle (512 = 8 XCD x 64): XCD i owns bh in [i*8,(i+1)*8)
    int lin = blockIdx.x + (blockIdx.y << 3);
    int v   = ((lin & 7) << 6) + (lin >> 3);
    const int qx = v & 7;
    const int bh = v >> 3;

    const __bf16* Qb = Qp + (long)bh * NSEQ * DP;
    const __bf16* Kb = Kp + (long)bh * NSEQ * DP;
    const __bf16* Vb = Vt + (long)bh * DP * NSEQ;

    char* Pa = lds + 49152 + wave * 4096;
    char* Pb = Pa + 2048;

    const int q0a = qx * 128 + wave * 16;
    const int q0b = q0a + 64;

    // staging assignment: 3 x 16B chunks per thread for each of K and V
    const __bf16* kG[3]; const __bf16* vG[3];
    int kL[3], vL[3];
    #pragma unroll
    for (int i = 0; i < 3; ++i) {
        int c = tid + i * 256;                    // 0..767
        int key = c / 12, part = c - key * 12;    // K: 64 rows x 12 chunks
        kL[i] = (key * 192 + part * 16) ^ ((key & 7) << 4);
        kG[i] = Kb + key * DP + part * 8;
        int dv = c >> 3, k8 = c & 7;              // V: 96 rows x 8 chunks
        vL[i] = (dv * 128 + k8 * 16) ^ ((dv & 7) << 4);
        vG[i] = Vb + dv * NSEQ + k8 * 8;
    }

    // Q fragments (B operand): Q[q=llo][d = dc*32 + lhi*8 + j]; QSCALE folded
    bf16x8 aqa[3], aqb[3];
    #pragma unroll
    for (int dc = 0; dc < 3; ++dc) {
        aqa[dc] = *(const bf16x8*)(Qb + (long)(q0a + llo) * DP + dc * 32 + lhi * 8);
        aqb[dc] = *(const bf16x8*)(Qb + (long)(q0b + llo) * DP + dc * 32 + lhi * 8);
    }

    float mra = -3.0e38f, lra = 0.f;   // per-lane state for q = q0a + llo
    float mrb = -3.0e38f, lrb = 0.f;   // per-lane state for q = q0b + llo
    f32x4 accA[5], accB[5];
    #pragma unroll
    for (int t = 0; t < 5; ++t) {
        accA[t] = (f32x4){0.f, 0.f, 0.f, 0.f};
        accB[t] = (f32x4){0.f, 0.f, 0.f, 0.f};
    }

    // prologue: stage tile 0 into buffer 0
    uint4 rK[3], rV[3];
    #pragma unroll
    for (int i = 0; i < 3; ++i) { rK[i] = *(const uint4*)kG[i]; rV[i] = *(const uint4*)vG[i]; }
    #pragma unroll
    for (int i = 0; i < 3; ++i) {
        *(uint4*)(lds + kL[i]) = rK[i];
        *(uint4*)(lds + 24576 + vL[i]) = rV[i];
    }
    __syncthreads();

    #pragma unroll 1
    for (int kb = 0; kb < 16; ++kb) {
        // T14: issue next-tile global loads; they land during this tile's compute
        if (kb < 15) {
            #pragma unroll
            for (int i = 0; i < 3; ++i) {
                rK[i] = *(const uint4*)(kG[i] + (kb + 1) * 64 * DP);
                rV[i] = *(const uint4*)(vG[i] + (kb + 1) * 64);
            }
        }
        char* Ks = lds + ((kb & 1) ? 12288 : 0);
        char* Vs = lds + 24576 + ((kb & 1) ? 12288 : 0);

        // S^T = mfma(K, Q) for both q-sets: each K frag feeds 2 MFMAs
        f32x4 sa[4], sb[4];
        __builtin_amdgcn_s_setprio(1);
        #pragma unroll
        for (int ct = 0; ct < 4; ++ct) {
            f32x4 za = (f32x4){0.f, 0.f, 0.f, 0.f};
            f32x4 zb = (f32x4){0.f, 0.f, 0.f, 0.f};
            #pragma unroll
            for (int dc = 0; dc < 3; ++dc) {
                bf16x8 kf = *(const bf16x8*)(Ks +
                    (((ct * 16 + llo) * 192 + dc * 64 + lhi * 16) ^ ((llo & 7) << 4)));
                za = __builtin_amdgcn_mfma_f32_16x16x32_bf16(kf, aqa[dc], za, 0, 0, 0);
                zb = __builtin_amdgcn_mfma_f32_16x16x32_bf16(kf, aqb[dc], zb, 0, 0, 0);
            }
            sa[ct] = za; sb[ct] = zb;
        }
        __builtin_amdgcn_s_setprio(0);

        // ---- online softmax set A (exp2 domain, lane-local row q=llo) ----
        {
            float m0 = fmaxf(fmaxf(sa[0][0], sa[0][1]), fmaxf(sa[0][2], sa[0][3]));
            float m1 = fmaxf(fmaxf(sa[1][0], sa[1][1]), fmaxf(sa[1][2], sa[1][3]));
            float m2 = fmaxf(fmaxf(sa[2][0], sa[2][1]), fmaxf(sa[2][2], sa[2][3]));
            float m3 = fmaxf(fmaxf(sa[3][0], sa[3][1]), fmaxf(sa[3][2], sa[3][3]));
            float mx = fmaxf(fmaxf(m0, m1), fmaxf(m2, m3));
            mx = fmaxf(mx, __shfl_xor(mx, 16, 64));
            mx = fmaxf(mx, __shfl_xor(mx, 32, 64));
            float mn = fmaxf(mra, mx);
            float al = exp2f(mra - mn);
            mra = mn;
            float p[4][4]; float sm = 0.f;
            #pragma unroll
            for (int ct = 0; ct < 4; ++ct)
                #pragma unroll
                for (int r = 0; r < 4; ++r) { p[ct][r] = exp2f(sa[ct][r] - mn); sm += p[ct][r]; }
            sm += __shfl_xor(sm, 16, 64);
            sm += __shfl_xor(sm, 32, 64);
            lra = lra * al + sm;
            float alq[4];
            #pragma unroll
            for (int r = 0; r < 4; ++r) alq[r] = __shfl(al, lhi * 4 + r, 64);
            #pragma unroll
            for (int t = 0; t < 5; ++t)
                #pragma unroll
                for (int r = 0; r < 4; ++r) accA[t][r] *= alq[r];
            #pragma unroll
            for (int ct = 0; ct < 4; ++ct) {
                bf16x4 pk = { (__bf16)p[ct][0], (__bf16)p[ct][1], (__bf16)p[ct][2], (__bf16)p[ct][3] };
                *(bf16x4*)(Pa + ((llo * 128 + ct * 32 + lhi * 8) ^ ((llo & 7) << 4))) = pk;
            }
        }
        // ---- online softmax set B ----
        {
            float m0 = fmaxf(fmaxf(sb[0][0], sb[0][1]), fmaxf(sb[0][2], sb[0][3]));
            float m1 = fmaxf(fmaxf(sb[1][0], sb[1][1]), fmaxf(sb[1][2], sb[1][3]));
            float m2 = fmaxf(fmaxf(sb[2][0], sb[2][1]), fmaxf(sb[2][2], sb[2][3]));
            float m3 = fmaxf(fmaxf(sb[3][0], sb[3][1]), fmaxf(sb[3][2], sb[3][3]));
            float mx = fmaxf(fmaxf(m0, m1), fmaxf(m2, m3));
            mx = fmaxf(mx, __shfl_xor(mx, 16, 64));
            mx = fmaxf(mx, __shfl_xor(mx, 32, 64));
            float mn = fmaxf(mrb, mx);
            float al = exp2f(mrb - mn);
            mrb = mn;
            float p[4][4]; float sm = 0.f;
            #pragma unroll
            for (int ct = 0; ct < 4; ++ct)
                #pragma unroll
                for (int r = 0; r < 4; ++r) { p[ct][r] = exp2f(sb[ct][r] - mn); sm += p[ct][r]; }
            sm += __shfl_xor(sm, 16, 64);
            sm += __shfl_xor(sm, 32, 64);
            lrb = lrb * al + sm;
            float alq[4];
            #pragma unroll
            for (int r = 0; r < 4; ++r) alq[r] = __shfl(al, lhi * 4 + r, 64);
            #pragma unroll
            for (int t = 0; t < 5; ++t)
                #pragma unroll
                for (int r = 0; r < 4; ++r) accB[t][r] *= alq[r];
            #pragma unroll
            for (int ct = 0; ct < 4; ++ct) {
                bf16x4 pk = { (__bf16)p[ct][0], (__bf16)p[ct][1], (__bf16)p[ct][2], (__bf16)p[ct][3] };
                *(bf16x4*)(Pb + ((llo * 128 + ct * 32 + lhi * 8) ^ ((llo & 7) << 4))) = pk;
            }
        }
        asm volatile("s_waitcnt lgkmcnt(0)" ::: "memory");

        // PV for both sets: each V frag feeds 2 MFMAs
        __builtin_amdgcn_s_setprio(1);
        #pragma unroll
        for (int nc = 0; nc < 2; ++nc) {
            bf16x8 pA = *(const bf16x8*)(Pa + ((llo * 128 + nc * 64 + lhi * 16) ^ ((llo & 7) << 4)));
            bf16x8 pB = *(const bf16x8*)(Pb + ((llo * 128 + nc * 64 + lhi * 16) ^ ((llo & 7) << 4)));
            #pragma unroll
            for (int t = 0; t < 5; ++t) {
                bf16x8 bv = *(const bf16x8*)(Vs +
                    (((t * 16 + llo) * 128 + nc * 64 + lhi * 16) ^ ((llo & 7) << 4)));
                accA[t] = __builtin_amdgcn_mfma_f32_16x16x32_bf16(pA, bv, accA[t], 0, 0, 0);
                accB[t] = __builtin_amdgcn_mfma_f32_16x16x32_bf16(pB, bv, accB[t], 0, 0, 0);
            }
        }
        __builtin_amdgcn_s_setprio(0);

        // write next tile into the idle buffer (all waves passed the previous
        // barrier, so nobody still reads it)
        if (kb < 15) {
            char* Kd = lds + ((kb & 1) ? 0 : 12288);
            char* Vd = lds + 24576 + ((kb & 1) ? 0 : 12288);
            #pragma unroll
            for (int i = 0; i < 3; ++i) {
                *(uint4*)(Kd + kL[i]) = rK[i];
                *(uint4*)(Vd + vL[i]) = rV[i];
            }
        }
        __syncthreads();
    }

    // epilogue: atto[b*1024+q][h*72+d], q = q0 + lhi*4 + r, d = t*16 + llo
    float linvA[4], linvB[4];
    #pragma unroll
    for (int r = 0; r < 4; ++r) {
        linvA[r] = 1.f / __shfl(lra, lhi * 4 + r, 64);
        linvB[r] = 1.f / __shfl(lrb, lhi * 4 + r, 64);
    }
    const int b = bh >> 4, h = bh & 15;
    #pragma unroll
    for (int t = 0; t < 5; ++t) {
        int d = t * 16 + llo;
        if (d < HD) {
            #pragma unroll
            for (int r = 0; r < 4; ++r) {
                int qa = q0a + lhi * 4 + r;
                int qb = q0b + lhi * 4 + r;
                atto[(long)(b * NSEQ + qa) * HID + h * HD + d] = (__bf16)(accA[t][r] * linvA[r]);
                atto[(long)(b * NSEQ + qb) * HID + h * HD + d] = (__bf16)(accB[t][r] * linvB[r]);
            }
        }
    }
}

// ---------------- GEMM 2: out = atto @ w_out + b_out (fp32 out) ----------------

__global__ __launch_bounds__(256) void gemm_out_kernel(
    const __bf16* __restrict__ atto, const __bf16* __restrict__ woutT,
    const float* __restrict__ b_out, float* __restrict__ out)
{
    __shared__ __bf16 smem[16384];
    f32x4 acc[4][4];
    #pragma unroll
    for (int i = 0; i < 4; ++i)
        #pragma unroll
        for (int j = 0; j < 4; ++j) acc[i][j] = (f32x4){0.f, 0.f, 0.f, 0.f};

    // bijective chunked XCD swizzle: 288 blocks, 36 per XCD (4 bx x 9 by)
    int lin = blockIdx.x + blockIdx.y * 32;
    int v   = (lin & 7) * 36 + (lin >> 3);
    int bxn = v / 9, byn = v - bxn * 9;
    long rowA0 = (long)bxn * 128, rowB0 = (long)byn * 128;
    gemm_mainloop(atto, woutT, HID, HID, HID, rowA0, rowB0, smem, acc);

    const int wave = threadIdx.x >> 6, lane = threadIdx.x & 63;
    const int wm = wave >> 1, wn = wave & 1, lhi = lane >> 4, llo = lane & 15;

    #pragma unroll
    for (int nt = 0; nt < 4; ++nt) {
        int n = (int)rowB0 + wn * 64 + nt * 16 + llo;
        float bias = b_out[n];
        #pragma unroll
        for (int mt = 0; mt < 4; ++mt) {
            #pragma unroll
            for (int r = 0; r < 4; ++r) {
                int m = (int)rowA0 + wm * 64 + mt * 16 + lhi * 4 + r;
                out[(long)m * HID + n] = acc[mt][nt][r] + bias;
            }
        }
    }
}

// ---------------- launch ----------------

extern "C" void kernel_launch(void* const* d_in, const int* in_sizes, int n_in,
                              void* d_out, int out_size, void* d_ws, size_t ws_size,
                              hipStream_t stream) {
    const float* x      = (const float*)d_in[0];
    const float* w_qkv  = (const float*)d_in[1];
    const float* b_qkv  = (const float*)d_in[2];
    const float* w_out  = (const float*)d_in[3];
    const float* b_out  = (const float*)d_in[4];
    float* out = (float*)d_out;
    char* ws = (char*)d_ws;

    __bf16* xb    = (__bf16*)(ws + XB_OFF);
    __bf16* wqkvT = (__bf16*)(ws + WQKVT_OFF);
    __bf16* woutT = (__bf16*)(ws + WOUTT_OFF);
    __bf16* Qp    = (__bf16*)(ws + QP_OFF);
    __bf16* Kp    = (__bf16*)(ws + KP_OFF);
    __bf16* Vt    = (__bf16*)(ws + VT_OFF);
    __bf16* atto  = (__bf16*)(ws + ATTO_OFF);

    // zero Qp/Kp/Vt (contiguous 37,748,736 B) for the D-padding
    zero_kernel<<<9216, 256, 0, stream>>>((uint4*)(ws + QP_OFF), 37748736L / 16);
    conv_x_kernel<<<4608, 256, 0, stream>>>(x, xb, 1179648L);
    transpose_cvt_kernel<<<dim3(108, 36), dim3(32, 8), 0, stream>>>(w_qkv, wqkvT, HID, QKV3);
    transpose_cvt_kernel<<<dim3(36, 36), dim3(32, 8), 0, stream>>>(w_out, woutT, HID, HID);
    gemm_qkv_kernel<<<dim3(32, 27), 256, 0, stream>>>(xb, wqkvT, b_qkv, Qp, Kp, Vt);
    flash_kernel<<<dim3(8, 64), 256, 0, stream>>>(Qp, Kp, Vt, atto);
    gemm_out_kernel<<<dim3(32, 9), 256, 0, stream>>>(atto, woutT, b_out, out);
}

// Round 5
// 186.381 us; speedup vs baseline: 1.7922x; 1.0437x over previous
//
#include <hip/hip_runtime.h>
#include <cstdint>

// Problem constants
#define NB 4
#define NSEQ 1024
#define NH 16
#define HD 72
#define HID 1152
#define QKV3 3456
#define DP 96           // padded head dim (multiple of 32 for K=32 MFMA)
// scale = 72^-0.5 folded with log2(e) so softmax runs in exp2 domain
#define QSCALE 0.17003713711193175f

typedef __attribute__((ext_vector_type(8))) __bf16 bf16x8;
typedef __attribute__((ext_vector_type(4))) __bf16 bf16x4;
typedef __attribute__((ext_vector_type(4))) float f32x4;

#define AS1 __attribute__((address_space(1)))
#define AS3 __attribute__((address_space(3)))

__device__ __forceinline__ void gl_lds16(const void* g, void* l) {
    // async global->LDS, 16B per lane; LDS dest = wave-uniform base + lane*16
    __builtin_amdgcn_global_load_lds((const AS1 uint32_t*)g, (AS3 uint32_t*)l, 16, 0, 0);
}

// raw barrier: no compiler-inserted vmcnt(0) drain (unlike __syncthreads)
#define RAW_BAR() asm volatile("s_barrier" ::: "memory")

// Workspace layout (bytes)
#define XB_OFF     0UL           // x as bf16 [4096][1152]; ALIASED as atto after gemm_qkv
#define WQKVT_OFF  9437184UL     // w_qkv^T bf16  [3584][1152] (rows 3456+ junk, unused)
#define WOUTT_OFF  17694720UL    // w_out^T bf16  [1280][1152] (rows 1152+ junk, unused)
#define QP_OFF     20643840UL    // Q padded bf16 [64][1024][96] (QSCALE folded)
#define KP_OFF     33226752UL    // K padded bf16 [64][1024][96]
#define VT_OFF     45809664UL    // V^T padded bf16 [64][96][1024]
// total: 58,392,576 bytes

// ---------------- prep kernels ----------------

// zero ONLY the d=72..95 pad regions of Qp/Kp/Vt (9.4 MB instead of 37.7 MB)
__global__ void pad_kernel(__bf16* __restrict__ Qp, __bf16* __restrict__ Kp,
                           __bf16* __restrict__ Vt) {
    int i = blockIdx.x * 256 + threadIdx.x;          // grid: 896*256 = 229376 exact
    uint4 z = make_uint4(0u, 0u, 0u, 0u);
    if (i < 131072) {
        __bf16* base = (i & 65536) ? Kp : Qp;
        int row = i & 65535;
        uint4* p = (uint4*)(base + row * 96 + 72);   // 48 B pad per row
        p[0] = z; p[1] = z; p[2] = z;
    } else {
        int j = i - 131072;                          // 0..98303
        int bh = j / 1536, w = j - bh * 1536;        // 24 rows x 1024 = 1536 uint4 per bh
        *((uint4*)(Vt + (long)bh * 98304 + 73728) + w) = z;
    }
}

__global__ void conv_x_kernel(const float* __restrict__ in, __bf16* __restrict__ out, long n4) {
    long i = (long)blockIdx.x * blockDim.x + threadIdx.x;
    if (i >= n4) return;
    float4 v = ((const float4*)in)[i];
    bf16x4 o = { (__bf16)v.x, (__bf16)v.y, (__bf16)v.z, (__bf16)v.w };
    ((bf16x4*)out)[i] = o;
}

// in fp32 [K][Nc] row-major -> out bf16 [Nc][K]
__global__ void transpose_cvt_kernel(const float* __restrict__ in, __bf16* __restrict__ out,
                                     int K, int Nc) {
    __shared__ float t[32][33];
    int n0 = blockIdx.x * 32, k0 = blockIdx.y * 32;
    int x = threadIdx.x, y = threadIdx.y;
    #pragma unroll
    for (int i = 0; i < 32; i += 8)
        t[y + i][x] = in[(long)(k0 + y + i) * Nc + n0 + x];
    __syncthreads();
    #pragma unroll
    for (int i = 0; i < 32; i += 8)
        out[(long)(n0 + y + i) * K + k0 + x] = (__bf16)t[x][y + i];
}

// ---------------- GEMM engine: BM x 256 tile, 8 waves (2M x 4N), BK=32 ----------------
// Triple-buffered LDS, global_load_lds staging 2 tiles ahead, counted vmcnt(L)
// at tile boundary only (never 0 in steady state), raw s_barrier (no drain),
// T2 XOR swizzle (byte ^= ((row>>1)&3)<<4) with pre-swizzled global source,
// T5 setprio around the MFMA clusters.  2 phases per K-tile.
// A row-major [M][K], Bt row-major [N][K]; C-frag: n=llo, m=lhi*4+r.

template<int MT>   // m-fragments per wave; BM = MT*32 (8 -> 256, 4 -> 128)
__device__ __forceinline__ void gemm_core(
    const __bf16* __restrict__ A, const __bf16* __restrict__ Bt,
    int lda, int ldb, int ntk, long rowA0, long rowB0,
    char* lds, f32x4 acc[MT][4])
{
    constexpr int BM    = MT * 32;
    constexpr int ATILE = BM * 64;        // bytes (rows of 64 B)
    constexpr int BTILE = 256 * 64;
    constexpr int TILE  = ATILE + BTILE;
    constexpr int L     = BM / 128 + 2;   // gl_lds per thread per tile

    const int tid  = threadIdx.x;
    const int wave = tid >> 6, lane = tid & 63;
    const int wm = wave >> 2, wn = wave & 3;      // 2 x 4 wave grid
    const int lhi = lane >> 4, llo = lane & 15;
    const int srow = tid >> 2;                    // staging row (0..127)
    const int scol = (tid & 3) * 8;               // staging col element

    auto stage = [&](int kt, int buf) {
        char* base = lds + buf * TILE;
        #pragma unroll
        for (int j = 0; j < BM / 128; ++j) {
            int r  = srow + j * 128;
            int ks = scol ^ ((((unsigned)r >> 1) & 3) << 3);   // pre-swizzled source
            gl_lds16(A + (rowA0 + r) * (long)lda + kt * 32 + ks, base + tid * 16 + j * 8192);
        }
        #pragma unroll
        for (int j = 0; j < 2; ++j) {
            int r  = srow + j * 128;
            int ks = scol ^ ((((unsigned)r >> 1) & 3) << 3);
            gl_lds16(Bt + (rowB0 + r) * (long)ldb + kt * 32 + ks,
                     base + ATILE + tid * 16 + j * 8192);
        }
    };

    stage(0, 0);
    stage(1, 1);
    asm volatile("s_waitcnt vmcnt(%0)" :: "n"(L) : "memory");   // tile0 landed
    RAW_BAR();

    int buf = 0;
    #pragma unroll 1
    for (int t = 0; t < ntk; ++t) {
        char* Ab = lds + buf * TILE;
        char* Bb = Ab + ATILE;
        int nb = buf + 2; if (nb >= 3) nb -= 3;
        if (t + 2 < ntk) stage(t + 2, nb);        // T14: issue 2 tiles ahead

        // B fragments (held across both phases)
        bf16x8 bfr[4];
        #pragma unroll
        for (int nt = 0; nt < 4; ++nt) {
            int R = wn * 64 + nt * 16 + llo;
            int b = (R * 64 + lhi * 16) ^ ((((unsigned)R >> 1) & 3) << 4);
            bfr[nt] = *(const bf16x8*)(Bb + b);
        }
        // ---- phase 0: A frags mt 0..MT/2-1 ----
        bf16x8 af[MT / 2];
        #pragma unroll
        for (int mt = 0; mt < MT / 2; ++mt) {
            int R = wm * (BM / 2) + mt * 16 + llo;
            int b = (R * 64 + lhi * 16) ^ ((((unsigned)R >> 1) & 3) << 4);
            af[mt] = *(const bf16x8*)(Ab + b);
        }
        __builtin_amdgcn_s_setprio(1);
        #pragma unroll
        for (int mt = 0; mt < MT / 2; ++mt)
            #pragma unroll
            for (int nt = 0; nt < 4; ++nt)
                acc[mt][nt] = __builtin_amdgcn_mfma_f32_16x16x32_bf16(af[mt], bfr[nt], acc[mt][nt], 0, 0, 0);
        __builtin_amdgcn_s_setprio(0);
        RAW_BAR();                                // phase barrier (scheduling)
        // ---- phase 1: A frags mt MT/2..MT-1 ----
        #pragma unroll
        for (int mt = 0; mt < MT / 2; ++mt) {
            int R = wm * (BM / 2) + (MT / 2 + mt) * 16 + llo;
            int b = (R * 64 + lhi * 16) ^ ((((unsigned)R >> 1) & 3) << 4);
            af[mt] = *(const bf16x8*)(Ab + b);
        }
        __builtin_amdgcn_s_setprio(1);
        #pragma unroll
        for (int mt = 0; mt < MT / 2; ++mt)
            #pragma unroll
            for (int nt = 0; nt < 4; ++nt)
                acc[MT / 2 + mt][nt] = __builtin_amdgcn_mfma_f32_16x16x32_bf16(af[mt], bfr[nt], acc[MT / 2 + mt][nt], 0, 0, 0);
        __builtin_amdgcn_s_setprio(0);
        // boundary: next tile (t+1) must be resident; keep t+2's L loads in flight
        if (t + 2 < ntk)      asm volatile("s_waitcnt vmcnt(%0)" :: "n"(L) : "memory");
        else if (t + 1 < ntk) asm volatile("s_waitcnt vmcnt(0)" ::: "memory");
        RAW_BAR();
        buf = (buf == 2) ? 0 : buf + 1;
    }
}

// ---------------- GEMM 1: qkv = x @ w_qkv + b, scatter to Qp/Kp/Vt ----------------
// BM=256: grid 224 blocks (16 M-tiles x 14 N-tiles, N padded 3456->3584)

__global__ __launch_bounds__(512, 2) void gemm_qkv_kernel(
    const __bf16* __restrict__ xb, const __bf16* __restrict__ wqkvT,
    const float* __restrict__ b_qkv,
    __bf16* __restrict__ Qp, __bf16* __restrict__ Kp, __bf16* __restrict__ Vt)
{
    __shared__ char lds[3 * (256 * 64 + 16384)];   // 96 KiB
    f32x4 acc[8][4];
    #pragma unroll
    for (int i = 0; i < 8; ++i)
        #pragma unroll
        for (int j = 0; j < 4; ++j) acc[i][j] = (f32x4){0.f, 0.f, 0.f, 0.f};

    // bijective chunked XCD swizzle: 224 blocks, 28 per XCD (2 bx x 14 by)
    int lin = blockIdx.x;
    int v   = (lin & 7) * 28 + (lin >> 3);
    int bx  = v / 14, by = v - bx * 14;
    long rowA0 = (long)bx * 256, rowB0 = (long)by * 256;

    gemm_core<8>(xb, wqkvT, HID, HID, HID / 32, rowA0, rowB0, lds, acc);

    const int wave = threadIdx.x >> 6, lane = threadIdx.x & 63;
    const int wm = wave >> 2, wn = wave & 3, lhi = lane >> 4, llo = lane & 15;

    #pragma unroll
    for (int nt = 0; nt < 4; ++nt) {
        int n = (int)rowB0 + wn * 64 + nt * 16 + llo;   // 0..3583
        if (n >= QKV3) continue;
        int sec = n / HID;
        int nn  = n - sec * HID;
        int h   = nn / HD;
        int d   = nn - h * HD;
        float bias = b_qkv[n];
        #pragma unroll
        for (int mt = 0; mt < 8; ++mt) {
            #pragma unroll
            for (int r = 0; r < 4; ++r) {
                int m = (int)rowA0 + wm * 128 + mt * 16 + lhi * 4 + r;  // 0..4095
                float vv = acc[mt][nt][r] + bias;
                int bb = m >> 10, nq = m & 1023;
                long bhn = (long)(bb * NH + h) * NSEQ + nq;
                if (sec == 0)      Qp[bhn * DP + d] = (__bf16)(vv * QSCALE);
                else if (sec == 1) Kp[bhn * DP + d] = (__bf16)vv;
                else               Vt[((long)(bb * NH + h) * DP + d) * NSEQ + nq] = (__bf16)vv;
            }
        }
    }
}

// ---------------- flash attention (unchanged from round 4) ----------------

__global__ __launch_bounds__(256) void flash_kernel(
    const __bf16* __restrict__ Qp, const __bf16* __restrict__ Kp,
    const __bf16* __restrict__ Vt, __bf16* __restrict__ atto)
{
    __shared__ char lds[65536];
    const int tid  = threadIdx.x;
    const int wave = tid >> 6, lane = tid & 63;
    const int lhi = lane >> 4, llo = lane & 15;

    // chunked XCD swizzle (512 = 8 XCD x 64): XCD i owns bh in [i*8,(i+1)*8)
    int lin = blockIdx.x + (blockIdx.y << 3);
    int v   = ((lin & 7) << 6) + (lin >> 3);
    const int qx = v & 7;
    const int bh = v >> 3;

    const __bf16* Qb = Qp + (long)bh * NSEQ * DP;
    const __bf16* Kb = Kp + (long)bh * NSEQ * DP;
    const __bf16* Vb = Vt + (long)bh * DP * NSEQ;

    char* Pa = lds + 49152 + wave * 4096;
    char* Pb = Pa + 2048;

    const int q0a = qx * 128 + wave * 16;
    const int q0b = q0a + 64;

    const __bf16* kG[3]; const __bf16* vG[3];
    int kL[3], vL[3];
    #pragma unroll
    for (int i = 0; i < 3; ++i) {
        int c = tid + i * 256;
        int key = c / 12, part = c - key * 12;
        kL[i] = (key * 192 + part * 16) ^ ((key & 7) << 4);
        kG[i] = Kb + key * DP + part * 8;
        int dv = c >> 3, k8 = c & 7;
        vL[i] = (dv * 128 + k8 * 16) ^ ((dv & 7) << 4);
        vG[i] = Vb + dv * NSEQ + k8 * 8;
    }

    bf16x8 aqa[3], aqb[3];
    #pragma unroll
    for (int dc = 0; dc < 3; ++dc) {
        aqa[dc] = *(const bf16x8*)(Qb + (long)(q0a + llo) * DP + dc * 32 + lhi * 8);
        aqb[dc] = *(const bf16x8*)(Qb + (long)(q0b + llo) * DP + dc * 32 + lhi * 8);
    }

    float mra = -3.0e38f, lra = 0.f;
    float mrb = -3.0e38f, lrb = 0.f;
    f32x4 accA[5], accB[5];
    #pragma unroll
    for (int t = 0; t < 5; ++t) {
        accA[t] = (f32x4){0.f, 0.f, 0.f, 0.f};
        accB[t] = (f32x4){0.f, 0.f, 0.f, 0.f};
    }

    uint4 rK[3], rV[3];
    #pragma unroll
    for (int i = 0; i < 3; ++i) { rK[i] = *(const uint4*)kG[i]; rV[i] = *(const uint4*)vG[i]; }
    #pragma unroll
    for (int i = 0; i < 3; ++i) {
        *(uint4*)(lds + kL[i]) = rK[i];
        *(uint4*)(lds + 24576 + vL[i]) = rV[i];
    }
    __syncthreads();

    #pragma unroll 1
    for (int kb = 0; kb < 16; ++kb) {
        if (kb < 15) {
            #pragma unroll
            for (int i = 0; i < 3; ++i) {
                rK[i] = *(const uint4*)(kG[i] + (kb + 1) * 64 * DP);
                rV[i] = *(const uint4*)(vG[i] + (kb + 1) * 64);
            }
        }
        char* Ks = lds + ((kb & 1) ? 12288 : 0);
        char* Vs = lds + 24576 + ((kb & 1) ? 12288 : 0);

        f32x4 sa[4], sb[4];
        __builtin_amdgcn_s_setprio(1);
        #pragma unroll
        for (int ct = 0; ct < 4; ++ct) {
            f32x4 za = (f32x4){0.f, 0.f, 0.f, 0.f};
            f32x4 zb = (f32x4){0.f, 0.f, 0.f, 0.f};
            #pragma unroll
            for (int dc = 0; dc < 3; ++dc) {
                bf16x8 kf = *(const bf16x8*)(Ks +
                    (((ct * 16 + llo) * 192 + dc * 64 + lhi * 16) ^ ((llo & 7) << 4)));
                za = __builtin_amdgcn_mfma_f32_16x16x32_bf16(kf, aqa[dc], za, 0, 0, 0);
                zb = __builtin_amdgcn_mfma_f32_16x16x32_bf16(kf, aqb[dc], zb, 0, 0, 0);
            }
            sa[ct] = za; sb[ct] = zb;
        }
        __builtin_amdgcn_s_setprio(0);

        {
            float m0 = fmaxf(fmaxf(sa[0][0], sa[0][1]), fmaxf(sa[0][2], sa[0][3]));
            float m1 = fmaxf(fmaxf(sa[1][0], sa[1][1]), fmaxf(sa[1][2], sa[1][3]));
            float m2 = fmaxf(fmaxf(sa[2][0], sa[2][1]), fmaxf(sa[2][2], sa[2][3]));
            float m3 = fmaxf(fmaxf(sa[3][0], sa[3][1]), fmaxf(sa[3][2], sa[3][3]));
            float mx = fmaxf(fmaxf(m0, m1), fmaxf(m2, m3));
            mx = fmaxf(mx, __shfl_xor(mx, 16, 64));
            mx = fmaxf(mx, __shfl_xor(mx, 32, 64));
            float mn = fmaxf(mra, mx);
            float al = exp2f(mra - mn);
            mra = mn;
            float p[4][4]; float sm = 0.f;
            #pragma unroll
            for (int ct = 0; ct < 4; ++ct)
                #pragma unroll
                for (int r = 0; r < 4; ++r) { p[ct][r] = exp2f(sa[ct][r] - mn); sm += p[ct][r]; }
            sm += __shfl_xor(sm, 16, 64);
            sm += __shfl_xor(sm, 32, 64);
            lra = lra * al + sm;
            float alq[4];
            #pragma unroll
            for (int r = 0; r < 4; ++r) alq[r] = __shfl(al, lhi * 4 + r, 64);
            #pragma unroll
            for (int t = 0; t < 5; ++t)
                #pragma unroll
                for (int r = 0; r < 4; ++r) accA[t][r] *= alq[r];
            #pragma unroll
            for (int ct = 0; ct < 4; ++ct) {
                bf16x4 pk = { (__bf16)p[ct][0], (__bf16)p[ct][1], (__bf16)p[ct][2], (__bf16)p[ct][3] };
                *(bf16x4*)(Pa + ((llo * 128 + ct * 32 + lhi * 8) ^ ((llo & 7) << 4))) = pk;
            }
        }
        {
            float m0 = fmaxf(fmaxf(sb[0][0], sb[0][1]), fmaxf(sb[0][2], sb[0][3]));
            float m1 = fmaxf(fmaxf(sb[1][0], sb[1][1]), fmaxf(sb[1][2], sb[1][3]));
            float m2 = fmaxf(fmaxf(sb[2][0], sb[2][1]), fmaxf(sb[2][2], sb[2][3]));
            float m3 = fmaxf(fmaxf(sb[3][0], sb[3][1]), fmaxf(sb[3][2], sb[3][3]));
            float mx = fmaxf(fmaxf(m0, m1), fmaxf(m2, m3));
            mx = fmaxf(mx, __shfl_xor(mx, 16, 64));
            mx = fmaxf(mx, __shfl_xor(mx, 32, 64));
            float mn = fmaxf(mrb, mx);
            float al = exp2f(mrb - mn);
            mrb = mn;
            float p[4][4]; float sm = 0.f;
            #pragma unroll
            for (int ct = 0; ct < 4; ++ct)
                #pragma unroll
                for (int r = 0; r < 4; ++r) { p[ct][r] = exp2f(sb[ct][r] - mn); sm += p[ct][r]; }
            sm += __shfl_xor(sm, 16, 64);
            sm += __shfl_xor(sm, 32, 64);
            lrb = lrb * al + sm;
            float alq[4];
            #pragma unroll
            for (int r = 0; r < 4; ++r) alq[r] = __shfl(al, lhi * 4 + r, 64);
            #pragma unroll
            for (int t = 0; t < 5; ++t)
                #pragma unroll
                for (int r = 0; r < 4; ++r) accB[t][r] *= alq[r];
            #pragma unroll
            for (int ct = 0; ct < 4; ++ct) {
                bf16x4 pk = { (__bf16)p[ct][0], (__bf16)p[ct][1], (__bf16)p[ct][2], (__bf16)p[ct][3] };
                *(bf16x4*)(Pb + ((llo * 128 + ct * 32 + lhi * 8) ^ ((llo & 7) << 4))) = pk;
            }
        }
        asm volatile("s_waitcnt lgkmcnt(0)" ::: "memory");

        __builtin_amdgcn_s_setprio(1);
        #pragma unroll
        for (int nc = 0; nc < 2; ++nc) {
            bf16x8 pA = *(const bf16x8*)(Pa + ((llo * 128 + nc * 64 + lhi * 16) ^ ((llo & 7) << 4)));
            bf16x8 pB = *(const bf16x8*)(Pb + ((llo * 128 + nc * 64 + lhi * 16) ^ ((llo & 7) << 4)));
            #pragma unroll
            for (int t = 0; t < 5; ++t) {
                bf16x8 bv = *(const bf16x8*)(Vs +
                    (((t * 16 + llo) * 128 + nc * 64 + lhi * 16) ^ ((llo & 7) << 4)));
                accA[t] = __builtin_amdgcn_mfma_f32_16x16x32_bf16(pA, bv, accA[t], 0, 0, 0);
                accB[t] = __builtin_amdgcn_mfma_f32_16x16x32_bf16(pB, bv, accB[t], 0, 0, 0);
            }
        }
        __builtin_amdgcn_s_setprio(0);

        if (kb < 15) {
            char* Kd = lds + ((kb & 1) ? 0 : 12288);
            char* Vd = lds + 24576 + ((kb & 1) ? 0 : 12288);
            #pragma unroll
            for (int i = 0; i < 3; ++i) {
                *(uint4*)(Kd + kL[i]) = rK[i];
                *(uint4*)(Vd + vL[i]) = rV[i];
            }
        }
        __syncthreads();
    }

    float linvA[4], linvB[4];
    #pragma unroll
    for (int r = 0; r < 4; ++r) {
        linvA[r] = 1.f / __shfl(lra, lhi * 4 + r, 64);
        linvB[r] = 1.f / __shfl(lrb, lhi * 4 + r, 64);
    }
    const int b = bh >> 4, h = bh & 15;
    #pragma unroll
    for (int t = 0; t < 5; ++t) {
        int d = t * 16 + llo;
        if (d < HD) {
            #pragma unroll
            for (int r = 0; r < 4; ++r) {
                int qa = q0a + lhi * 4 + r;
                int qb = q0b + lhi * 4 + r;
                atto[(long)(b * NSEQ + qa) * HID + h * HD + d] = (__bf16)(accA[t][r] * linvA[r]);
                atto[(long)(b * NSEQ + qb) * HID + h * HD + d] = (__bf16)(accB[t][r] * linvB[r]);
            }
        }
    }
}

// ---------------- GEMM 2: out = atto @ w_out + b_out (fp32 out) ----------------
// BM=128: grid 160 blocks (32 M-tiles x 5 N-tiles, N padded 1152->1280)

__global__ __launch_bounds__(512, 2) void gemm_out_kernel(
    const __bf16* __restrict__ atto, const __bf16* __restrict__ woutT,
    const float* __restrict__ b_out, float* __restrict__ out)
{
    __shared__ char lds[3 * (128 * 64 + 16384)];   // 72 KiB
    f32x4 acc[4][4];
    #pragma unroll
    for (int i = 0; i < 4; ++i)
        #pragma unroll
        for (int j = 0; j < 4; ++j) acc[i][j] = (f32x4){0.f, 0.f, 0.f, 0.f};

    // bijective chunked XCD swizzle: 160 blocks, 20 per XCD (4 bx x 5 by)
    int lin = blockIdx.x;
    int v   = (lin & 7) * 20 + (lin >> 3);
    int bx  = v / 5, by = v - bx * 5;
    long rowA0 = (long)bx * 128, rowB0 = (long)by * 256;

    gemm_core<4>(atto, woutT, HID, HID, HID / 32, rowA0, rowB0, lds, acc);

    const int wave = threadIdx.x >> 6, lane = threadIdx.x & 63;
    const int wm = wave >> 2, wn = wave & 3, lhi = lane >> 4, llo = lane & 15;

    #pragma unroll
    for (int nt = 0; nt < 4; ++nt) {
        int n = (int)rowB0 + wn * 64 + nt * 16 + llo;   // 0..1279
        if (n >= HID) continue;
        float bias = b_out[n];
        #pragma unroll
        for (int mt = 0; mt < 4; ++mt) {
            #pragma unroll
            for (int r = 0; r < 4; ++r) {
                int m = (int)rowA0 + wm * 64 + mt * 16 + lhi * 4 + r;
                out[(long)m * HID + n] = acc[mt][nt][r] + bias;
            }
        }
    }
}

// ---------------- launch ----------------

extern "C" void kernel_launch(void* const* d_in, const int* in_sizes, int n_in,
                              void* d_out, int out_size, void* d_ws, size_t ws_size,
                              hipStream_t stream) {
    const float* x      = (const float*)d_in[0];
    const float* w_qkv  = (const float*)d_in[1];
    const float* b_qkv  = (const float*)d_in[2];
    const float* w_out  = (const float*)d_in[3];
    const float* b_out  = (const float*)d_in[4];
    float* out = (float*)d_out;
    char* ws = (char*)d_ws;

    __bf16* xb    = (__bf16*)(ws + XB_OFF);
    __bf16* atto  = (__bf16*)(ws + XB_OFF);     // aliases xb (dead after gemm_qkv)
    __bf16* wqkvT = (__bf16*)(ws + WQKVT_OFF);
    __bf16* woutT = (__bf16*)(ws + WOUTT_OFF);
    __bf16* Qp    = (__bf16*)(ws + QP_OFF);
    __bf16* Kp    = (__bf16*)(ws + KP_OFF);
    __bf16* Vt    = (__bf16*)(ws + VT_OFF);

    pad_kernel<<<896, 256, 0, stream>>>(Qp, Kp, Vt);
    conv_x_kernel<<<4608, 256, 0, stream>>>(x, xb, 1179648L);
    transpose_cvt_kernel<<<dim3(108, 36), dim3(32, 8), 0, stream>>>(w_qkv, wqkvT, HID, QKV3);
    transpose_cvt_kernel<<<dim3(36, 36), dim3(32, 8), 0, stream>>>(w_out, woutT, HID, HID);
    gemm_qkv_kernel<<<224, 512, 0, stream>>>(xb, wqkvT, b_qkv, Qp, Kp, Vt);
    flash_kernel<<<dim3(8, 64), 256, 0, stream>>>(Qp, Kp, Vt, atto);
    gemm_out_kernel<<<160, 512, 0, stream>>>(atto, woutT, b_out, out);
}

// Round 6
// 165.834 us; speedup vs baseline: 2.0143x; 1.1239x over previous
//
#include <hip/hip_runtime.h>
#include <cstdint>

// Problem constants
#define NB 4
#define NSEQ 1024
#define NH 16
#define HD 72
#define HID 1152
#define QKV3 3456
#define DP 96           // padded head dim (multiple of 32 for K=32 MFMA)
// scale = 72^-0.5 folded with log2(e) so softmax runs in exp2 domain
#define QSCALE 0.17003713711193175f

typedef __attribute__((ext_vector_type(8))) __bf16 bf16x8;
typedef __attribute__((ext_vector_type(4))) __bf16 bf16x4;
typedef __attribute__((ext_vector_type(4))) float f32x4;

#define AS1 __attribute__((address_space(1)))
#define AS3 __attribute__((address_space(3)))

__device__ __forceinline__ void gl_lds16(const void* g, void* l) {
    // async global->LDS, 16B per lane; LDS dest = wave-uniform base + lane*16
    __builtin_amdgcn_global_load_lds((const AS1 uint32_t*)g, (AS3 uint32_t*)l, 16, 0, 0);
}

// raw barrier: no compiler-inserted vmcnt(0) drain (unlike __syncthreads)
#define RAW_BAR() asm volatile("s_barrier" ::: "memory")

// Workspace layout (bytes)
#define XB_OFF     0UL           // x as bf16 [4096][1152]; ALIASED as atto after gemm_qkv
#define WQKVT_OFF  9437184UL     // w_qkv^T bf16  [3584][1152] (rows 3456+ junk, unused)
#define WOUTT_OFF  17694720UL    // w_out^T bf16  [1280][1152] (rows 1152+ junk, unused)
#define QP_OFF     20643840UL    // Q padded bf16 [64][1024][96] (QSCALE folded)
#define KP_OFF     33226752UL    // K padded bf16 [64][1024][96]
#define VT_OFF     45809664UL    // V^T padded bf16 [64][96][1024]
// total: 58,392,576 bytes

// ---------------- prep kernels ----------------

// zero ONLY the d=72..95 pad regions of Qp/Kp/Vt (9.4 MB instead of 37.7 MB)
__global__ void pad_kernel(__bf16* __restrict__ Qp, __bf16* __restrict__ Kp,
                           __bf16* __restrict__ Vt) {
    int i = blockIdx.x * 256 + threadIdx.x;          // grid: 896*256 = 229376 exact
    uint4 z = make_uint4(0u, 0u, 0u, 0u);
    if (i < 131072) {
        __bf16* base = (i & 65536) ? Kp : Qp;
        int row = i & 65535;
        uint4* p = (uint4*)(base + row * 96 + 72);   // 48 B pad per row
        p[0] = z; p[1] = z; p[2] = z;
    } else {
        int j = i - 131072;                          // 0..98303
        int bh = j / 1536, w = j - bh * 1536;        // 24 rows x 1024 = 1536 uint4 per bh
        *((uint4*)(Vt + (long)bh * 98304 + 73728) + w) = z;
    }
}

__global__ void conv_x_kernel(const float* __restrict__ in, __bf16* __restrict__ out, long n4) {
    long i = (long)blockIdx.x * blockDim.x + threadIdx.x;
    if (i >= n4) return;
    float4 v = ((const float4*)in)[i];
    bf16x4 o = { (__bf16)v.x, (__bf16)v.y, (__bf16)v.z, (__bf16)v.w };
    ((bf16x4*)out)[i] = o;
}

// in fp32 [K][Nc] row-major -> out bf16 [Nc][K]
__global__ void transpose_cvt_kernel(const float* __restrict__ in, __bf16* __restrict__ out,
                                     int K, int Nc) {
    __shared__ float t[32][33];
    int n0 = blockIdx.x * 32, k0 = blockIdx.y * 32;
    int x = threadIdx.x, y = threadIdx.y;
    #pragma unroll
    for (int i = 0; i < 32; i += 8)
        t[y + i][x] = in[(long)(k0 + y + i) * Nc + n0 + x];
    __syncthreads();
    #pragma unroll
    for (int i = 0; i < 32; i += 8)
        out[(long)(n0 + y + i) * K + k0 + x] = (__bf16)t[x][y + i];
}

// ---------------- GEMM engine: BM x 256 tile, 8 waves (2M x 4N), BK=32 ----------------
// Triple-buffered LDS, global_load_lds staging 2 tiles ahead, counted vmcnt(L)
// at tile boundary only, raw s_barrier (ONE per tile), T2 XOR swizzle with
// pre-swizzled global source, T5 setprio around the MFMA clusters.

template<int MT>   // m-fragments per wave; BM = MT*32 (8 -> 256, 4 -> 128)
__device__ __forceinline__ void gemm_core(
    const __bf16* __restrict__ A, const __bf16* __restrict__ Bt,
    int lda, int ldb, int ntk, long rowA0, long rowB0,
    char* lds, f32x4 acc[MT][4])
{
    constexpr int BM    = MT * 32;
    constexpr int ATILE = BM * 64;        // bytes (rows of 64 B)
    constexpr int BTILE = 256 * 64;
    constexpr int TILE  = ATILE + BTILE;
    constexpr int L     = BM / 128 + 2;   // gl_lds per thread per tile

    const int tid  = threadIdx.x;
    const int wave = tid >> 6, lane = tid & 63;
    const int wm = wave >> 2, wn = wave & 3;      // 2 x 4 wave grid
    const int lhi = lane >> 4, llo = lane & 15;
    const int srow = tid >> 2;                    // staging row (0..127)
    const int scol = (tid & 3) * 8;               // staging col element

    auto stage = [&](int kt, int buf) {
        char* base = lds + buf * TILE;
        #pragma unroll
        for (int j = 0; j < BM / 128; ++j) {
            int r  = srow + j * 128;
            int ks = scol ^ ((((unsigned)r >> 1) & 3) << 3);   // pre-swizzled source
            gl_lds16(A + (rowA0 + r) * (long)lda + kt * 32 + ks, base + tid * 16 + j * 8192);
        }
        #pragma unroll
        for (int j = 0; j < 2; ++j) {
            int r  = srow + j * 128;
            int ks = scol ^ ((((unsigned)r >> 1) & 3) << 3);
            gl_lds16(Bt + (rowB0 + r) * (long)ldb + kt * 32 + ks,
                     base + ATILE + tid * 16 + j * 8192);
        }
    };

    stage(0, 0);
    stage(1, 1);
    asm volatile("s_waitcnt vmcnt(%0)" :: "n"(L) : "memory");   // tile0 landed
    RAW_BAR();

    int buf = 0;
    #pragma unroll 1
    for (int t = 0; t < ntk; ++t) {
        char* Ab = lds + buf * TILE;
        char* Bb = Ab + ATILE;
        int nb = buf + 2; if (nb >= 3) nb -= 3;
        if (t + 2 < ntk) stage(t + 2, nb);        // issue 2 tiles ahead

        // B fragments (held across both halves)
        bf16x8 bfr[4];
        #pragma unroll
        for (int nt = 0; nt < 4; ++nt) {
            int R = wn * 64 + nt * 16 + llo;
            int b = (R * 64 + lhi * 16) ^ ((((unsigned)R >> 1) & 3) << 4);
            bfr[nt] = *(const bf16x8*)(Bb + b);
        }
        // ---- half 0: A frags mt 0..MT/2-1 ----
        bf16x8 af[MT / 2];
        #pragma unroll
        for (int mt = 0; mt < MT / 2; ++mt) {
            int R = wm * (BM / 2) + mt * 16 + llo;
            int b = (R * 64 + lhi * 16) ^ ((((unsigned)R >> 1) & 3) << 4);
            af[mt] = *(const bf16x8*)(Ab + b);
        }
        __builtin_amdgcn_s_setprio(1);
        #pragma unroll
        for (int mt = 0; mt < MT / 2; ++mt)
            #pragma unroll
            for (int nt = 0; nt < 4; ++nt)
                acc[mt][nt] = __builtin_amdgcn_mfma_f32_16x16x32_bf16(af[mt], bfr[nt], acc[mt][nt], 0, 0, 0);
        __builtin_amdgcn_s_setprio(0);
        // ---- half 1: A frags mt MT/2..MT-1 ----
        #pragma unroll
        for (int mt = 0; mt < MT / 2; ++mt) {
            int R = wm * (BM / 2) + (MT / 2 + mt) * 16 + llo;
            int b = (R * 64 + lhi * 16) ^ ((((unsigned)R >> 1) & 3) << 4);
            af[mt] = *(const bf16x8*)(Ab + b);
        }
        __builtin_amdgcn_s_setprio(1);
        #pragma unroll
        for (int mt = 0; mt < MT / 2; ++mt)
            #pragma unroll
            for (int nt = 0; nt < 4; ++nt)
                acc[MT / 2 + mt][nt] = __builtin_amdgcn_mfma_f32_16x16x32_bf16(af[mt], bfr[nt], acc[MT / 2 + mt][nt], 0, 0, 0);
        __builtin_amdgcn_s_setprio(0);
        // boundary: next tile (t+1) must be resident; keep t+2's L loads in flight
        if (t + 2 < ntk)      asm volatile("s_waitcnt vmcnt(%0)" :: "n"(L) : "memory");
        else if (t + 1 < ntk) asm volatile("s_waitcnt vmcnt(0)" ::: "memory");
        RAW_BAR();
        buf = (buf == 2) ? 0 : buf + 1;
    }
}

// ---------------- GEMM 1: qkv = x @ w_qkv + b, scatter to Qp/Kp/Vt ----------------
// BM=256: grid 224 blocks (16 M-tiles x 14 N-tiles, N padded 3456->3584)

__global__ __launch_bounds__(512, 2) void gemm_qkv_kernel(
    const __bf16* __restrict__ xb, const __bf16* __restrict__ wqkvT,
    const float* __restrict__ b_qkv,
    __bf16* __restrict__ Qp, __bf16* __restrict__ Kp, __bf16* __restrict__ Vt)
{
    __shared__ char lds[3 * (256 * 64 + 16384)];   // 96 KiB
    f32x4 acc[8][4];
    #pragma unroll
    for (int i = 0; i < 8; ++i)
        #pragma unroll
        for (int j = 0; j < 4; ++j) acc[i][j] = (f32x4){0.f, 0.f, 0.f, 0.f};

    // bijective chunked XCD swizzle: 224 blocks, 28 per XCD (2 bx x 14 by)
    int lin = blockIdx.x;
    int v   = (lin & 7) * 28 + (lin >> 3);
    int bx  = v / 14, by = v - bx * 14;
    long rowA0 = (long)bx * 256, rowB0 = (long)by * 256;

    gemm_core<8>(xb, wqkvT, HID, HID, HID / 32, rowA0, rowB0, lds, acc);

    const int wave = threadIdx.x >> 6, lane = threadIdx.x & 63;
    const int wm = wave >> 2, wn = wave & 3, lhi = lane >> 4, llo = lane & 15;

    #pragma unroll
    for (int nt = 0; nt < 4; ++nt) {
        int n = (int)rowB0 + wn * 64 + nt * 16 + llo;   // 0..3583
        if (n >= QKV3) continue;
        int sec = n / HID;
        int nn  = n - sec * HID;
        int h   = nn / HD;
        int d   = nn - h * HD;
        float bias = b_qkv[n];
        if (sec == 2) {
            // V: r-quad is nq-contiguous -> one 8B bf16x4 store per mt
            #pragma unroll
            for (int mt = 0; mt < 8; ++mt) {
                int m0 = (int)rowA0 + wm * 128 + mt * 16 + lhi * 4;
                int bb = m0 >> 10, nq0 = m0 & 1023;
                bf16x4 pk = { (__bf16)(acc[mt][nt][0] + bias), (__bf16)(acc[mt][nt][1] + bias),
                              (__bf16)(acc[mt][nt][2] + bias), (__bf16)(acc[mt][nt][3] + bias) };
                *(bf16x4*)(Vt + ((long)(bb * NH + h) * DP + d) * NSEQ + nq0) = pk;
            }
        } else {
            __bf16* dst = (sec == 0) ? Qp : Kp;
            float scl = (sec == 0) ? QSCALE : 1.0f;
            #pragma unroll
            for (int mt = 0; mt < 8; ++mt) {
                #pragma unroll
                for (int r = 0; r < 4; ++r) {
                    int m = (int)rowA0 + wm * 128 + mt * 16 + lhi * 4 + r;
                    int bb = m >> 10, nq = m & 1023;
                    long bhn = (long)(bb * NH + h) * NSEQ + nq;
                    dst[bhn * DP + d] = (__bf16)((acc[mt][nt][r] + bias) * scl);
                }
            }
        }
    }
}

// ---------------- flash attention v5 ----------------
// Flipped PV: mfma(V_frag, P_frag, acc) -> acc[t][r] = O[q=llo][d=t*16+lhi*4+r].
// Softmax state (q=llo) now shares orientation with O: no alq/linv shuffles.
// Defer-max (T13, THR=8): skip rescale while __all(mx <= mrun+8).

__global__ __launch_bounds__(256) void flash_kernel(
    const __bf16* __restrict__ Qp, const __bf16* __restrict__ Kp,
    const __bf16* __restrict__ Vt, __bf16* __restrict__ atto)
{
    __shared__ char lds[65536];
    const int tid  = threadIdx.x;
    const int wave = tid >> 6, lane = tid & 63;
    const int lhi = lane >> 4, llo = lane & 15;

    // chunked XCD swizzle (512 = 8 XCD x 64): XCD i owns bh in [i*8,(i+1)*8)
    int lin = blockIdx.x + (blockIdx.y << 3);
    int v   = ((lin & 7) << 6) + (lin >> 3);
    const int qx = v & 7;
    const int bh = v >> 3;

    const __bf16* Qb = Qp + (long)bh * NSEQ * DP;
    const __bf16* Kb = Kp + (long)bh * NSEQ * DP;
    const __bf16* Vb = Vt + (long)bh * DP * NSEQ;

    char* Pa = lds + 49152 + wave * 4096;
    char* Pb = Pa + 2048;

    const int q0a = qx * 128 + wave * 16;
    const int q0b = q0a + 64;

    const __bf16* kG[3]; const __bf16* vG[3];
    int kL[3], vL[3];
    #pragma unroll
    for (int i = 0; i < 3; ++i) {
        int c = tid + i * 256;
        int key = c / 12, part = c - key * 12;
        kL[i] = (key * 192 + part * 16) ^ ((key & 7) << 4);
        kG[i] = Kb + key * DP + part * 8;
        int dv = c >> 3, k8 = c & 7;
        vL[i] = (dv * 128 + k8 * 16) ^ ((dv & 7) << 4);
        vG[i] = Vb + dv * NSEQ + k8 * 8;
    }

    bf16x8 aqa[3], aqb[3];
    #pragma unroll
    for (int dc = 0; dc < 3; ++dc) {
        aqa[dc] = *(const bf16x8*)(Qb + (long)(q0a + llo) * DP + dc * 32 + lhi * 8);
        aqb[dc] = *(const bf16x8*)(Qb + (long)(q0b + llo) * DP + dc * 32 + lhi * 8);
    }

    float mra = -3.0e38f, lra = 0.f;   // per-lane state for q = q0a + llo
    float mrb = -3.0e38f, lrb = 0.f;   // per-lane state for q = q0b + llo
    f32x4 accA[5], accB[5];
    #pragma unroll
    for (int t = 0; t < 5; ++t) {
        accA[t] = (f32x4){0.f, 0.f, 0.f, 0.f};
        accB[t] = (f32x4){0.f, 0.f, 0.f, 0.f};
    }

    uint4 rK[3], rV[3];
    #pragma unroll
    for (int i = 0; i < 3; ++i) { rK[i] = *(const uint4*)kG[i]; rV[i] = *(const uint4*)vG[i]; }
    #pragma unroll
    for (int i = 0; i < 3; ++i) {
        *(uint4*)(lds + kL[i]) = rK[i];
        *(uint4*)(lds + 24576 + vL[i]) = rV[i];
    }
    __syncthreads();

    #pragma unroll 1
    for (int kb = 0; kb < 16; ++kb) {
        if (kb < 15) {
            #pragma unroll
            for (int i = 0; i < 3; ++i) {
                rK[i] = *(const uint4*)(kG[i] + (kb + 1) * 64 * DP);
                rV[i] = *(const uint4*)(vG[i] + (kb + 1) * 64);
            }
        }
        char* Ks = lds + ((kb & 1) ? 12288 : 0);
        char* Vs = lds + 24576 + ((kb & 1) ? 12288 : 0);

        // S^T = mfma(K, Q) for both q-sets: s[ct][r] = S[q=llo][key=ct*16+lhi*4+r]
        f32x4 sa[4], sb[4];
        __builtin_amdgcn_s_setprio(1);
        #pragma unroll
        for (int ct = 0; ct < 4; ++ct) {
            f32x4 za = (f32x4){0.f, 0.f, 0.f, 0.f};
            f32x4 zb = (f32x4){0.f, 0.f, 0.f, 0.f};
            #pragma unroll
            for (int dc = 0; dc < 3; ++dc) {
                bf16x8 kf = *(const bf16x8*)(Ks +
                    (((ct * 16 + llo) * 192 + dc * 64 + lhi * 16) ^ ((llo & 7) << 4)));
                za = __builtin_amdgcn_mfma_f32_16x16x32_bf16(kf, aqa[dc], za, 0, 0, 0);
                zb = __builtin_amdgcn_mfma_f32_16x16x32_bf16(kf, aqb[dc], zb, 0, 0, 0);
            }
            sa[ct] = za; sb[ct] = zb;
        }
        __builtin_amdgcn_s_setprio(0);

        // ---- online softmax set A (exp2 domain, lane-local row q=llo) ----
        {
            float m0 = fmaxf(fmaxf(sa[0][0], sa[0][1]), fmaxf(sa[0][2], sa[0][3]));
            float m1 = fmaxf(fmaxf(sa[1][0], sa[1][1]), fmaxf(sa[1][2], sa[1][3]));
            float m2 = fmaxf(fmaxf(sa[2][0], sa[2][1]), fmaxf(sa[2][2], sa[2][3]));
            float m3 = fmaxf(fmaxf(sa[3][0], sa[3][1]), fmaxf(sa[3][2], sa[3][3]));
            float mx = fmaxf(fmaxf(m0, m1), fmaxf(m2, m3));
            mx = fmaxf(mx, __shfl_xor(mx, 16, 64));
            mx = fmaxf(mx, __shfl_xor(mx, 32, 64));
            if (!__all(mx <= mra + 8.0f)) {        // T13 defer-max
                float mn = fmaxf(mra, mx);
                float al = exp2f(mra - mn);
                mra = mn;
                lra *= al;
                #pragma unroll
                for (int t = 0; t < 5; ++t)
                    #pragma unroll
                    for (int r = 0; r < 4; ++r) accA[t][r] *= al;
            }
            float p[4][4]; float sm = 0.f;
            #pragma unroll
            for (int ct = 0; ct < 4; ++ct)
                #pragma unroll
                for (int r = 0; r < 4; ++r) { p[ct][r] = exp2f(sa[ct][r] - mra); sm += p[ct][r]; }
            sm += __shfl_xor(sm, 16, 64);
            sm += __shfl_xor(sm, 32, 64);
            lra += sm;
            #pragma unroll
            for (int ct = 0; ct < 4; ++ct) {
                bf16x4 pk = { (__bf16)p[ct][0], (__bf16)p[ct][1], (__bf16)p[ct][2], (__bf16)p[ct][3] };
                *(bf16x4*)(Pa + ((llo * 128 + ct * 32 + lhi * 8) ^ ((llo & 7) << 4))) = pk;
            }
        }
        // ---- online softmax set B ----
        {
            float m0 = fmaxf(fmaxf(sb[0][0], sb[0][1]), fmaxf(sb[0][2], sb[0][3]));
            float m1 = fmaxf(fmaxf(sb[1][0], sb[1][1]), fmaxf(sb[1][2], sb[1][3]));
            float m2 = fmaxf(fmaxf(sb[2][0], sb[2][1]), fmaxf(sb[2][2], sb[2][3]));
            float m3 = fmaxf(fmaxf(sb[3][0], sb[3][1]), fmaxf(sb[3][2], sb[3][3]));
            float mx = fmaxf(fmaxf(m0, m1), fmaxf(m2, m3));
            mx = fmaxf(mx, __shfl_xor(mx, 16, 64));
            mx = fmaxf(mx, __shfl_xor(mx, 32, 64));
            if (!__all(mx <= mrb + 8.0f)) {
                float mn = fmaxf(mrb, mx);
                float al = exp2f(mrb - mn);
                mrb = mn;
                lrb *= al;
                #pragma unroll
                for (int t = 0; t < 5; ++t)
                    #pragma unroll
                    for (int r = 0; r < 4; ++r) accB[t][r] *= al;
            }
            float p[4][4]; float sm = 0.f;
            #pragma unroll
            for (int ct = 0; ct < 4; ++ct)
                #pragma unroll
                for (int r = 0; r < 4; ++r) { p[ct][r] = exp2f(sb[ct][r] - mrb); sm += p[ct][r]; }
            sm += __shfl_xor(sm, 16, 64);
            sm += __shfl_xor(sm, 32, 64);
            lrb += sm;
            #pragma unroll
            for (int ct = 0; ct < 4; ++ct) {
                bf16x4 pk = { (__bf16)p[ct][0], (__bf16)p[ct][1], (__bf16)p[ct][2], (__bf16)p[ct][3] };
                *(bf16x4*)(Pb + ((llo * 128 + ct * 32 + lhi * 8) ^ ((llo & 7) << 4))) = pk;
            }
        }
        asm volatile("s_waitcnt lgkmcnt(0)" ::: "memory");

        // PV flipped: A = V^T frag (row=d), B = P frag (col=q) -> O[q=llo][d]
        __builtin_amdgcn_s_setprio(1);
        #pragma unroll
        for (int nc = 0; nc < 2; ++nc) {
            bf16x8 pA = *(const bf16x8*)(Pa + ((llo * 128 + nc * 64 + lhi * 16) ^ ((llo & 7) << 4)));
            bf16x8 pB = *(const bf16x8*)(Pb + ((llo * 128 + nc * 64 + lhi * 16) ^ ((llo & 7) << 4)));
            #pragma unroll
            for (int t = 0; t < 5; ++t) {
                bf16x8 bv = *(const bf16x8*)(Vs +
                    (((t * 16 + llo) * 128 + nc * 64 + lhi * 16) ^ ((llo & 7) << 4)));
                accA[t] = __builtin_amdgcn_mfma_f32_16x16x32_bf16(bv, pA, accA[t], 0, 0, 0);
                accB[t] = __builtin_amdgcn_mfma_f32_16x16x32_bf16(bv, pB, accB[t], 0, 0, 0);
            }
        }
        __builtin_amdgcn_s_setprio(0);

        if (kb < 15) {
            char* Kd = lds + ((kb & 1) ? 0 : 12288);
            char* Vd = lds + 24576 + ((kb & 1) ? 0 : 12288);
            #pragma unroll
            for (int i = 0; i < 3; ++i) {
                *(uint4*)(Kd + kL[i]) = rK[i];
                *(uint4*)(Vd + vL[i]) = rV[i];
            }
        }
        __syncthreads();
    }

    // epilogue: per-lane q=llo; d = t*16 + lhi*4 + r -> bf16x4 8B stores
    const float linvA = 1.f / lra;
    const float linvB = 1.f / lrb;
    const int b = bh >> 4, h = bh & 15;
    const int qa = q0a + llo, qb = q0b + llo;
    __bf16* outA = atto + (long)(b * NSEQ + qa) * HID + h * HD;
    __bf16* outB = atto + (long)(b * NSEQ + qb) * HID + h * HD;
    #pragma unroll
    for (int t = 0; t < 5; ++t) {
        int d0 = t * 16 + lhi * 4;
        if (d0 < HD) {
            bf16x4 oa = { (__bf16)(accA[t][0] * linvA), (__bf16)(accA[t][1] * linvA),
                          (__bf16)(accA[t][2] * linvA), (__bf16)(accA[t][3] * linvA) };
            bf16x4 ob = { (__bf16)(accB[t][0] * linvB), (__bf16)(accB[t][1] * linvB),
                          (__bf16)(accB[t][2] * linvB), (__bf16)(accB[t][3] * linvB) };
            *(bf16x4*)(outA + d0) = oa;
            *(bf16x4*)(outB + d0) = ob;
        }
    }
}

// ---------------- GEMM 2: out = atto @ w_out + b_out (fp32 out) ----------------
// BM=128: grid 160 blocks (32 M-tiles x 5 N-tiles, N padded 1152->1280)

__global__ __launch_bounds__(512, 2) void gemm_out_kernel(
    const __bf16* __restrict__ atto, const __bf16* __restrict__ woutT,
    const float* __restrict__ b_out, float* __restrict__ out)
{
    __shared__ char lds[3 * (128 * 64 + 16384)];   // 72 KiB
    f32x4 acc[4][4];
    #pragma unroll
    for (int i = 0; i < 4; ++i)
        #pragma unroll
        for (int j = 0; j < 4; ++j) acc[i][j] = (f32x4){0.f, 0.f, 0.f, 0.f};

    // bijective chunked XCD swizzle: 160 blocks, 20 per XCD (4 bx x 5 by)
    int lin = blockIdx.x;
    int v   = (lin & 7) * 20 + (lin >> 3);
    int bx  = v / 5, by = v - bx * 5;
    long rowA0 = (long)bx * 128, rowB0 = (long)by * 256;

    gemm_core<4>(atto, woutT, HID, HID, HID / 32, rowA0, rowB0, lds, acc);

    const int wave = threadIdx.x >> 6, lane = threadIdx.x & 63;
    const int wm = wave >> 2, wn = wave & 3, lhi = lane >> 4, llo = lane & 15;

    #pragma unroll
    for (int nt = 0; nt < 4; ++nt) {
        int n = (int)rowB0 + wn * 64 + nt * 16 + llo;   // 0..1279
        if (n >= HID) continue;
        float bias = b_out[n];
        #pragma unroll
        for (int mt = 0; mt < 4; ++mt) {
            #pragma unroll
            for (int r = 0; r < 4; ++r) {
                int m = (int)rowA0 + wm * 64 + mt * 16 + lhi * 4 + r;
                out[(long)m * HID + n] = acc[mt][nt][r] + bias;
            }
        }
    }
}

// ---------------- launch ----------------

extern "C" void kernel_launch(void* const* d_in, const int* in_sizes, int n_in,
                              void* d_out, int out_size, void* d_ws, size_t ws_size,
                              hipStream_t stream) {
    const float* x      = (const float*)d_in[0];
    const float* w_qkv  = (const float*)d_in[1];
    const float* b_qkv  = (const float*)d_in[2];
    const float* w_out  = (const float*)d_in[3];
    const float* b_out  = (const float*)d_in[4];
    float* out = (float*)d_out;
    char* ws = (char*)d_ws;

    __bf16* xb    = (__bf16*)(ws + XB_OFF);
    __bf16* atto  = (__bf16*)(ws + XB_OFF);     // aliases xb (dead after gemm_qkv)
    __bf16* wqkvT = (__bf16*)(ws + WQKVT_OFF);
    __bf16* woutT = (__bf16*)(ws + WOUTT_OFF);
    __bf16* Qp    = (__bf16*)(ws + QP_OFF);
    __bf16* Kp    = (__bf16*)(ws + KP_OFF);
    __bf16* Vt    = (__bf16*)(ws + VT_OFF);

    pad_kernel<<<896, 256, 0, stream>>>(Qp, Kp, Vt);
    conv_x_kernel<<<4608, 256, 0, stream>>>(x, xb, 1179648L);
    transpose_cvt_kernel<<<dim3(108, 36), dim3(32, 8), 0, stream>>>(w_qkv, wqkvT, HID, QKV3);
    transpose_cvt_kernel<<<dim3(36, 36), dim3(32, 8), 0, stream>>>(w_out, woutT, HID, HID);
    gemm_qkv_kernel<<<224, 512, 0, stream>>>(xb, wqkvT, b_qkv, Qp, Kp, Vt);
    flash_kernel<<<dim3(8, 64), 256, 0, stream>>>(Qp, Kp, Vt, atto);
    gemm_out_kernel<<<160, 512, 0, stream>>>(atto, woutT, b_out, out);
}

// Round 7
// 165.497 us; speedup vs baseline: 2.0184x; 1.0020x over previous
//
#include <hip/hip_runtime.h>
#include <cstdint>

// Problem constants
#define NB 4
#define NSEQ 1024
#define NH 16
#define HD 72
#define HID 1152
#define QKV3 3456
#define DP 96           // padded head dim (multiple of 32 for K=32 MFMA)
// scale = 72^-0.5 folded with log2(e) so softmax runs in exp2 domain
#define QSCALE 0.17003713711193175f

typedef __attribute__((ext_vector_type(8))) __bf16 bf16x8;
typedef __attribute__((ext_vector_type(4))) __bf16 bf16x4;
typedef __attribute__((ext_vector_type(4))) float f32x4;

#define AS1 __attribute__((address_space(1)))
#define AS3 __attribute__((address_space(3)))

__device__ __forceinline__ void gl_lds16(const void* g, void* l) {
    // async global->LDS, 16B per lane; LDS dest = wave-uniform base + lane*16
    __builtin_amdgcn_global_load_lds((const AS1 uint32_t*)g, (AS3 uint32_t*)l, 16, 0, 0);
}

// raw barrier: no compiler-inserted vmcnt(0) drain (unlike __syncthreads)
#define RAW_BAR() asm volatile("s_barrier" ::: "memory")

// Workspace layout (bytes)
#define XB_OFF     0UL           // x as bf16 [4096][1152]; ALIASED as atto after gemm_qkv
#define WQKVT_OFF  9437184UL     // w_qkv^T bf16  [3584][1152] (rows 3456+ junk, unused)
#define WOUTT_OFF  17694720UL    // w_out^T bf16  [1280][1152] (rows 1152+ junk, unused)
#define QP_OFF     20643840UL    // Q padded bf16 [64][1024][96] (QSCALE folded)
#define KP_OFF     33226752UL    // K padded bf16 [64][1024][96]
#define VT_OFF     45809664UL    // V^T padded bf16 [64][96][1024]
// total: 58,392,576 bytes

// ---------------- prep kernels ----------------

// zero ONLY the d=72..95 pad regions of Qp/Kp/Vt
__global__ void pad_kernel(__bf16* __restrict__ Qp, __bf16* __restrict__ Kp,
                           __bf16* __restrict__ Vt) {
    int i = blockIdx.x * 256 + threadIdx.x;          // grid: 896*256 = 229376 exact
    uint4 z = make_uint4(0u, 0u, 0u, 0u);
    if (i < 131072) {
        __bf16* base = (i & 65536) ? Kp : Qp;
        int row = i & 65535;
        uint4* p = (uint4*)(base + row * 96 + 72);   // 48 B pad per row
        p[0] = z; p[1] = z; p[2] = z;
    } else {
        int j = i - 131072;                          // 0..98303
        int bh = j / 1536, w = j - bh * 1536;        // 24 rows x 1024 = 1536 uint4 per bh
        *((uint4*)(Vt + (long)bh * 98304 + 73728) + w) = z;
    }
}

__global__ void conv_x_kernel(const float* __restrict__ in, __bf16* __restrict__ out, long n4) {
    long i = (long)blockIdx.x * blockDim.x + threadIdx.x;
    if (i >= n4) return;
    float4 v = ((const float4*)in)[i];
    bf16x4 o = { (__bf16)v.x, (__bf16)v.y, (__bf16)v.z, (__bf16)v.w };
    ((bf16x4*)out)[i] = o;
}

// in fp32 [K][Nc] row-major -> out bf16 [Nc][K]
__global__ void transpose_cvt_kernel(const float* __restrict__ in, __bf16* __restrict__ out,
                                     int K, int Nc) {
    __shared__ float t[32][33];
    int n0 = blockIdx.x * 32, k0 = blockIdx.y * 32;
    int x = threadIdx.x, y = threadIdx.y;
    #pragma unroll
    for (int i = 0; i < 32; i += 8)
        t[y + i][x] = in[(long)(k0 + y + i) * Nc + n0 + x];
    __syncthreads();
    #pragma unroll
    for (int i = 0; i < 32; i += 8)
        out[(long)(n0 + y + i) * K + k0 + x] = (__bf16)t[x][y + i];
}

// ---------------- GEMM engine: BM x 256 tile, 8 waves (2M x 4N), BK=32 ----------------
// DOUBLE-buffered LDS (48 KB for BM=128 -> up to 3 blocks/CU), global_load_lds
// staging 1 tile ahead, vmcnt(0)+raw s_barrier once per tile, T2 XOR swizzle
// with pre-swizzled global source, T5 setprio around MFMA clusters.

template<int MT>   // m-fragments per wave; BM = MT*32 (4 -> 128)
__device__ __forceinline__ void gemm_core(
    const __bf16* __restrict__ A, const __bf16* __restrict__ Bt,
    int lda, int ldb, int ntk, long rowA0, long rowB0,
    char* lds, f32x4 acc[MT][4])
{
    constexpr int BM    = MT * 32;
    constexpr int ATILE = BM * 64;        // bytes (rows of 64 B)
    constexpr int TILE  = ATILE + 256 * 64;

    const int tid  = threadIdx.x;
    const int wave = tid >> 6, lane = tid & 63;
    const int wm = wave >> 2, wn = wave & 3;      // 2 x 4 wave grid
    const int lhi = lane >> 4, llo = lane & 15;
    const int srow = tid >> 2;                    // staging row (0..127)
    const int scol = (tid & 3) * 8;               // staging col element

    auto stage = [&](int kt, int buf) {
        char* base = lds + buf * TILE;
        #pragma unroll
        for (int j = 0; j < BM / 128; ++j) {
            int r  = srow + j * 128;
            int ks = scol ^ ((((unsigned)r >> 1) & 3) << 3);   // pre-swizzled source
            gl_lds16(A + (rowA0 + r) * (long)lda + kt * 32 + ks, base + tid * 16 + j * 8192);
        }
        #pragma unroll
        for (int j = 0; j < 2; ++j) {
            int r  = srow + j * 128;
            int ks = scol ^ ((((unsigned)r >> 1) & 3) << 3);
            gl_lds16(Bt + (rowB0 + r) * (long)ldb + kt * 32 + ks,
                     base + ATILE + tid * 16 + j * 8192);
        }
    };

    stage(0, 0);
    asm volatile("s_waitcnt vmcnt(0)" ::: "memory");
    RAW_BAR();

    #pragma unroll 1
    for (int t = 0; t < ntk; ++t) {
        char* Ab = lds + (t & 1) * TILE;
        char* Bb = Ab + ATILE;
        if (t + 1 < ntk) stage(t + 1, (t & 1) ^ 1);

        bf16x8 bfr[4];
        #pragma unroll
        for (int nt = 0; nt < 4; ++nt) {
            int R = wn * 64 + nt * 16 + llo;
            int b = (R * 64 + lhi * 16) ^ ((((unsigned)R >> 1) & 3) << 4);
            bfr[nt] = *(const bf16x8*)(Bb + b);
        }
        bf16x8 af[MT / 2];
        #pragma unroll
        for (int mt = 0; mt < MT / 2; ++mt) {
            int R = wm * (BM / 2) + mt * 16 + llo;
            int b = (R * 64 + lhi * 16) ^ ((((unsigned)R >> 1) & 3) << 4);
            af[mt] = *(const bf16x8*)(Ab + b);
        }
        __builtin_amdgcn_s_setprio(1);
        #pragma unroll
        for (int mt = 0; mt < MT / 2; ++mt)
            #pragma unroll
            for (int nt = 0; nt < 4; ++nt)
                acc[mt][nt] = __builtin_amdgcn_mfma_f32_16x16x32_bf16(af[mt], bfr[nt], acc[mt][nt], 0, 0, 0);
        __builtin_amdgcn_s_setprio(0);
        #pragma unroll
        for (int mt = 0; mt < MT / 2; ++mt) {
            int R = wm * (BM / 2) + (MT / 2 + mt) * 16 + llo;
            int b = (R * 64 + lhi * 16) ^ ((((unsigned)R >> 1) & 3) << 4);
            af[mt] = *(const bf16x8*)(Ab + b);
        }
        __builtin_amdgcn_s_setprio(1);
        #pragma unroll
        for (int mt = 0; mt < MT / 2; ++mt)
            #pragma unroll
            for (int nt = 0; nt < 4; ++nt)
                acc[MT / 2 + mt][nt] = __builtin_amdgcn_mfma_f32_16x16x32_bf16(af[mt], bfr[nt], acc[MT / 2 + mt][nt], 0, 0, 0);
        __builtin_amdgcn_s_setprio(0);
        asm volatile("s_waitcnt vmcnt(0)" ::: "memory");   // own next-tile loads landed
        RAW_BAR();
    }
}

// ---------------- GEMM 1: qkv = x @ w_qkv + b, scatter to Qp/Kp/Vt ----------------
// BM=128: grid 448 blocks (32 M-tiles x 14 N-tiles, N padded 3456->3584)

__global__ __launch_bounds__(512, 4) void gemm_qkv_kernel(
    const __bf16* __restrict__ xb, const __bf16* __restrict__ wqkvT,
    const float* __restrict__ b_qkv,
    __bf16* __restrict__ Qp, __bf16* __restrict__ Kp, __bf16* __restrict__ Vt)
{
    __shared__ char lds[49152];
    f32x4 acc[4][4];
    #pragma unroll
    for (int i = 0; i < 4; ++i)
        #pragma unroll
        for (int j = 0; j < 4; ++j) acc[i][j] = (f32x4){0.f, 0.f, 0.f, 0.f};

    // bijective chunked XCD swizzle: 448 blocks, 56 per XCD (4 bx x 14 by)
    int lin = blockIdx.x;
    int v   = (lin & 7) * 56 + (lin >> 3);
    int bx  = v / 14, by = v - bx * 14;
    long rowA0 = (long)bx * 128, rowB0 = (long)by * 256;

    gemm_core<4>(xb, wqkvT, HID, HID, HID / 32, rowA0, rowB0, lds, acc);

    const int wave = threadIdx.x >> 6, lane = threadIdx.x & 63;
    const int wm = wave >> 2, wn = wave & 3, lhi = lane >> 4, llo = lane & 15;

    #pragma unroll
    for (int nt = 0; nt < 4; ++nt) {
        int n = (int)rowB0 + wn * 64 + nt * 16 + llo;   // 0..3583
        if (n >= QKV3) continue;
        int sec = n / HID;
        int nn  = n - sec * HID;
        int h   = nn / HD;
        int d   = nn - h * HD;
        float bias = b_qkv[n];
        if (sec == 2) {
            // V: r-quad is nq-contiguous -> one 8B bf16x4 store per mt
            #pragma unroll
            for (int mt = 0; mt < 4; ++mt) {
                int m0 = (int)rowA0 + wm * 64 + mt * 16 + lhi * 4;
                int bb = m0 >> 10, nq0 = m0 & 1023;
                bf16x4 pk = { (__bf16)(acc[mt][nt][0] + bias), (__bf16)(acc[mt][nt][1] + bias),
                              (__bf16)(acc[mt][nt][2] + bias), (__bf16)(acc[mt][nt][3] + bias) };
                *(bf16x4*)(Vt + ((long)(bb * NH + h) * DP + d) * NSEQ + nq0) = pk;
            }
        } else {
            __bf16* dst = (sec == 0) ? Qp : Kp;
            float scl = (sec == 0) ? QSCALE : 1.0f;
            #pragma unroll
            for (int mt = 0; mt < 4; ++mt) {
                #pragma unroll
                for (int r = 0; r < 4; ++r) {
                    int m = (int)rowA0 + wm * 64 + mt * 16 + lhi * 4 + r;
                    int bb = m >> 10, nq = m & 1023;
                    long bhn = (long)(bb * NH + h) * NSEQ + nq;
                    dst[bhn * DP + d] = (__bf16)((acc[mt][nt][r] + bias) * scl);
                }
            }
        }
    }
}

// ---------------- flash attention v6 ----------------
// 8 waves (512 thr) share K/V tiles; 256 blocks -> 2 blocks/CU = 16 waves/CU.
// K single-buffered [64][256B] (padded rows, in-row XOR swizzle), V double-
// buffered [96][128B]; all staging via global_load_lds with inverse-swizzled
// per-lane global source (rule #21). 2 raw barriers/iter: bar1 after QK gates
// the K overwrite; V(kb+1) issues at iter start into the idle buffer; own
// vmcnt(0) before bar2. Per-wave math identical to v5 (flipped PV, defer-max).
// LDS map: Ks [0,16K) ; V0 [16K,28K) ; V1 [28K,40K) ; P [40K,72K) (4K/wave).

__global__ __launch_bounds__(512, 4) void flash_kernel(
    const __bf16* __restrict__ Qp, const __bf16* __restrict__ Kp,
    const __bf16* __restrict__ Vt, __bf16* __restrict__ atto)
{
    __shared__ char lds[73728];
    const int tid  = threadIdx.x;
    const int wave = tid >> 6, lane = tid & 63;
    const int lhi = lane >> 4, llo = lane & 15;

    // chunked XCD swizzle (256 = 8 XCD x 32): XCD i owns bh in [i*8,(i+1)*8)
    int lin = blockIdx.x;
    int v   = ((lin & 7) << 5) + (lin >> 3);
    const int qx = v & 3;          // q-chunk of 256 rows
    const int bh = v >> 2;

    const __bf16* Qb  = Qp + (long)bh * NSEQ * DP;
    const char*   KbB = (const char*)(Kp + (long)bh * NSEQ * DP);
    const char*   VbB = (const char*)(Vt + (long)bh * DP * NSEQ);

    char* Pa = lds + 40960 + wave * 4096;
    char* Pb = Pa + 2048;
    const int q0a = qx * 256 + wave * 16;
    const int q0b = q0a + 128;

    // ---- staging (global_load_lds, linear LDS dest, inverse-swizzled source) ----
    auto stageK = [&](int kt) {
        #pragma unroll
        for (int j = 0; j < 2; ++j) {
            int bk  = wave * 2 + j;                 // 16 x 1KB blocks
            int key = bk * 4 + (lane >> 4);         // LDS row (256 B each)
            int c   = (lane & 15) * 16;             // byte within row
            gl_lds16(KbB + ((long)(kt * 64 + key)) * 192 + (c ^ ((key & 7) << 4)),
                     lds + bk * 1024);
        }
    };
    auto stageV = [&](int kt, int vb) {
        int dv = wave * 8 + (lane >> 3);            // LDS row (128 B each)
        int c  = (lane & 7) * 16;
        gl_lds16(VbB + (long)dv * 2048 + kt * 128 + (c ^ ((dv & 7) << 4)),
                 lds + 16384 + vb * 12288 + wave * 1024);
        if (wave < 4) {
            int dv2 = 64 + wave * 8 + (lane >> 3);
            gl_lds16(VbB + (long)dv2 * 2048 + kt * 128 + (c ^ ((dv2 & 7) << 4)),
                     lds + 16384 + vb * 12288 + 8192 + wave * 1024);
        }
    };

    // Q fragments (B operand): Q[q][d = dc*32 + lhi*8 + j]; QSCALE folded
    bf16x8 aqa[3], aqb[3];
    #pragma unroll
    for (int dc = 0; dc < 3; ++dc) {
        aqa[dc] = *(const bf16x8*)(Qb + (long)(q0a + llo) * DP + dc * 32 + lhi * 8);
        aqb[dc] = *(const bf16x8*)(Qb + (long)(q0b + llo) * DP + dc * 32 + lhi * 8);
    }

    float mra = -3.0e38f, lra = 0.f;   // per-lane state for q = q0a + llo
    float mrb = -3.0e38f, lrb = 0.f;   // per-lane state for q = q0b + llo
    f32x4 accA[5], accB[5];
    #pragma unroll
    for (int t = 0; t < 5; ++t) {
        accA[t] = (f32x4){0.f, 0.f, 0.f, 0.f};
        accB[t] = (f32x4){0.f, 0.f, 0.f, 0.f};
    }

    // prologue: tile 0
    stageK(0);
    stageV(0, 0);
    asm volatile("s_waitcnt vmcnt(0)" ::: "memory");
    RAW_BAR();

    #pragma unroll 1
    for (int kb = 0; kb < 16; ++kb) {
        const int vbuf = kb & 1;
        if (kb < 15) stageV(kb + 1, vbuf ^ 1);     // lands during QK+softmax

        // S^T = mfma(K, Q): s[ct][r] = S[q=llo][key=ct*16+lhi*4+r]
        f32x4 sa[4], sb[4];
        __builtin_amdgcn_s_setprio(1);
        #pragma unroll
        for (int ct = 0; ct < 4; ++ct) {
            f32x4 za = (f32x4){0.f, 0.f, 0.f, 0.f};
            f32x4 zb = (f32x4){0.f, 0.f, 0.f, 0.f};
            #pragma unroll
            for (int dc = 0; dc < 3; ++dc) {
                bf16x8 kf = *(const bf16x8*)(lds +
                    (((ct * 16 + llo) * 256 + dc * 64 + lhi * 16) ^ ((llo & 7) << 4)));
                za = __builtin_amdgcn_mfma_f32_16x16x32_bf16(kf, aqa[dc], za, 0, 0, 0);
                zb = __builtin_amdgcn_mfma_f32_16x16x32_bf16(kf, aqb[dc], zb, 0, 0, 0);
            }
            sa[ct] = za; sb[ct] = zb;
        }
        __builtin_amdgcn_s_setprio(0);
        RAW_BAR();                                  // all waves done reading Ks
        if (kb < 15) stageK(kb + 1);                // overwrite Ks for next iter

        // ---- online softmax set A (exp2 domain, lane-local row q=llo) ----
        {
            float m0 = fmaxf(fmaxf(sa[0][0], sa[0][1]), fmaxf(sa[0][2], sa[0][3]));
            float m1 = fmaxf(fmaxf(sa[1][0], sa[1][1]), fmaxf(sa[1][2], sa[1][3]));
            float m2 = fmaxf(fmaxf(sa[2][0], sa[2][1]), fmaxf(sa[2][2], sa[2][3]));
            float m3 = fmaxf(fmaxf(sa[3][0], sa[3][1]), fmaxf(sa[3][2], sa[3][3]));
            float mx = fmaxf(fmaxf(m0, m1), fmaxf(m2, m3));
            mx = fmaxf(mx, __shfl_xor(mx, 16, 64));
            mx = fmaxf(mx, __shfl_xor(mx, 32, 64));
            if (!__all(mx <= mra + 8.0f)) {        // T13 defer-max
                float mn = fmaxf(mra, mx);
                float al = exp2f(mra - mn);
                mra = mn;
                lra *= al;
                #pragma unroll
                for (int t = 0; t < 5; ++t)
                    #pragma unroll
                    for (int r = 0; r < 4; ++r) accA[t][r] *= al;
            }
            float p[4][4]; float sm = 0.f;
            #pragma unroll
            for (int ct = 0; ct < 4; ++ct)
                #pragma unroll
                for (int r = 0; r < 4; ++r) { p[ct][r] = exp2f(sa[ct][r] - mra); sm += p[ct][r]; }
            sm += __shfl_xor(sm, 16, 64);
            sm += __shfl_xor(sm, 32, 64);
            lra += sm;
            #pragma unroll
            for (int ct = 0; ct < 4; ++ct) {
                bf16x4 pk = { (__bf16)p[ct][0], (__bf16)p[ct][1], (__bf16)p[ct][2], (__bf16)p[ct][3] };
                *(bf16x4*)(Pa + ((llo * 128 + ct * 32 + lhi * 8) ^ ((llo & 7) << 4))) = pk;
            }
        }
        // ---- online softmax set B ----
        {
            float m0 = fmaxf(fmaxf(sb[0][0], sb[0][1]), fmaxf(sb[0][2], sb[0][3]));
            float m1 = fmaxf(fmaxf(sb[1][0], sb[1][1]), fmaxf(sb[1][2], sb[1][3]));
            float m2 = fmaxf(fmaxf(sb[2][0], sb[2][1]), fmaxf(sb[2][2], sb[2][3]));
            float m3 = fmaxf(fmaxf(sb[3][0], sb[3][1]), fmaxf(sb[3][2], sb[3][3]));
            float mx = fmaxf(fmaxf(m0, m1), fmaxf(m2, m3));
            mx = fmaxf(mx, __shfl_xor(mx, 16, 64));
            mx = fmaxf(mx, __shfl_xor(mx, 32, 64));
            if (!__all(mx <= mrb + 8.0f)) {
                float mn = fmaxf(mrb, mx);
                float al = exp2f(mrb - mn);
                mrb = mn;
                lrb *= al;
                #pragma unroll
                for (int t = 0; t < 5; ++t)
                    #pragma unroll
                    for (int r = 0; r < 4; ++r) accB[t][r] *= al;
            }
            float p[4][4]; float sm = 0.f;
            #pragma unroll
            for (int ct = 0; ct < 4; ++ct)
                #pragma unroll
                for (int r = 0; r < 4; ++r) { p[ct][r] = exp2f(sb[ct][r] - mrb); sm += p[ct][r]; }
            sm += __shfl_xor(sm, 16, 64);
            sm += __shfl_xor(sm, 32, 64);
            lrb += sm;
            #pragma unroll
            for (int ct = 0; ct < 4; ++ct) {
                bf16x4 pk = { (__bf16)p[ct][0], (__bf16)p[ct][1], (__bf16)p[ct][2], (__bf16)p[ct][3] };
                *(bf16x4*)(Pb + ((llo * 128 + ct * 32 + lhi * 8) ^ ((llo & 7) << 4))) = pk;
            }
        }
        asm volatile("s_waitcnt lgkmcnt(0)" ::: "memory");

        // PV flipped: A = V^T frag (row=d), B = P frag (col=q) -> O[q=llo][d]
        __builtin_amdgcn_s_setprio(1);
        #pragma unroll
        for (int nc = 0; nc < 2; ++nc) {
            bf16x8 pA = *(const bf16x8*)(Pa + ((llo * 128 + nc * 64 + lhi * 16) ^ ((llo & 7) << 4)));
            bf16x8 pB = *(const bf16x8*)(Pb + ((llo * 128 + nc * 64 + lhi * 16) ^ ((llo & 7) << 4)));
            #pragma unroll
            for (int t = 0; t < 5; ++t) {
                bf16x8 bv = *(const bf16x8*)(lds + 16384 + vbuf * 12288 +
                    (((t * 16 + llo) * 128 + nc * 64 + lhi * 16) ^ ((llo & 7) << 4)));
                accA[t] = __builtin_amdgcn_mfma_f32_16x16x32_bf16(bv, pA, accA[t], 0, 0, 0);
                accB[t] = __builtin_amdgcn_mfma_f32_16x16x32_bf16(bv, pB, accB[t], 0, 0, 0);
            }
        }
        __builtin_amdgcn_s_setprio(0);

        if (kb < 15) asm volatile("s_waitcnt vmcnt(0)" ::: "memory");  // own K/V staged
        RAW_BAR();
    }

    // epilogue: per-lane q=llo; d = t*16 + lhi*4 + r -> bf16x4 8B stores
    const float linvA = 1.f / lra;
    const float linvB = 1.f / lrb;
    const int b = bh >> 4, h = bh & 15;
    const int qa = q0a + llo, qb = q0b + llo;
    __bf16* outA = atto + (long)(b * NSEQ + qa) * HID + h * HD;
    __bf16* outB = atto + (long)(b * NSEQ + qb) * HID + h * HD;
    #pragma unroll
    for (int t = 0; t < 5; ++t) {
        int d0 = t * 16 + lhi * 4;
        if (d0 < HD) {
            bf16x4 oa = { (__bf16)(accA[t][0] * linvA), (__bf16)(accA[t][1] * linvA),
                          (__bf16)(accA[t][2] * linvA), (__bf16)(accA[t][3] * linvA) };
            bf16x4 ob = { (__bf16)(accB[t][0] * linvB), (__bf16)(accB[t][1] * linvB),
                          (__bf16)(accB[t][2] * linvB), (__bf16)(accB[t][3] * linvB) };
            *(bf16x4*)(outA + d0) = oa;
            *(bf16x4*)(outB + d0) = ob;
        }
    }
}

// ---------------- GEMM 2: out = atto @ w_out + b_out (fp32 out) ----------------
// BM=128: grid 160 blocks (32 M-tiles x 5 N-tiles, N padded 1152->1280)

__global__ __launch_bounds__(512, 4) void gemm_out_kernel(
    const __bf16* __restrict__ atto, const __bf16* __restrict__ woutT,
    const float* __restrict__ b_out, float* __restrict__ out)
{
    __shared__ char lds[49152];
    f32x4 acc[4][4];
    #pragma unroll
    for (int i = 0; i < 4; ++i)
        #pragma unroll
        for (int j = 0; j < 4; ++j) acc[i][j] = (f32x4){0.f, 0.f, 0.f, 0.f};

    // bijective chunked XCD swizzle: 160 blocks, 20 per XCD (4 bx x 5 by)
    int lin = blockIdx.x;
    int v   = (lin & 7) * 20 + (lin >> 3);
    int bx  = v / 5, by = v - bx * 5;
    long rowA0 = (long)bx * 128, rowB0 = (long)by * 256;

    gemm_core<4>(atto, woutT, HID, HID, HID / 32, rowA0, rowB0, lds, acc);

    const int wave = threadIdx.x >> 6, lane = threadIdx.x & 63;
    const int wm = wave >> 2, wn = wave & 3, lhi = lane >> 4, llo = lane & 15;

    #pragma unroll
    for (int nt = 0; nt < 4; ++nt) {
        int n = (int)rowB0 + wn * 64 + nt * 16 + llo;   // 0..1279
        if (n >= HID) continue;
        float bias = b_out[n];
        #pragma unroll
        for (int mt = 0; mt < 4; ++mt) {
            #pragma unroll
            for (int r = 0; r < 4; ++r) {
                int m = (int)rowA0 + wm * 64 + mt * 16 + lhi * 4 + r;
                out[(long)m * HID + n] = acc[mt][nt][r] + bias;
            }
        }
    }
}

// ---------------- launch ----------------

extern "C" void kernel_launch(void* const* d_in, const int* in_sizes, int n_in,
                              void* d_out, int out_size, void* d_ws, size_t ws_size,
                              hipStream_t stream) {
    const float* x      = (const float*)d_in[0];
    const float* w_qkv  = (const float*)d_in[1];
    const float* b_qkv  = (const float*)d_in[2];
    const float* w_out  = (const float*)d_in[3];
    const float* b_out  = (const float*)d_in[4];
    float* out = (float*)d_out;
    char* ws = (char*)d_ws;

    __bf16* xb    = (__bf16*)(ws + XB_OFF);
    __bf16* atto  = (__bf16*)(ws + XB_OFF);     // aliases xb (dead after gemm_qkv)
    __bf16* wqkvT = (__bf16*)(ws + WQKVT_OFF);
    __bf16* woutT = (__bf16*)(ws + WOUTT_OFF);
    __bf16* Qp    = (__bf16*)(ws + QP_OFF);
    __bf16* Kp    = (__bf16*)(ws + KP_OFF);
    __bf16* Vt    = (__bf16*)(ws + VT_OFF);

    pad_kernel<<<896, 256, 0, stream>>>(Qp, Kp, Vt);
    conv_x_kernel<<<4608, 256, 0, stream>>>(x, xb, 1179648L);
    transpose_cvt_kernel<<<dim3(108, 36), dim3(32, 8), 0, stream>>>(w_qkv, wqkvT, HID, QKV3);
    transpose_cvt_kernel<<<dim3(36, 36), dim3(32, 8), 0, stream>>>(w_out, woutT, HID, HID);
    gemm_qkv_kernel<<<448, 512, 0, stream>>>(xb, wqkvT, b_qkv, Qp, Kp, Vt);
    flash_kernel<<<256, 512, 0, stream>>>(Qp, Kp, Vt, atto);
    gemm_out_kernel<<<160, 512, 0, stream>>>(atto, woutT, b_out, out);
}

// Round 8
// 134.433 us; speedup vs baseline: 2.4848x; 1.2311x over previous
//
#include <hip/hip_runtime.h>
#include <cstdint>

// Problem constants
#define NB 4
#define NSEQ 1024
#define NH 16
#define HD 72
#define HID 1152
#define QKV3 3456
#define DP 96           // padded head dim (multiple of 32 for K=32 MFMA)
// scale = 72^-0.5 folded with log2(e) so softmax runs in exp2 domain
#define QSCALE 0.17003713711193175f

typedef __attribute__((ext_vector_type(8))) __bf16 bf16x8;
typedef __attribute__((ext_vector_type(4))) __bf16 bf16x4;
typedef __attribute__((ext_vector_type(4))) float f32x4;

#define AS1 __attribute__((address_space(1)))
#define AS3 __attribute__((address_space(3)))

__device__ __forceinline__ void gl_lds16(const void* g, void* l) {
    // async global->LDS, 16B per lane; LDS dest = wave-uniform base + lane*16
    __builtin_amdgcn_global_load_lds((const AS1 uint32_t*)g, (AS3 uint32_t*)l, 16, 0, 0);
}

// raw barrier: no compiler-inserted vmcnt(0) drain (unlike __syncthreads)
#define RAW_BAR() asm volatile("s_barrier" ::: "memory")

// Workspace layout (bytes)
#define XB_OFF     0UL           // x as bf16 [4096][1152]; ALIASED as atto after gemm_qkv
#define WQKVT_OFF  9437184UL     // w_qkv^T bf16  [3584][1152] (rows 3456+ junk, unused)
#define WOUTT_OFF  17694720UL    // w_out^T bf16  [1280][1152] (rows 1152+ junk, unused)
#define QP_OFF     20643840UL    // Q padded bf16 [64][1024][96] (QSCALE folded)
#define KP_OFF     33226752UL    // K padded bf16 [64][1024][96]
#define VT_OFF     45809664UL    // V^T padded bf16 [64][96][1024]
// total: 58,392,576 bytes

// ---------------- prep kernels ----------------

// zero ONLY the d=72..95 pad regions of Qp/Kp/Vt
__global__ void pad_kernel(__bf16* __restrict__ Qp, __bf16* __restrict__ Kp,
                           __bf16* __restrict__ Vt) {
    int i = blockIdx.x * 256 + threadIdx.x;          // grid: 896*256 = 229376 exact
    uint4 z = make_uint4(0u, 0u, 0u, 0u);
    if (i < 131072) {
        __bf16* base = (i & 65536) ? Kp : Qp;
        int row = i & 65535;
        uint4* p = (uint4*)(base + row * 96 + 72);   // 48 B pad per row
        p[0] = z; p[1] = z; p[2] = z;
    } else {
        int j = i - 131072;                          // 0..98303
        int bh = j / 1536, w = j - bh * 1536;        // 24 rows x 1024 = 1536 uint4 per bh
        *((uint4*)(Vt + (long)bh * 98304 + 73728) + w) = z;
    }
}

__global__ void conv_x_kernel(const float* __restrict__ in, __bf16* __restrict__ out, long n4) {
    long i = (long)blockIdx.x * blockDim.x + threadIdx.x;
    if (i >= n4) return;
    float4 v = ((const float4*)in)[i];
    bf16x4 o = { (__bf16)v.x, (__bf16)v.y, (__bf16)v.z, (__bf16)v.w };
    ((bf16x4*)out)[i] = o;
}

// in fp32 [K][Nc] row-major -> out bf16 [Nc][K]
__global__ void transpose_cvt_kernel(const float* __restrict__ in, __bf16* __restrict__ out,
                                     int K, int Nc) {
    __shared__ float t[32][33];
    int n0 = blockIdx.x * 32, k0 = blockIdx.y * 32;
    int x = threadIdx.x, y = threadIdx.y;
    #pragma unroll
    for (int i = 0; i < 32; i += 8)
        t[y + i][x] = in[(long)(k0 + y + i) * Nc + n0 + x];
    __syncthreads();
    #pragma unroll
    for (int i = 0; i < 32; i += 8)
        out[(long)(n0 + y + i) * K + k0 + x] = (__bf16)t[x][y + i];
}

// ---------------- GEMM engine: BM x 256 tile, 8 waves (2M x 4N), BK=32 ----------------
// DOUBLE-buffered LDS, global_load_lds staging 1 tile ahead, vmcnt(0)+raw
// s_barrier once per tile, T2 XOR swizzle with pre-swizzled global source,
// T5 setprio around MFMA clusters.

template<int MT>   // m-fragments per wave; BM = MT*32 (4 -> 128)
__device__ __forceinline__ void gemm_core(
    const __bf16* __restrict__ A, const __bf16* __restrict__ Bt,
    int lda, int ldb, int ntk, long rowA0, long rowB0,
    char* lds, f32x4 acc[MT][4])
{
    constexpr int BM    = MT * 32;
    constexpr int ATILE = BM * 64;        // bytes (rows of 64 B)
    constexpr int TILE  = ATILE + 256 * 64;

    const int tid  = threadIdx.x;
    const int wave = tid >> 6, lane = tid & 63;
    const int wm = wave >> 2, wn = wave & 3;      // 2 x 4 wave grid
    const int lhi = lane >> 4, llo = lane & 15;
    const int srow = tid >> 2;                    // staging row (0..127)
    const int scol = (tid & 3) * 8;               // staging col element

    auto stage = [&](int kt, int buf) {
        char* base = lds + buf * TILE;
        #pragma unroll
        for (int j = 0; j < BM / 128; ++j) {
            int r  = srow + j * 128;
            int ks = scol ^ ((((unsigned)r >> 1) & 3) << 3);   // pre-swizzled source
            gl_lds16(A + (rowA0 + r) * (long)lda + kt * 32 + ks, base + tid * 16 + j * 8192);
        }
        #pragma unroll
        for (int j = 0; j < 2; ++j) {
            int r  = srow + j * 128;
            int ks = scol ^ ((((unsigned)r >> 1) & 3) << 3);
            gl_lds16(Bt + (rowB0 + r) * (long)ldb + kt * 32 + ks,
                     base + ATILE + tid * 16 + j * 8192);
        }
    };

    stage(0, 0);
    asm volatile("s_waitcnt vmcnt(0)" ::: "memory");
    RAW_BAR();

    #pragma unroll 1
    for (int t = 0; t < ntk; ++t) {
        char* Ab = lds + (t & 1) * TILE;
        char* Bb = Ab + ATILE;
        if (t + 1 < ntk) stage(t + 1, (t & 1) ^ 1);

        bf16x8 bfr[4];
        #pragma unroll
        for (int nt = 0; nt < 4; ++nt) {
            int R = wn * 64 + nt * 16 + llo;
            int b = (R * 64 + lhi * 16) ^ ((((unsigned)R >> 1) & 3) << 4);
            bfr[nt] = *(const bf16x8*)(Bb + b);
        }
        bf16x8 af[MT / 2];
        #pragma unroll
        for (int mt = 0; mt < MT / 2; ++mt) {
            int R = wm * (BM / 2) + mt * 16 + llo;
            int b = (R * 64 + lhi * 16) ^ ((((unsigned)R >> 1) & 3) << 4);
            af[mt] = *(const bf16x8*)(Ab + b);
        }
        __builtin_amdgcn_s_setprio(1);
        #pragma unroll
        for (int mt = 0; mt < MT / 2; ++mt)
            #pragma unroll
            for (int nt = 0; nt < 4; ++nt)
                acc[mt][nt] = __builtin_amdgcn_mfma_f32_16x16x32_bf16(af[mt], bfr[nt], acc[mt][nt], 0, 0, 0);
        __builtin_amdgcn_s_setprio(0);
        #pragma unroll
        for (int mt = 0; mt < MT / 2; ++mt) {
            int R = wm * (BM / 2) + (MT / 2 + mt) * 16 + llo;
            int b = (R * 64 + lhi * 16) ^ ((((unsigned)R >> 1) & 3) << 4);
            af[mt] = *(const bf16x8*)(Ab + b);
        }
        __builtin_amdgcn_s_setprio(1);
        #pragma unroll
        for (int mt = 0; mt < MT / 2; ++mt)
            #pragma unroll
            for (int nt = 0; nt < 4; ++nt)
                acc[MT / 2 + mt][nt] = __builtin_amdgcn_mfma_f32_16x16x32_bf16(af[mt], bfr[nt], acc[MT / 2 + mt][nt], 0, 0, 0);
        __builtin_amdgcn_s_setprio(0);
        asm volatile("s_waitcnt vmcnt(0)" ::: "memory");   // own next-tile loads landed
        RAW_BAR();
    }
}

// ---------------- GEMM 1: qkv = x @ w_qkv + b, scatter to Qp/Kp/Vt ----------------
// BM=128: grid 448 blocks (32 M-tiles x 14 N-tiles, N padded 3456->3584)

__global__ __launch_bounds__(512, 4) void gemm_qkv_kernel(
    const __bf16* __restrict__ xb, const __bf16* __restrict__ wqkvT,
    const float* __restrict__ b_qkv,
    __bf16* __restrict__ Qp, __bf16* __restrict__ Kp, __bf16* __restrict__ Vt)
{
    __shared__ char lds[49152];
    f32x4 acc[4][4];
    #pragma unroll
    for (int i = 0; i < 4; ++i)
        #pragma unroll
        for (int j = 0; j < 4; ++j) acc[i][j] = (f32x4){0.f, 0.f, 0.f, 0.f};

    // bijective chunked XCD swizzle: 448 blocks, 56 per XCD (4 bx x 14 by)
    int lin = blockIdx.x;
    int v   = (lin & 7) * 56 + (lin >> 3);
    int bx  = v / 14, by = v - bx * 14;
    long rowA0 = (long)bx * 128, rowB0 = (long)by * 256;

    gemm_core<4>(xb, wqkvT, HID, HID, HID / 32, rowA0, rowB0, lds, acc);

    const int wave = threadIdx.x >> 6, lane = threadIdx.x & 63;
    const int wm = wave >> 2, wn = wave & 3, lhi = lane >> 4, llo = lane & 15;

    #pragma unroll
    for (int nt = 0; nt < 4; ++nt) {
        int n = (int)rowB0 + wn * 64 + nt * 16 + llo;   // 0..3583
        if (n >= QKV3) continue;
        int sec = n / HID;
        int nn  = n - sec * HID;
        int h   = nn / HD;
        int d   = nn - h * HD;
        float bias = b_qkv[n];
        if (sec == 2) {
            // V: r-quad is nq-contiguous -> one 8B bf16x4 store per mt
            #pragma unroll
            for (int mt = 0; mt < 4; ++mt) {
                int m0 = (int)rowA0 + wm * 64 + mt * 16 + lhi * 4;
                int bb = m0 >> 10, nq0 = m0 & 1023;
                bf16x4 pk = { (__bf16)(acc[mt][nt][0] + bias), (__bf16)(acc[mt][nt][1] + bias),
                              (__bf16)(acc[mt][nt][2] + bias), (__bf16)(acc[mt][nt][3] + bias) };
                *(bf16x4*)(Vt + ((long)(bb * NH + h) * DP + d) * NSEQ + nq0) = pk;
            }
        } else {
            __bf16* dst = (sec == 0) ? Qp : Kp;
            float scl = (sec == 0) ? QSCALE : 1.0f;
            #pragma unroll
            for (int mt = 0; mt < 4; ++mt) {
                #pragma unroll
                for (int r = 0; r < 4; ++r) {
                    int m = (int)rowA0 + wm * 64 + mt * 16 + lhi * 4 + r;
                    int bb = m >> 10, nq = m & 1023;
                    long bhn = (long)(bb * NH + h) * NSEQ + nq;
                    dst[bhn * DP + d] = (__bf16)((acc[mt][nt][r] + bias) * scl);
                }
            }
        }
    }
}

// ---------------- flash attention v7 ----------------
// 512 blocks x 8 waves, ONE 16-row q-set per wave (128 rows/block) -> 2 blocks
// per CU = 16 waves/CU = 4 waves/SIMD; co-resident blocks are not barrier-
// synced, so one block's MFMA phase overlaps the other's softmax/barrier.
// K AND V double-buffered -> ONE raw barrier per iteration: stage kb+1 into
// idle buffers at top, QK from K[buf], softmax, PV from V[buf], own vmcnt(0),
// barrier. Per-wave math identical to v6 (flipped PV, defer-max, exp2 domain).
// LDS map (72 KB): K0 [0,16K) K1 [16K,32K) ; V0 [32K,44K) V1 [44K,56K) ;
// P [56K,72K) = 2 KB/wave.

__global__ __launch_bounds__(512, 4) void flash_kernel(
    const __bf16* __restrict__ Qp, const __bf16* __restrict__ Kp,
    const __bf16* __restrict__ Vt, __bf16* __restrict__ atto)
{
    __shared__ char lds[73728];
    const int tid  = threadIdx.x;
    const int wave = tid >> 6, lane = tid & 63;
    const int lhi = lane >> 4, llo = lane & 15;

    // chunked XCD swizzle (512 = 8 XCD x 64): XCD i owns bh in [i*8,(i+1)*8)
    int lin = blockIdx.x;
    int v   = ((lin & 7) << 6) + (lin >> 3);
    const int qx = v & 7;          // q-chunk of 128 rows
    const int bh = v >> 3;

    const __bf16* Qb  = Qp + (long)bh * NSEQ * DP;
    const char*   KbB = (const char*)(Kp + (long)bh * NSEQ * DP);
    const char*   VbB = (const char*)(Vt + (long)bh * DP * NSEQ);

    char* P = lds + 57344 + wave * 2048;
    const int q0 = qx * 128 + wave * 16;

    // ---- staging (global_load_lds, linear LDS dest, inverse-swizzled source) ----
    auto stageK = [&](int kt, int kbuf) {
        #pragma unroll
        for (int j = 0; j < 2; ++j) {
            int bk  = wave * 2 + j;                 // 16 x 1KB chunks
            int key = bk * 4 + (lane >> 4);         // LDS row (256 B each)
            int c   = (lane & 15) * 16;             // byte within row
            gl_lds16(KbB + ((long)(kt * 64 + key)) * 192 + (c ^ ((key & 7) << 4)),
                     lds + kbuf * 16384 + bk * 1024);
        }
    };
    auto stageV = [&](int kt, int vb) {
        int dv = wave * 8 + (lane >> 3);            // LDS row (128 B each)
        int c  = (lane & 7) * 16;
        gl_lds16(VbB + (long)dv * 2048 + kt * 128 + (c ^ ((dv & 7) << 4)),
                 lds + 32768 + vb * 12288 + wave * 1024);
        if (wave < 4) {
            int dv2 = 64 + wave * 8 + (lane >> 3);
            gl_lds16(VbB + (long)dv2 * 2048 + kt * 128 + (c ^ ((dv2 & 7) << 4)),
                     lds + 32768 + vb * 12288 + 8192 + wave * 1024);
        }
    };

    // Q fragments (B operand): Q[q][d = dc*32 + lhi*8 + j]; QSCALE folded
    bf16x8 aq[3];
    #pragma unroll
    for (int dc = 0; dc < 3; ++dc)
        aq[dc] = *(const bf16x8*)(Qb + (long)(q0 + llo) * DP + dc * 32 + lhi * 8);

    float mr = -3.0e38f, lr = 0.f;     // per-lane state for q = q0 + llo
    f32x4 acc[5];
    #pragma unroll
    for (int t = 0; t < 5; ++t) acc[t] = (f32x4){0.f, 0.f, 0.f, 0.f};

    // prologue: tile 0 into buffers 0
    stageK(0, 0);
    stageV(0, 0);
    asm volatile("s_waitcnt vmcnt(0)" ::: "memory");
    RAW_BAR();

    #pragma unroll 1
    for (int kb = 0; kb < 16; ++kb) {
        const int buf = kb & 1;
        if (kb < 15) {                              // lands during this iter's compute
            stageK(kb + 1, buf ^ 1);
            stageV(kb + 1, buf ^ 1);
        }

        // S^T = mfma(K, Q): s[ct][r] = S[q=llo][key=ct*16+lhi*4+r]
        f32x4 s[4];
        __builtin_amdgcn_s_setprio(1);
        #pragma unroll
        for (int ct = 0; ct < 4; ++ct) {
            f32x4 z = (f32x4){0.f, 0.f, 0.f, 0.f};
            #pragma unroll
            for (int dc = 0; dc < 3; ++dc) {
                bf16x8 kf = *(const bf16x8*)(lds + buf * 16384 +
                    (((ct * 16 + llo) * 256 + dc * 64 + lhi * 16) ^ ((llo & 7) << 4)));
                z = __builtin_amdgcn_mfma_f32_16x16x32_bf16(kf, aq[dc], z, 0, 0, 0);
            }
            s[ct] = z;
        }
        __builtin_amdgcn_s_setprio(0);

        // ---- online softmax (exp2 domain, lane-local row q=llo) ----
        float m0 = fmaxf(fmaxf(s[0][0], s[0][1]), fmaxf(s[0][2], s[0][3]));
        float m1 = fmaxf(fmaxf(s[1][0], s[1][1]), fmaxf(s[1][2], s[1][3]));
        float m2 = fmaxf(fmaxf(s[2][0], s[2][1]), fmaxf(s[2][2], s[2][3]));
        float m3 = fmaxf(fmaxf(s[3][0], s[3][1]), fmaxf(s[3][2], s[3][3]));
        float mx = fmaxf(fmaxf(m0, m1), fmaxf(m2, m3));
        mx = fmaxf(mx, __shfl_xor(mx, 16, 64));
        mx = fmaxf(mx, __shfl_xor(mx, 32, 64));
        if (!__all(mx <= mr + 8.0f)) {             // T13 defer-max
            float mn = fmaxf(mr, mx);
            float al = exp2f(mr - mn);
            mr = mn;
            lr *= al;
            #pragma unroll
            for (int t = 0; t < 5; ++t)
                #pragma unroll
                for (int r = 0; r < 4; ++r) acc[t][r] *= al;
        }
        float p[4][4]; float sm = 0.f;
        #pragma unroll
        for (int ct = 0; ct < 4; ++ct)
            #pragma unroll
            for (int r = 0; r < 4; ++r) { p[ct][r] = exp2f(s[ct][r] - mr); sm += p[ct][r]; }
        sm += __shfl_xor(sm, 16, 64);
        sm += __shfl_xor(sm, 32, 64);
        lr += sm;
        #pragma unroll
        for (int ct = 0; ct < 4; ++ct) {
            bf16x4 pk = { (__bf16)p[ct][0], (__bf16)p[ct][1], (__bf16)p[ct][2], (__bf16)p[ct][3] };
            *(bf16x4*)(P + ((llo * 128 + ct * 32 + lhi * 8) ^ ((llo & 7) << 4))) = pk;
        }
        asm volatile("s_waitcnt lgkmcnt(0)" ::: "memory");

        // PV flipped: A = V^T frag (row=d), B = P frag (col=q) -> O[q=llo][d]
        __builtin_amdgcn_s_setprio(1);
        #pragma unroll
        for (int nc = 0; nc < 2; ++nc) {
            bf16x8 pP = *(const bf16x8*)(P + ((llo * 128 + nc * 64 + lhi * 16) ^ ((llo & 7) << 4)));
            #pragma unroll
            for (int t = 0; t < 5; ++t) {
                bf16x8 bv = *(const bf16x8*)(lds + 32768 + buf * 12288 +
                    (((t * 16 + llo) * 128 + nc * 64 + lhi * 16) ^ ((llo & 7) << 4)));
                acc[t] = __builtin_amdgcn_mfma_f32_16x16x32_bf16(bv, pP, acc[t], 0, 0, 0);
            }
        }
        __builtin_amdgcn_s_setprio(0);

        if (kb < 15) asm volatile("s_waitcnt vmcnt(0)" ::: "memory");  // own stages landed
        RAW_BAR();
    }

    // epilogue: per-lane q=llo; d = t*16 + lhi*4 + r -> bf16x4 8B stores
    const float linv = 1.f / lr;
    const int b = bh >> 4, h = bh & 15;
    const int q = q0 + llo;
    __bf16* outP = atto + (long)(b * NSEQ + q) * HID + h * HD;
    #pragma unroll
    for (int t = 0; t < 5; ++t) {
        int d0 = t * 16 + lhi * 4;
        if (d0 < HD) {
            bf16x4 o = { (__bf16)(acc[t][0] * linv), (__bf16)(acc[t][1] * linv),
                         (__bf16)(acc[t][2] * linv), (__bf16)(acc[t][3] * linv) };
            *(bf16x4*)(outP + d0) = o;
        }
    }
}

// ---------------- GEMM 2: out = atto @ w_out + b_out (fp32 out) ----------------
// BM=128: grid 160 blocks (32 M-tiles x 5 N-tiles, N padded 1152->1280)

__global__ __launch_bounds__(512, 4) void gemm_out_kernel(
    const __bf16* __restrict__ atto, const __bf16* __restrict__ woutT,
    const float* __restrict__ b_out, float* __restrict__ out)
{
    __shared__ char lds[49152];
    f32x4 acc[4][4];
    #pragma unroll
    for (int i = 0; i < 4; ++i)
        #pragma unroll
        for (int j = 0; j < 4; ++j) acc[i][j] = (f32x4){0.f, 0.f, 0.f, 0.f};

    // bijective chunked XCD swizzle: 160 blocks, 20 per XCD (4 bx x 5 by)
    int lin = blockIdx.x;
    int v   = (lin & 7) * 20 + (lin >> 3);
    int bx  = v / 5, by = v - bx * 5;
    long rowA0 = (long)bx * 128, rowB0 = (long)by * 256;

    gemm_core<4>(atto, woutT, HID, HID, HID / 32, rowA0, rowB0, lds, acc);

    const int wave = threadIdx.x >> 6, lane = threadIdx.x & 63;
    const int wm = wave >> 2, wn = wave & 3, lhi = lane >> 4, llo = lane & 15;

    #pragma unroll
    for (int nt = 0; nt < 4; ++nt) {
        int n = (int)rowB0 + wn * 64 + nt * 16 + llo;   // 0..1279
        if (n >= HID) continue;
        float bias = b_out[n];
        #pragma unroll
        for (int mt = 0; mt < 4; ++mt) {
            #pragma unroll
            for (int r = 0; r < 4; ++r) {
                int m = (int)rowA0 + wm * 64 + mt * 16 + lhi * 4 + r;
                out[(long)m * HID + n] = acc[mt][nt][r] + bias;
            }
        }
    }
}

// ---------------- launch ----------------

extern "C" void kernel_launch(void* const* d_in, const int* in_sizes, int n_in,
                              void* d_out, int out_size, void* d_ws, size_t ws_size,
                              hipStream_t stream) {
    const float* x      = (const float*)d_in[0];
    const float* w_qkv  = (const float*)d_in[1];
    const float* b_qkv  = (const float*)d_in[2];
    const float* w_out  = (const float*)d_in[3];
    const float* b_out  = (const float*)d_in[4];
    float* out = (float*)d_out;
    char* ws = (char*)d_ws;

    __bf16* xb    = (__bf16*)(ws + XB_OFF);
    __bf16* atto  = (__bf16*)(ws + XB_OFF);     // aliases xb (dead after gemm_qkv)
    __bf16* wqkvT = (__bf16*)(ws + WQKVT_OFF);
    __bf16* woutT = (__bf16*)(ws + WOUTT_OFF);
    __bf16* Qp    = (__bf16*)(ws + QP_OFF);
    __bf16* Kp    = (__bf16*)(ws + KP_OFF);
    __bf16* Vt    = (__bf16*)(ws + VT_OFF);

    pad_kernel<<<896, 256, 0, stream>>>(Qp, Kp, Vt);
    conv_x_kernel<<<4608, 256, 0, stream>>>(x, xb, 1179648L);
    transpose_cvt_kernel<<<dim3(108, 36), dim3(32, 8), 0, stream>>>(w_qkv, wqkvT, HID, QKV3);
    transpose_cvt_kernel<<<dim3(36, 36), dim3(32, 8), 0, stream>>>(w_out, woutT, HID, HID);
    gemm_qkv_kernel<<<448, 512, 0, stream>>>(xb, wqkvT, b_qkv, Qp, Kp, Vt);
    flash_kernel<<<512, 512, 0, stream>>>(Qp, Kp, Vt, atto);
    gemm_out_kernel<<<160, 512, 0, stream>>>(atto, woutT, b_out, out);
}

// Round 9
// 127.233 us; speedup vs baseline: 2.6254x; 1.0566x over previous
//
#include <hip/hip_runtime.h>
#include <cstdint>

// Problem constants
#define NB 4
#define NSEQ 1024
#define NH 16
#define HD 72
#define HID 1152
#define QKV3 3456
#define DP 96           // padded head dim (multiple of 32 for K=32 MFMA)
// scale = 72^-0.5 folded with log2(e) so softmax runs in exp2 domain
#define QSCALE 0.17003713711193175f

typedef __attribute__((ext_vector_type(8))) __bf16 bf16x8;
typedef __attribute__((ext_vector_type(4))) __bf16 bf16x4;
typedef __attribute__((ext_vector_type(4))) float f32x4;

#define AS1 __attribute__((address_space(1)))
#define AS3 __attribute__((address_space(3)))

__device__ __forceinline__ void gl_lds16(const void* g, void* l) {
    // async global->LDS, 16B per lane; LDS dest = wave-uniform base + lane*16
    __builtin_amdgcn_global_load_lds((const AS1 uint32_t*)g, (AS3 uint32_t*)l, 16, 0, 0);
}

// raw barrier: no compiler-inserted vmcnt(0) drain (unlike __syncthreads)
#define RAW_BAR() asm volatile("s_barrier" ::: "memory")

// Workspace layout (bytes)
#define XB_OFF     0UL           // x as bf16 [4096][1152]; ALIASED as atto after gemm_qkv
#define WQKVT_OFF  9437184UL     // w_qkv^T bf16  [3584][1152] (rows 3456+ junk, unused)
#define WOUTT_OFF  17694720UL    // w_out^T bf16  [1280][1152] (rows 1152+ junk, unused)
#define QP_OFF     20643840UL    // Q padded bf16 [64][1024][96] (QSCALE folded)
#define KP_OFF     33226752UL    // K padded bf16 [64][1024][96]
#define VT_OFF     45809664UL    // V^T padded bf16 [64][96][1024]
// total: 58,392,576 bytes

// ---------------- fused prep kernel ----------------
// blocks [0,4608):      x fp32 -> bf16 (float4/thread)
// blocks [4608,8496):   w_qkv [1152][3456] -> wqkvT [3456][1152] bf16 (32x32 tiles)
// blocks [8496,9792):   w_out [1152][1152] -> woutT bf16
// blocks [9792,10688):  zero d=72..95 pad regions of Qp/Kp/Vt

__global__ void prep_kernel(const float* __restrict__ x, __bf16* __restrict__ xb,
                            const float* __restrict__ w_qkv, __bf16* __restrict__ wqkvT,
                            const float* __restrict__ w_out, __bf16* __restrict__ woutT,
                            __bf16* __restrict__ Qp, __bf16* __restrict__ Kp,
                            __bf16* __restrict__ Vt) {
    __shared__ float t[32][33];
    const int blk = blockIdx.x, tid = threadIdx.x;
    if (blk < 4608) {
        long i = (long)blk * 256 + tid;
        float4 v = ((const float4*)x)[i];
        bf16x4 o = { (__bf16)v.x, (__bf16)v.y, (__bf16)v.z, (__bf16)v.w };
        ((bf16x4*)xb)[i] = o;
    } else if (blk < 9792) {
        const float* in;  __bf16* outp;  int Nc, K, n0, k0;
        if (blk < 8496) {
            int b = blk - 4608; in = w_qkv; outp = wqkvT; Nc = QKV3; K = HID;
            n0 = (b % 108) * 32; k0 = (b / 108) * 32;
        } else {
            int b = blk - 8496; in = w_out; outp = woutT; Nc = HID; K = HID;
            n0 = (b % 36) * 32; k0 = (b / 36) * 32;
        }
        int xx = tid & 31, yy = tid >> 5;
        #pragma unroll
        for (int i = 0; i < 32; i += 8)
            t[yy + i][xx] = in[(long)(k0 + yy + i) * Nc + n0 + xx];
        __syncthreads();
        #pragma unroll
        for (int i = 0; i < 32; i += 8)
            outp[(long)(n0 + yy + i) * K + k0 + xx] = (__bf16)t[xx][yy + i];
    } else {
        int i = (blk - 9792) * 256 + tid;            // 0..229375
        uint4 z = make_uint4(0u, 0u, 0u, 0u);
        if (i < 131072) {
            __bf16* base = (i & 65536) ? Kp : Qp;
            int row = i & 65535;
            uint4* p = (uint4*)(base + row * 96 + 72);   // 48 B pad per row
            p[0] = z; p[1] = z; p[2] = z;
        } else {
            int j = i - 131072;                          // 0..98303
            int bh = j / 1536, w = j - bh * 1536;
            *((uint4*)(Vt + (long)bh * 98304 + 73728) + w) = z;
        }
    }
}

// ---------------- GEMM engine: BM x 256 tile, 8 waves (2M x 4N), BK=32 ----------------
// TRIPLE-buffered LDS, global_load_lds staging 2 tiles ahead, counted vmcnt(L)
// at tile boundary (never drained to 0 in steady state; each wave waits for its
// OWN t+1 loads, barrier then guarantees tile t+1 resident block-wide),
// raw s_barrier once per tile, T2 XOR swizzle with pre-swizzled global source,
// T5 setprio around MFMA clusters.

template<int MT>   // m-fragments per wave; BM = MT*32 (4 -> 128)
__device__ __forceinline__ void gemm_core(
    const __bf16* __restrict__ A, const __bf16* __restrict__ Bt,
    int lda, int ldb, int ntk, long rowA0, long rowB0,
    char* lds, f32x4 acc[MT][4])
{
    constexpr int BM    = MT * 32;
    constexpr int ATILE = BM * 64;        // bytes (rows of 64 B)
    constexpr int TILE  = ATILE + 256 * 64;
    constexpr int L     = BM / 128 + 2;   // gl_lds per thread per tile (=3)

    const int tid  = threadIdx.x;
    const int wave = tid >> 6, lane = tid & 63;
    const int wm = wave >> 2, wn = wave & 3;      // 2 x 4 wave grid
    const int lhi = lane >> 4, llo = lane & 15;
    const int srow = tid >> 2;                    // staging row (0..127)
    const int scol = (tid & 3) * 8;               // staging col element

    auto stage = [&](int kt, int buf) {
        char* base = lds + buf * TILE;
        #pragma unroll
        for (int j = 0; j < BM / 128; ++j) {
            int r  = srow + j * 128;
            int ks = scol ^ ((((unsigned)r >> 1) & 3) << 3);   // pre-swizzled source
            gl_lds16(A + (rowA0 + r) * (long)lda + kt * 32 + ks, base + tid * 16 + j * 8192);
        }
        #pragma unroll
        for (int j = 0; j < 2; ++j) {
            int r  = srow + j * 128;
            int ks = scol ^ ((((unsigned)r >> 1) & 3) << 3);
            gl_lds16(Bt + (rowB0 + r) * (long)ldb + kt * 32 + ks,
                     base + ATILE + tid * 16 + j * 8192);
        }
    };

    stage(0, 0);
    stage(1, 1);
    asm volatile("s_waitcnt vmcnt(%0)" :: "n"(L) : "memory");   // tile0 landed
    RAW_BAR();

    int buf = 0;
    #pragma unroll 1
    for (int t = 0; t < ntk; ++t) {
        char* Ab = lds + buf * TILE;
        char* Bb = Ab + ATILE;
        int nb = buf + 2; if (nb >= 3) nb -= 3;
        if (t + 2 < ntk) stage(t + 2, nb);        // issue 2 tiles ahead

        bf16x8 bfr[4];
        #pragma unroll
        for (int nt = 0; nt < 4; ++nt) {
            int R = wn * 64 + nt * 16 + llo;
            int b = (R * 64 + lhi * 16) ^ ((((unsigned)R >> 1) & 3) << 4);
            bfr[nt] = *(const bf16x8*)(Bb + b);
        }
        bf16x8 af[MT / 2];
        #pragma unroll
        for (int mt = 0; mt < MT / 2; ++mt) {
            int R = wm * (BM / 2) + mt * 16 + llo;
            int b = (R * 64 + lhi * 16) ^ ((((unsigned)R >> 1) & 3) << 4);
            af[mt] = *(const bf16x8*)(Ab + b);
        }
        __builtin_amdgcn_s_setprio(1);
        #pragma unroll
        for (int mt = 0; mt < MT / 2; ++mt)
            #pragma unroll
            for (int nt = 0; nt < 4; ++nt)
                acc[mt][nt] = __builtin_amdgcn_mfma_f32_16x16x32_bf16(af[mt], bfr[nt], acc[mt][nt], 0, 0, 0);
        __builtin_amdgcn_s_setprio(0);
        #pragma unroll
        for (int mt = 0; mt < MT / 2; ++mt) {
            int R = wm * (BM / 2) + (MT / 2 + mt) * 16 + llo;
            int b = (R * 64 + lhi * 16) ^ ((((unsigned)R >> 1) & 3) << 4);
            af[mt] = *(const bf16x8*)(Ab + b);
        }
        __builtin_amdgcn_s_setprio(1);
        #pragma unroll
        for (int mt = 0; mt < MT / 2; ++mt)
            #pragma unroll
            for (int nt = 0; nt < 4; ++nt)
                acc[MT / 2 + mt][nt] = __builtin_amdgcn_mfma_f32_16x16x32_bf16(af[mt], bfr[nt], acc[MT / 2 + mt][nt], 0, 0, 0);
        __builtin_amdgcn_s_setprio(0);
        // boundary: wait until only t+2's L loads remain -> t+1 resident
        if (t + 2 < ntk)      asm volatile("s_waitcnt vmcnt(%0)" :: "n"(L) : "memory");
        else if (t + 1 < ntk) asm volatile("s_waitcnt vmcnt(0)" ::: "memory");
        RAW_BAR();
        buf = (buf == 2) ? 0 : buf + 1;
    }
}

// ---------------- GEMM 1: qkv = x @ w_qkv + b, scatter to Qp/Kp/Vt ----------------
// BM=128: grid 448 blocks (32 M-tiles x 14 N-tiles, N padded 3456->3584)

__global__ __launch_bounds__(512, 4) void gemm_qkv_kernel(
    const __bf16* __restrict__ xb, const __bf16* __restrict__ wqkvT,
    const float* __restrict__ b_qkv,
    __bf16* __restrict__ Qp, __bf16* __restrict__ Kp, __bf16* __restrict__ Vt)
{
    __shared__ char lds[73728];
    f32x4 acc[4][4];
    #pragma unroll
    for (int i = 0; i < 4; ++i)
        #pragma unroll
        for (int j = 0; j < 4; ++j) acc[i][j] = (f32x4){0.f, 0.f, 0.f, 0.f};

    // bijective chunked XCD swizzle: 448 blocks, 56 per XCD (4 bx x 14 by)
    int lin = blockIdx.x;
    int v   = (lin & 7) * 56 + (lin >> 3);
    int bx  = v / 14, by = v - bx * 14;
    long rowA0 = (long)bx * 128, rowB0 = (long)by * 256;

    gemm_core<4>(xb, wqkvT, HID, HID, HID / 32, rowA0, rowB0, lds, acc);

    const int wave = threadIdx.x >> 6, lane = threadIdx.x & 63;
    const int wm = wave >> 2, wn = wave & 3, lhi = lane >> 4, llo = lane & 15;

    #pragma unroll
    for (int nt = 0; nt < 4; ++nt) {
        int n = (int)rowB0 + wn * 64 + nt * 16 + llo;   // 0..3583
        if (n >= QKV3) continue;
        int sec = n / HID;
        int nn  = n - sec * HID;
        int h   = nn / HD;
        int d   = nn - h * HD;
        float bias = b_qkv[n];
        if (sec == 2) {
            // V: r-quad is nq-contiguous -> one 8B bf16x4 store per mt
            #pragma unroll
            for (int mt = 0; mt < 4; ++mt) {
                int m0 = (int)rowA0 + wm * 64 + mt * 16 + lhi * 4;
                int bb = m0 >> 10, nq0 = m0 & 1023;
                bf16x4 pk = { (__bf16)(acc[mt][nt][0] + bias), (__bf16)(acc[mt][nt][1] + bias),
                              (__bf16)(acc[mt][nt][2] + bias), (__bf16)(acc[mt][nt][3] + bias) };
                *(bf16x4*)(Vt + ((long)(bb * NH + h) * DP + d) * NSEQ + nq0) = pk;
            }
        } else {
            __bf16* dst = (sec == 0) ? Qp : Kp;
            float scl = (sec == 0) ? QSCALE : 1.0f;
            #pragma unroll
            for (int mt = 0; mt < 4; ++mt) {
                #pragma unroll
                for (int r = 0; r < 4; ++r) {
                    int m = (int)rowA0 + wm * 64 + mt * 16 + lhi * 4 + r;
                    int bb = m >> 10, nq = m & 1023;
                    long bhn = (long)(bb * NH + h) * NSEQ + nq;
                    dst[bhn * DP + d] = (__bf16)((acc[mt][nt][r] + bias) * scl);
                }
            }
        }
    }
}

// ---------------- flash attention v8 ----------------
// 512 blocks x 8 waves, one 16-row q-set per wave -> 2 independent blocks/CU.
// K AND V double-buffered -> ONE raw barrier per iteration. K uses FULL-ROW
// (row&15)<<4 swizzle (16 slots for 16 llo lanes -> conflict-free QK reads);
// staging global source pre-swizzled with the same involution (rule #21).
// Per-wave math identical to v7 (flipped PV, defer-max, exp2 domain).
// LDS map (72 KB): K0 [0,16K) K1 [16K,32K) ; V0 [32K,44K) V1 [44K,56K) ;
// P [56K,72K) = 2 KB/wave.

__global__ __launch_bounds__(512, 4) void flash_kernel(
    const __bf16* __restrict__ Qp, const __bf16* __restrict__ Kp,
    const __bf16* __restrict__ Vt, __bf16* __restrict__ atto)
{
    __shared__ char lds[73728];
    const int tid  = threadIdx.x;
    const int wave = tid >> 6, lane = tid & 63;
    const int lhi = lane >> 4, llo = lane & 15;

    // chunked XCD swizzle (512 = 8 XCD x 64): XCD i owns bh in [i*8,(i+1)*8)
    int lin = blockIdx.x;
    int v   = ((lin & 7) << 6) + (lin >> 3);
    const int qx = v & 7;          // q-chunk of 128 rows
    const int bh = v >> 3;

    const __bf16* Qb  = Qp + (long)bh * NSEQ * DP;
    const char*   KbB = (const char*)(Kp + (long)bh * NSEQ * DP);
    const char*   VbB = (const char*)(Vt + (long)bh * DP * NSEQ);

    char* P = lds + 57344 + wave * 2048;
    const int q0 = qx * 128 + wave * 16;

    // ---- staging (global_load_lds, linear LDS dest, inverse-swizzled source) ----
    auto stageK = [&](int kt, int kbuf) {
        #pragma unroll
        for (int j = 0; j < 2; ++j) {
            int bk  = wave * 2 + j;                 // 16 x 1KB chunks
            int key = bk * 4 + (lane >> 4);         // LDS row (256 B each)
            int c   = (lane & 15) * 16;             // byte slot within row
            gl_lds16(KbB + ((long)(kt * 64 + key)) * 192 + (c ^ ((key & 15) << 4)),
                     lds + kbuf * 16384 + bk * 1024);
        }
    };
    auto stageV = [&](int kt, int vb) {
        int dv = wave * 8 + (lane >> 3);            // LDS row (128 B each)
        int c  = (lane & 7) * 16;
        gl_lds16(VbB + (long)dv * 2048 + kt * 128 + (c ^ ((dv & 7) << 4)),
                 lds + 32768 + vb * 12288 + wave * 1024);
        if (wave < 4) {
            int dv2 = 64 + wave * 8 + (lane >> 3);
            gl_lds16(VbB + (long)dv2 * 2048 + kt * 128 + (c ^ ((dv2 & 7) << 4)),
                     lds + 32768 + vb * 12288 + 8192 + wave * 1024);
        }
    };

    // Q fragments (B operand): Q[q][d = dc*32 + lhi*8 + j]; QSCALE folded
    bf16x8 aq[3];
    #pragma unroll
    for (int dc = 0; dc < 3; ++dc)
        aq[dc] = *(const bf16x8*)(Qb + (long)(q0 + llo) * DP + dc * 32 + lhi * 8);

    float mr = -3.0e38f, lr = 0.f;     // per-lane state for q = q0 + llo
    f32x4 acc[5];
    #pragma unroll
    for (int t = 0; t < 5; ++t) acc[t] = (f32x4){0.f, 0.f, 0.f, 0.f};

    // prologue: tile 0 into buffers 0
    stageK(0, 0);
    stageV(0, 0);
    asm volatile("s_waitcnt vmcnt(0)" ::: "memory");
    RAW_BAR();

    #pragma unroll 1
    for (int kb = 0; kb < 16; ++kb) {
        const int buf = kb & 1;
        if (kb < 15) {                              // lands during this iter's compute
            stageK(kb + 1, buf ^ 1);
            stageV(kb + 1, buf ^ 1);
        }

        // S^T = mfma(K, Q): s[ct][r] = S[q=llo][key=ct*16+lhi*4+r]
        f32x4 s[4];
        __builtin_amdgcn_s_setprio(1);
        #pragma unroll
        for (int ct = 0; ct < 4; ++ct) {
            f32x4 z = (f32x4){0.f, 0.f, 0.f, 0.f};
            #pragma unroll
            for (int dc = 0; dc < 3; ++dc) {
                bf16x8 kf = *(const bf16x8*)(lds + buf * 16384 +
                    (((ct * 16 + llo) * 256 + dc * 64 + lhi * 16) ^ ((llo & 15) << 4)));
                z = __builtin_amdgcn_mfma_f32_16x16x32_bf16(kf, aq[dc], z, 0, 0, 0);
            }
            s[ct] = z;
        }
        __builtin_amdgcn_s_setprio(0);

        // ---- online softmax (exp2 domain, lane-local row q=llo) ----
        float m0 = fmaxf(fmaxf(s[0][0], s[0][1]), fmaxf(s[0][2], s[0][3]));
        float m1 = fmaxf(fmaxf(s[1][0], s[1][1]), fmaxf(s[1][2], s[1][3]));
        float m2 = fmaxf(fmaxf(s[2][0], s[2][1]), fmaxf(s[2][2], s[2][3]));
        float m3 = fmaxf(fmaxf(s[3][0], s[3][1]), fmaxf(s[3][2], s[3][3]));
        float mx = fmaxf(fmaxf(m0, m1), fmaxf(m2, m3));
        mx = fmaxf(mx, __shfl_xor(mx, 16, 64));
        mx = fmaxf(mx, __shfl_xor(mx, 32, 64));
        if (!__all(mx <= mr + 8.0f)) {             // T13 defer-max
            float mn = fmaxf(mr, mx);
            float al = exp2f(mr - mn);
            mr = mn;
            lr *= al;
            #pragma unroll
            for (int t = 0; t < 5; ++t)
                #pragma unroll
                for (int r = 0; r < 4; ++r) acc[t][r] *= al;
        }
        float p[4][4]; float sm = 0.f;
        #pragma unroll
        for (int ct = 0; ct < 4; ++ct)
            #pragma unroll
            for (int r = 0; r < 4; ++r) { p[ct][r] = exp2f(s[ct][r] - mr); sm += p[ct][r]; }
        sm += __shfl_xor(sm, 16, 64);
        sm += __shfl_xor(sm, 32, 64);
        lr += sm;
        #pragma unroll
        for (int ct = 0; ct < 4; ++ct) {
            bf16x4 pk = { (__bf16)p[ct][0], (__bf16)p[ct][1], (__bf16)p[ct][2], (__bf16)p[ct][3] };
            *(bf16x4*)(P + ((llo * 128 + ct * 32 + lhi * 8) ^ ((llo & 7) << 4))) = pk;
        }
        asm volatile("s_waitcnt lgkmcnt(0)" ::: "memory");

        // PV flipped: A = V^T frag (row=d), B = P frag (col=q) -> O[q=llo][d]
        __builtin_amdgcn_s_setprio(1);
        #pragma unroll
        for (int nc = 0; nc < 2; ++nc) {
            bf16x8 pP = *(const bf16x8*)(P + ((llo * 128 + nc * 64 + lhi * 16) ^ ((llo & 7) << 4)));
            #pragma unroll
            for (int t = 0; t < 5; ++t) {
                bf16x8 bv = *(const bf16x8*)(lds + 32768 + buf * 12288 +
                    (((t * 16 + llo) * 128 + nc * 64 + lhi * 16) ^ ((llo & 7) << 4)));
                acc[t] = __builtin_amdgcn_mfma_f32_16x16x32_bf16(bv, pP, acc[t], 0, 0, 0);
            }
        }
        __builtin_amdgcn_s_setprio(0);

        if (kb < 15) asm volatile("s_waitcnt vmcnt(0)" ::: "memory");  // own stages landed
        RAW_BAR();
    }

    // epilogue: per-lane q=llo; d = t*16 + lhi*4 + r -> bf16x4 8B stores
    const float linv = 1.f / lr;
    const int b = bh >> 4, h = bh & 15;
    const int q = q0 + llo;
    __bf16* outP = atto + (long)(b * NSEQ + q) * HID + h * HD;
    #pragma unroll
    for (int t = 0; t < 5; ++t) {
        int d0 = t * 16 + lhi * 4;
        if (d0 < HD) {
            bf16x4 o = { (__bf16)(acc[t][0] * linv), (__bf16)(acc[t][1] * linv),
                         (__bf16)(acc[t][2] * linv), (__bf16)(acc[t][3] * linv) };
            *(bf16x4*)(outP + d0) = o;
        }
    }
}

// ---------------- GEMM 2: out = atto @ w_out + b_out (fp32 out) ----------------
// BM=128: grid 160 blocks (32 M-tiles x 5 N-tiles, N padded 1152->1280)

__global__ __launch_bounds__(512, 4) void gemm_out_kernel(
    const __bf16* __restrict__ atto, const __bf16* __restrict__ woutT,
    const float* __restrict__ b_out, float* __restrict__ out)
{
    __shared__ char lds[73728];
    f32x4 acc[4][4];
    #pragma unroll
    for (int i = 0; i < 4; ++i)
        #pragma unroll
        for (int j = 0; j < 4; ++j) acc[i][j] = (f32x4){0.f, 0.f, 0.f, 0.f};

    // bijective chunked XCD swizzle: 160 blocks, 20 per XCD (4 bx x 5 by)
    int lin = blockIdx.x;
    int v   = (lin & 7) * 20 + (lin >> 3);
    int bx  = v / 5, by = v - bx * 5;
    long rowA0 = (long)bx * 128, rowB0 = (long)by * 256;

    gemm_core<4>(atto, woutT, HID, HID, HID / 32, rowA0, rowB0, lds, acc);

    const int wave = threadIdx.x >> 6, lane = threadIdx.x & 63;
    const int wm = wave >> 2, wn = wave & 3, lhi = lane >> 4, llo = lane & 15;

    #pragma unroll
    for (int nt = 0; nt < 4; ++nt) {
        int n = (int)rowB0 + wn * 64 + nt * 16 + llo;   // 0..1279
        if (n >= HID) continue;
        float bias = b_out[n];
        #pragma unroll
        for (int mt = 0; mt < 4; ++mt) {
            #pragma unroll
            for (int r = 0; r < 4; ++r) {
                int m = (int)rowA0 + wm * 64 + mt * 16 + lhi * 4 + r;
                out[(long)m * HID + n] = acc[mt][nt][r] + bias;
            }
        }
    }
}

// ---------------- launch ----------------

extern "C" void kernel_launch(void* const* d_in, const int* in_sizes, int n_in,
                              void* d_out, int out_size, void* d_ws, size_t ws_size,
                              hipStream_t stream) {
    const float* x      = (const float*)d_in[0];
    const float* w_qkv  = (const float*)d_in[1];
    const float* b_qkv  = (const float*)d_in[2];
    const float* w_out  = (const float*)d_in[3];
    const float* b_out  = (const float*)d_in[4];
    float* out = (float*)d_out;
    char* ws = (char*)d_ws;

    __bf16* xb    = (__bf16*)(ws + XB_OFF);
    __bf16* atto  = (__bf16*)(ws + XB_OFF);     // aliases xb (dead after gemm_qkv)
    __bf16* wqkvT = (__bf16*)(ws + WQKVT_OFF);
    __bf16* woutT = (__bf16*)(ws + WOUTT_OFF);
    __bf16* Qp    = (__bf16*)(ws + QP_OFF);
    __bf16* Kp    = (__bf16*)(ws + KP_OFF);
    __bf16* Vt    = (__bf16*)(ws + VT_OFF);

    prep_kernel<<<10688, 256, 0, stream>>>(x, xb, w_qkv, wqkvT, w_out, woutT, Qp, Kp, Vt);
    gemm_qkv_kernel<<<448, 512, 0, stream>>>(xb, wqkvT, b_qkv, Qp, Kp, Vt);
    flash_kernel<<<512, 512, 0, stream>>>(Qp, Kp, Vt, atto);
    gemm_out_kernel<<<160, 512, 0, stream>>>(atto, woutT, b_out, out);
}